// Round 1
// baseline (1490.505 us; speedup 1.0000x reference)
//
#include <hip/hip_runtime.h>
#include <math.h>

#define N_NODES 50000
#define N_EDGES 800000
#define IN_CH 128
#define HID 64
#define HEADS 4
#define OUT_CH 10
#define N_GRAPHS 512
#define NEG_SLOPE 0.2f

// ---- float <-> order-preserving uint (for atomicMax on floats) ----
__device__ __forceinline__ unsigned f2o(float f) {
    unsigned u = __float_as_uint(f);
    return (u & 0x80000000u) ? ~u : (u | 0x80000000u);
}
__device__ __forceinline__ float o2f(unsigned o) {
    return (o & 0x80000000u) ? __uint_as_float(o ^ 0x80000000u)
                             : __uint_as_float(~o);
}

// ---- simple LDS-tiled fp32 GEMM: Y[nrows,NC] = X[nrows,K] @ W[K,NC] ----
// blockDim.x must == NC
template<int K, int NC, int TM>
__global__ void gemm_k(const float* __restrict__ X, const float* __restrict__ W,
                       float* __restrict__ Y, int nrows) {
    __shared__ float xs[TM][K];
    int row0 = blockIdx.x * TM;
    for (int idx = threadIdx.x; idx < TM * K; idx += NC) {
        int r = idx / K, c = idx % K;
        int gr = row0 + r;
        xs[r][c] = (gr < nrows) ? X[(size_t)gr * K + c] : 0.f;
    }
    __syncthreads();
    int col = threadIdx.x;
    float acc[TM];
#pragma unroll
    for (int r = 0; r < TM; r++) acc[r] = 0.f;
    for (int k = 0; k < K; k++) {
        float w = W[k * NC + col];
#pragma unroll
        for (int r = 0; r < TM; r++) acc[r] += xs[r][k] * w;
    }
    for (int r = 0; r < TM; r++) {
        int gr = row0 + r;
        if (gr < nrows) Y[(size_t)gr * NC + col] = acc[r];
    }
}

// ---- per-node attention coefficients: a_s[n,h], a_d[n,h] ----
// block = H*C threads (C==64); wave w handles head w
template<int H, int C>
__global__ void attn_k(const float* __restrict__ Hm,
                       const float* __restrict__ asrc, const float* __restrict__ adst,
                       float* __restrict__ As, float* __restrict__ Ad) {
    int node = blockIdx.x;
    int t = threadIdx.x;
    int hd = t / C;
    int lane = t & 63;
    float v = Hm[(size_t)node * H * C + t];
    float s = v * asrc[t];
    float d = v * adst[t];
#pragma unroll
    for (int o = 32; o > 0; o >>= 1) { s += __shfl_xor(s, o); d += __shfl_xor(d, o); }
    if (lane == 0) { As[node * H + hd] = s; Ad[node * H + hd] = d; }
}

// ---- per-edge segment max (ordered-uint atomicMax) ----
template<int H>
__global__ void edge_max_k(const int* __restrict__ src, const int* __restrict__ dst,
                           const float* __restrict__ As, const float* __restrict__ Ad,
                           unsigned* __restrict__ M, int etot) {
    int i = blockIdx.x * blockDim.x + threadIdx.x;
    if (i >= etot) return;
    int s, d;
    if (i < N_EDGES) { s = src[i]; d = dst[i]; } else { s = d = i - N_EDGES; }
#pragma unroll
    for (int h = 0; h < H; h++) {
        float e = As[s * H + h] + Ad[d * H + h];
        e = e > 0.f ? e : NEG_SLOPE * e;
        atomicMax(&M[d * H + h], f2o(e));
    }
}

// ---- per-edge accumulate: denom[dst,h] += alpha; out[dst,h,:] += alpha*h[src,h,:] ----
// one 64-lane group per edge; blockDim = 256 (4 edges/block)
template<int H, int C>
__global__ void edge_acc_k(const int* __restrict__ src, const int* __restrict__ dst,
                           const float* __restrict__ As, const float* __restrict__ Ad,
                           const unsigned* __restrict__ M, const float* __restrict__ Hm,
                           float* __restrict__ Den, float* __restrict__ Out, int etot) {
    int lane = threadIdx.x & 63;
    int eidx = blockIdx.x * (blockDim.x >> 6) + (threadIdx.x >> 6);
    if (eidx >= etot) return;
    int s, d;
    if (eidx < N_EDGES) { s = src[eidx]; d = dst[eidx]; } else { s = d = eidx - N_EDGES; }
    float al[H];
#pragma unroll
    for (int h = 0; h < H; h++) {
        float e = As[s * H + h] + Ad[d * H + h];
        e = e > 0.f ? e : NEG_SLOPE * e;
        al[h] = expf(e - o2f(M[d * H + h]));
    }
    if (lane < H) atomicAdd(&Den[d * H + lane], al[lane]);
#pragma unroll
    for (int h = 0; h < H; h++) {
        atomicAdd(&Out[((size_t)d * H + h) * C + lane],
                  al[h] * Hm[((size_t)s * H + h) * C + lane]);
    }
}

// ---- normalize + bias + ELU (in place) ----
template<int H, int C>
__global__ void norm_k(float* __restrict__ Out, const float* __restrict__ Den,
                       const float* __restrict__ bias) {
    int node = blockIdx.x;
    int t = threadIdx.x;            // H*C threads
    int h = t / C;
    float v = Out[(size_t)node * H * C + t] / Den[node * H + h] + bias[t];
    v = v > 0.f ? v : expm1f(v);
    Out[(size_t)node * H * C + t] = v;
}

// ---- global mean pool (accumulate) ----
__global__ void pool_k(const float* __restrict__ Out2, const int* __restrict__ batch,
                       float* __restrict__ pooled, float* __restrict__ cnt) {
    int i = blockIdx.x * blockDim.x + threadIdx.x;
    if (i >= N_NODES * 64) return;
    int node = i >> 6, c = i & 63;
    int g = batch[node];
    atomicAdd(&pooled[g * 64 + c], Out2[i]);
    if (c == 0) atomicAdd(&cnt[g], 1.f);
}

// ---- final: out[g,:] = (pooled[g,:]/cnt) @ Wl + bl ----
__global__ void final_k(const float* __restrict__ pooled, const float* __restrict__ cnt,
                        const float* __restrict__ Wl, const float* __restrict__ bl,
                        float* __restrict__ out) {
    int g = blockIdx.x;
    int t = threadIdx.x;  // 64
    __shared__ float s[64];
    float c = cnt[g];
    c = c > 1.f ? c : 1.f;
    s[t] = pooled[g * 64 + t] / c;
    __syncthreads();
    if (t < OUT_CH) {
        float acc = bl[t];
        for (int k = 0; k < 64; k++) acc += s[k] * Wl[k * OUT_CH + t];
        out[g * OUT_CH + t] = acc;
    }
}

extern "C" void kernel_launch(void* const* d_in, const int* in_sizes, int n_in,
                              void* d_out, int out_size, void* d_ws, size_t ws_size,
                              hipStream_t stream) {
    const float* x    = (const float*)d_in[0];
    const int*   ei   = (const int*)d_in[1];
    const int*   batch= (const int*)d_in[2];
    const float* W1   = (const float*)d_in[3];
    const float* as1  = (const float*)d_in[4];
    const float* ad1  = (const float*)d_in[5];
    const float* b1   = (const float*)d_in[6];
    const float* W2   = (const float*)d_in[7];
    const float* as2  = (const float*)d_in[8];
    const float* ad2  = (const float*)d_in[9];
    const float* b2   = (const float*)d_in[10];
    const float* Wl   = (const float*)d_in[11];
    const float* bl   = (const float*)d_in[12];
    float* out = (float*)d_out;

    const int* src = ei;
    const int* dst = ei + N_EDGES;
    const int ETOT = N_EDGES + N_NODES;

    char* ws = (char*)d_ws;
    size_t off = 0;
    auto alloc = [&](size_t bytes) {
        void* p = ws + off;
        off = (off + bytes + 255) & ~((size_t)255);
        return p;
    };
    float*    h1   = (float*)   alloc((size_t)N_NODES * 256 * 4);
    float*    out1 = (float*)   alloc((size_t)N_NODES * 256 * 4);
    float*    h2   = (float*)   alloc((size_t)N_NODES * 64 * 4);
    float*    out2 = (float*)   alloc((size_t)N_NODES * 64 * 4);
    float*    As1  = (float*)   alloc((size_t)N_NODES * 4 * 4);
    float*    Ad1  = (float*)   alloc((size_t)N_NODES * 4 * 4);
    unsigned* M1   = (unsigned*)alloc((size_t)N_NODES * 4 * 4);
    float*    Den1 = (float*)   alloc((size_t)N_NODES * 4 * 4);
    float*    As2  = (float*)   alloc((size_t)N_NODES * 4);
    float*    Ad2  = (float*)   alloc((size_t)N_NODES * 4);
    unsigned* M2   = (unsigned*)alloc((size_t)N_NODES * 4);
    float*    Den2 = (float*)   alloc((size_t)N_NODES * 4);
    float*    pooled=(float*)   alloc((size_t)N_GRAPHS * 64 * 4);
    float*    cnt  = (float*)   alloc((size_t)N_GRAPHS * 4);

    // zero the accumulators (every call — harness does not re-poison)
    hipMemsetAsync(out1, 0, (size_t)N_NODES * 256 * 4, stream);
    hipMemsetAsync(out2, 0, (size_t)N_NODES * 64 * 4, stream);
    hipMemsetAsync(M1,   0, (size_t)N_NODES * 4 * 4, stream);
    hipMemsetAsync(Den1, 0, (size_t)N_NODES * 4 * 4, stream);
    hipMemsetAsync(M2,   0, (size_t)N_NODES * 4, stream);
    hipMemsetAsync(Den2, 0, (size_t)N_NODES * 4, stream);
    hipMemsetAsync(pooled, 0, (size_t)N_GRAPHS * 64 * 4, stream);
    hipMemsetAsync(cnt,  0, (size_t)N_GRAPHS * 4, stream);

    // ---- layer 1 ----
    gemm_k<IN_CH, 256, 16><<<N_NODES / 16, 256, 0, stream>>>(x, W1, h1, N_NODES);
    attn_k<4, 64><<<N_NODES, 256, 0, stream>>>(h1, as1, ad1, As1, Ad1);
    edge_max_k<4><<<(ETOT + 255) / 256, 256, 0, stream>>>(src, dst, As1, Ad1, M1, ETOT);
    edge_acc_k<4, 64><<<(ETOT + 3) / 4, 256, 0, stream>>>(src, dst, As1, Ad1, M1, h1, Den1, out1, ETOT);
    norm_k<4, 64><<<N_NODES, 256, 0, stream>>>(out1, Den1, b1);

    // ---- layer 2 ----
    gemm_k<256, 64, 16><<<N_NODES / 16, 64, 0, stream>>>(out1, W2, h2, N_NODES);
    attn_k<1, 64><<<N_NODES, 64, 0, stream>>>(h2, as2, ad2, As2, Ad2);
    edge_max_k<1><<<(ETOT + 255) / 256, 256, 0, stream>>>(src, dst, As2, Ad2, M2, ETOT);
    edge_acc_k<1, 64><<<(ETOT + 3) / 4, 256, 0, stream>>>(src, dst, As2, Ad2, M2, h2, Den2, out2, ETOT);
    norm_k<1, 64><<<N_NODES, 64, 0, stream>>>(out2, Den2, b2);

    // ---- pool + head ----
    pool_k<<<(N_NODES * 64 + 255) / 256, 256, 0, stream>>>(out2, batch, pooled, cnt);
    final_k<<<N_GRAPHS, 64, 0, stream>>>(pooled, cnt, Wl, bl, out);
}

// Round 2
// 915.695 us; speedup vs baseline: 1.6277x; 1.6277x over previous
//
#include <hip/hip_runtime.h>
#include <math.h>

#define N_NODES 50000
#define N_EDGES 800000
#define IN_CH 128
#define HID 64
#define HEADS 4
#define OUT_CH 10
#define N_GRAPHS 512
#define NEG_SLOPE 0.2f

// ---- simple LDS-tiled fp32 GEMM: Y[nrows,NC] = X[nrows,K] @ W[K,NC] ----
// blockDim.x must == NC
template<int K, int NC, int TM>
__global__ void gemm_k(const float* __restrict__ X, const float* __restrict__ W,
                       float* __restrict__ Y, int nrows) {
    __shared__ float xs[TM][K];
    int row0 = blockIdx.x * TM;
    for (int idx = threadIdx.x; idx < TM * K; idx += NC) {
        int r = idx / K, c = idx % K;
        int gr = row0 + r;
        xs[r][c] = (gr < nrows) ? X[(size_t)gr * K + c] : 0.f;
    }
    __syncthreads();
    int col = threadIdx.x;
    float acc[TM];
#pragma unroll
    for (int r = 0; r < TM; r++) acc[r] = 0.f;
    for (int k = 0; k < K; k++) {
        float w = W[k * NC + col];
#pragma unroll
        for (int r = 0; r < TM; r++) acc[r] += xs[r][k] * w;
    }
    for (int r = 0; r < TM; r++) {
        int gr = row0 + r;
        if (gr < nrows) Y[(size_t)gr * NC + col] = acc[r];
    }
}

// ---- per-node attention coefficients: a_s[n,h], a_d[n,h] ----
template<int H, int C>
__global__ void attn_k(const float* __restrict__ Hm,
                       const float* __restrict__ asrc, const float* __restrict__ adst,
                       float* __restrict__ As, float* __restrict__ Ad) {
    int node = blockIdx.x;
    int t = threadIdx.x;
    int hd = t / C;
    int lane = t & 63;
    float v = Hm[(size_t)node * H * C + t];
    float s = v * asrc[t];
    float d = v * adst[t];
#pragma unroll
    for (int o = 32; o > 0; o >>= 1) { s += __shfl_xor(s, o); d += __shfl_xor(d, o); }
    if (lane == 0) { As[node * H + hd] = s; Ad[node * H + hd] = d; }
}

// ---- CSR build: histogram of dst (incl. self loops) ----
__global__ void hist_k(const int* __restrict__ dst, int* __restrict__ deg, int etot) {
    int i = blockIdx.x * blockDim.x + threadIdx.x;
    if (i >= etot) return;
    int d = (i < N_EDGES) ? dst[i] : i - N_EDGES;
    atomicAdd(&deg[d], 1);
}

// ---- single-block exclusive scan of deg[n] -> rowptr[n+1] ----
__global__ void scan_k(const int* __restrict__ deg, int* __restrict__ rowptr, int n) {
    __shared__ int part[1024];
    int t = threadIdx.x;
    const int CH = (n + 1023) / 1024;
    int b = t * CH;
    int sum = 0;
    for (int i = 0; i < CH; i++) if (b + i < n) sum += deg[b + i];
    part[t] = sum;
    for (int o = 1; o < 1024; o <<= 1) {
        __syncthreads();
        int v = (t >= o) ? part[t - o] : 0;
        __syncthreads();
        part[t] += v;
    }
    __syncthreads();
    int ex = (t == 0) ? 0 : part[t - 1];
    for (int i = 0; i < CH; i++) if (b + i < n) { rowptr[b + i] = ex; ex += deg[b + i]; }
    if (t == 1023) rowptr[n] = ex;
}

// ---- scatter src ids into CSR slots ----
__global__ void scatter_k(const int* __restrict__ src, const int* __restrict__ dst,
                          const int* __restrict__ rowptr, int* __restrict__ cursor,
                          int* __restrict__ csrc, int etot) {
    int i = blockIdx.x * blockDim.x + threadIdx.x;
    if (i >= etot) return;
    int s, d;
    if (i < N_EDGES) { s = src[i]; d = dst[i]; } else { s = d = i - N_EDGES; }
    int pos = atomicAdd(&cursor[d], 1);
    csrc[rowptr[d] + pos] = s;
}

// ---- fused per-(node,head) aggregation: max, denom, weighted gather, norm+bias+ELU ----
// one 64-lane wave per (node,head); blockDim = 256
template<int H, int C>
__global__ void agg_k(const int* __restrict__ rowptr, const int* __restrict__ csrc,
                      const float* __restrict__ As, const float* __restrict__ Ad,
                      const float* __restrict__ Hm, const float* __restrict__ bias,
                      float* __restrict__ Out, int nnodes) {
    int lane = threadIdx.x & 63;
    int gw = blockIdx.x * (blockDim.x >> 6) + (threadIdx.x >> 6);
    int node = gw / H, h = gw % H;
    if (node >= nnodes) return;
    int beg = rowptr[node], end = rowptr[node + 1];
    float ad = Ad[node * H + h];
    // pass 1: segment max (lane-parallel over edges)
    float m = -INFINITY;
    for (int j = beg + lane; j < end; j += 64) {
        float e = As[csrc[j] * H + h] + ad;
        e = e > 0.f ? e : NEG_SLOPE * e;
        m = fmaxf(m, e);
    }
#pragma unroll
    for (int o = 32; o > 0; o >>= 1) m = fmaxf(m, __shfl_xor(m, o));
    // pass 2: denom
    float den = 0.f;
    for (int j = beg + lane; j < end; j += 64) {
        float e = As[csrc[j] * H + h] + ad;
        e = e > 0.f ? e : NEG_SLOPE * e;
        den += expf(e - m);
    }
#pragma unroll
    for (int o = 32; o > 0; o >>= 1) den += __shfl_xor(den, o);
    float inv = 1.f / den;
    // pass 3: weighted gather (lane = channel, serial over edges)
    float acc = 0.f;
    for (int j = beg; j < end; j++) {
        int s = csrc[j];
        float e = As[s * H + h] + ad;
        e = e > 0.f ? e : NEG_SLOPE * e;
        float a = expf(e - m) * inv;
        acc += a * Hm[((size_t)s * H + h) * C + lane];
    }
    float v = acc + bias[h * C + lane];
    v = v > 0.f ? v : expm1f(v);
    Out[((size_t)node * H + h) * C + lane] = v;
}

// ---- global mean pool (accumulate) ----
__global__ void pool_k(const float* __restrict__ Out2, const int* __restrict__ batch,
                       float* __restrict__ pooled, float* __restrict__ cnt) {
    int i = blockIdx.x * blockDim.x + threadIdx.x;
    if (i >= N_NODES * 64) return;
    int node = i >> 6, c = i & 63;
    int g = batch[node];
    atomicAdd(&pooled[g * 64 + c], Out2[i]);
    if (c == 0) atomicAdd(&cnt[g], 1.f);
}

// ---- final: out[g,:] = (pooled[g,:]/cnt) @ Wl + bl ----
__global__ void final_k(const float* __restrict__ pooled, const float* __restrict__ cnt,
                        const float* __restrict__ Wl, const float* __restrict__ bl,
                        float* __restrict__ out) {
    int g = blockIdx.x;
    int t = threadIdx.x;  // 64
    __shared__ float s[64];
    float c = cnt[g];
    c = c > 1.f ? c : 1.f;
    s[t] = pooled[g * 64 + t] / c;
    __syncthreads();
    if (t < OUT_CH) {
        float acc = bl[t];
        for (int k = 0; k < 64; k++) acc += s[k] * Wl[k * OUT_CH + t];
        out[g * OUT_CH + t] = acc;
    }
}

extern "C" void kernel_launch(void* const* d_in, const int* in_sizes, int n_in,
                              void* d_out, int out_size, void* d_ws, size_t ws_size,
                              hipStream_t stream) {
    const float* x    = (const float*)d_in[0];
    const int*   ei   = (const int*)d_in[1];
    const int*   batch= (const int*)d_in[2];
    const float* W1   = (const float*)d_in[3];
    const float* as1  = (const float*)d_in[4];
    const float* ad1  = (const float*)d_in[5];
    const float* b1   = (const float*)d_in[6];
    const float* W2   = (const float*)d_in[7];
    const float* as2  = (const float*)d_in[8];
    const float* ad2  = (const float*)d_in[9];
    const float* b2   = (const float*)d_in[10];
    const float* Wl   = (const float*)d_in[11];
    const float* bl   = (const float*)d_in[12];
    float* out = (float*)d_out;

    const int* src = ei;
    const int* dst = ei + N_EDGES;
    const int ETOT = N_EDGES + N_NODES;

    char* ws = (char*)d_ws;
    size_t off = 0;
    auto alloc = [&](size_t bytes) {
        void* p = ws + off;
        off = (off + bytes + 255) & ~((size_t)255);
        return p;
    };
    float* h1     = (float*)alloc((size_t)N_NODES * 256 * 4);
    float* out1   = (float*)alloc((size_t)N_NODES * 256 * 4);
    float* h2     = (float*)alloc((size_t)N_NODES * 64 * 4);
    float* out2   = (float*)alloc((size_t)N_NODES * 64 * 4);
    float* As1    = (float*)alloc((size_t)N_NODES * 4 * 4);
    float* Ad1    = (float*)alloc((size_t)N_NODES * 4 * 4);
    float* As2    = (float*)alloc((size_t)N_NODES * 4);
    float* Ad2    = (float*)alloc((size_t)N_NODES * 4);
    int*   deg    = (int*)  alloc((size_t)N_NODES * 4);
    int*   rowptr = (int*)  alloc((size_t)(N_NODES + 1) * 4);
    int*   cursor = (int*)  alloc((size_t)N_NODES * 4);
    int*   csrc   = (int*)  alloc((size_t)ETOT * 4);
    float* pooled = (float*)alloc((size_t)N_GRAPHS * 64 * 4);
    float* cnt    = (float*)alloc((size_t)N_GRAPHS * 4);

    // zero accumulators (every call — harness does not re-poison)
    hipMemsetAsync(deg,    0, (size_t)N_NODES * 4, stream);
    hipMemsetAsync(cursor, 0, (size_t)N_NODES * 4, stream);
    hipMemsetAsync(pooled, 0, (size_t)N_GRAPHS * 64 * 4, stream);
    hipMemsetAsync(cnt,    0, (size_t)N_GRAPHS * 4, stream);

    // ---- CSR build (shared by both layers) ----
    hist_k<<<(ETOT + 255) / 256, 256, 0, stream>>>(dst, deg, ETOT);
    scan_k<<<1, 1024, 0, stream>>>(deg, rowptr, N_NODES);
    scatter_k<<<(ETOT + 255) / 256, 256, 0, stream>>>(src, dst, rowptr, cursor, csrc, ETOT);

    // ---- layer 1 ----
    gemm_k<IN_CH, 256, 16><<<N_NODES / 16, 256, 0, stream>>>(x, W1, h1, N_NODES);
    attn_k<4, 64><<<N_NODES, 256, 0, stream>>>(h1, as1, ad1, As1, Ad1);
    agg_k<4, 64><<<(N_NODES * 4 + 3) / 4, 256, 0, stream>>>(rowptr, csrc, As1, Ad1, h1, b1, out1, N_NODES);

    // ---- layer 2 ----
    gemm_k<256, 64, 16><<<N_NODES / 16, 64, 0, stream>>>(out1, W2, h2, N_NODES);
    attn_k<1, 64><<<N_NODES, 64, 0, stream>>>(h2, as2, ad2, As2, Ad2);
    agg_k<1, 64><<<(N_NODES + 3) / 4, 256, 0, stream>>>(rowptr, csrc, As2, Ad2, h2, b2, out2, N_NODES);

    // ---- pool + head ----
    pool_k<<<(N_NODES * 64 + 255) / 256, 256, 0, stream>>>(out2, batch, pooled, cnt);
    final_k<<<N_GRAPHS, 64, 0, stream>>>(pooled, cnt, Wl, bl, out);
}

// Round 3
// 724.438 us; speedup vs baseline: 2.0575x; 1.2640x over previous
//
#include <hip/hip_runtime.h>
#include <math.h>

#define N_NODES 50000
#define N_EDGES 800000
#define IN_CH 128
#define HID 64
#define HEADS 4
#define OUT_CH 10
#define N_GRAPHS 512
#define NEG_SLOPE 0.2f

// ---- simple LDS-tiled fp32 GEMM: Y[nrows,NC] = X[nrows,K] @ W[K,NC] ----
template<int K, int NC, int TM>
__global__ void gemm_k(const float* __restrict__ X, const float* __restrict__ W,
                       float* __restrict__ Y, int nrows) {
    __shared__ float xs[TM][K];
    int row0 = blockIdx.x * TM;
    for (int idx = threadIdx.x; idx < TM * K; idx += NC) {
        int r = idx / K, c = idx % K;
        int gr = row0 + r;
        xs[r][c] = (gr < nrows) ? X[(size_t)gr * K + c] : 0.f;
    }
    __syncthreads();
    int col = threadIdx.x;
    float acc[TM];
#pragma unroll
    for (int r = 0; r < TM; r++) acc[r] = 0.f;
    for (int k = 0; k < K; k++) {
        float w = W[k * NC + col];
#pragma unroll
        for (int r = 0; r < TM; r++) acc[r] += xs[r][k] * w;
    }
    for (int r = 0; r < TM; r++) {
        int gr = row0 + r;
        if (gr < nrows) Y[(size_t)gr * NC + col] = acc[r];
    }
}

// ---- per-node attention coefficients: a_s[n,h], a_d[n,h] ----
template<int H, int C>
__global__ void attn_k(const float* __restrict__ Hm,
                       const float* __restrict__ asrc, const float* __restrict__ adst,
                       float* __restrict__ As, float* __restrict__ Ad) {
    int node = blockIdx.x;
    int t = threadIdx.x;
    int hd = t / C;
    int lane = t & 63;
    float v = Hm[(size_t)node * H * C + t];
    float s = v * asrc[t];
    float d = v * adst[t];
#pragma unroll
    for (int o = 32; o > 0; o >>= 1) { s += __shfl_xor(s, o); d += __shfl_xor(d, o); }
    if (lane == 0) { As[node * H + hd] = s; Ad[node * H + hd] = d; }
}

// ---- CSR build: histogram of dst (incl. self loops) ----
__global__ void hist_k(const int* __restrict__ dst, int* __restrict__ deg, int etot) {
    int i = blockIdx.x * blockDim.x + threadIdx.x;
    if (i >= etot) return;
    int d = (i < N_EDGES) ? dst[i] : i - N_EDGES;
    atomicAdd(&deg[d], 1);
}

// ---- single-block exclusive scan of deg[n] -> rowptr[n+1] ----
__global__ void scan_k(const int* __restrict__ deg, int* __restrict__ rowptr, int n) {
    __shared__ int part[1024];
    int t = threadIdx.x;
    const int CH = (n + 1023) / 1024;
    int b = t * CH;
    int sum = 0;
    for (int i = 0; i < CH; i++) if (b + i < n) sum += deg[b + i];
    part[t] = sum;
    for (int o = 1; o < 1024; o <<= 1) {
        __syncthreads();
        int v = (t >= o) ? part[t - o] : 0;
        __syncthreads();
        part[t] += v;
    }
    __syncthreads();
    int ex = (t == 0) ? 0 : part[t - 1];
    for (int i = 0; i < CH; i++) if (b + i < n) { rowptr[b + i] = ex; ex += deg[b + i]; }
    if (t == 1023) rowptr[n] = ex;
}

// ---- scatter src AND dst ids into CSR slots ----
__global__ void scatter_k(const int* __restrict__ src, const int* __restrict__ dst,
                          const int* __restrict__ rowptr, int* __restrict__ cursor,
                          int* __restrict__ csrc, int* __restrict__ cdst, int etot) {
    int i = blockIdx.x * blockDim.x + threadIdx.x;
    if (i >= etot) return;
    int s, d;
    if (i < N_EDGES) { s = src[i]; d = dst[i]; } else { s = d = i - N_EDGES; }
    int pos = rowptr[d] + atomicAdd(&cursor[d], 1);
    csrc[pos] = s;
    cdst[pos] = d;
}

// ---- per-edge raw attention logits into head-planes: E[h*ETOT + j] ----
template<int H>
__global__ void edge_e_k(const int* __restrict__ csrc, const int* __restrict__ cdst,
                         const float* __restrict__ As, const float* __restrict__ Ad,
                         float* __restrict__ E, int etot) {
    int j = blockIdx.x * blockDim.x + threadIdx.x;
    if (j >= etot) return;
    int s = csrc[j], d = cdst[j];
    if (H == 4) {
        float4 a = *(const float4*)&As[s * 4];
        float4 b = *(const float4*)&Ad[d * 4];
        float e0 = a.x + b.x, e1 = a.y + b.y, e2 = a.z + b.z, e3 = a.w + b.w;
        E[0 * (size_t)etot + j] = e0 > 0.f ? e0 : NEG_SLOPE * e0;
        E[1 * (size_t)etot + j] = e1 > 0.f ? e1 : NEG_SLOPE * e1;
        E[2 * (size_t)etot + j] = e2 > 0.f ? e2 : NEG_SLOPE * e2;
        E[3 * (size_t)etot + j] = e3 > 0.f ? e3 : NEG_SLOPE * e3;
    } else {
        float e = As[s] + Ad[d];
        E[j] = e > 0.f ? e : NEG_SLOPE * e;
    }
}

// ---- segment softmax in CSR order: overwrite E plane with alpha ----
// one wave per (node,head); blockDim = 256
template<int H>
__global__ void softmax_k(const int* __restrict__ rowptr, float* __restrict__ E,
                          int etot, int nnodes) {
    int lane = threadIdx.x & 63;
    int gw = blockIdx.x * (blockDim.x >> 6) + (threadIdx.x >> 6);
    int node = gw / H, h = gw % H;
    if (node >= nnodes) return;
    int beg = rowptr[node], end = rowptr[node + 1];
    float* ep = E + (size_t)h * etot;
    int deg = end - beg;
    if (deg <= 64) {
        int j = beg + lane;
        float v = (j < end) ? ep[j] : -INFINITY;
        float m = v;
#pragma unroll
        for (int o = 32; o > 0; o >>= 1) m = fmaxf(m, __shfl_xor(m, o));
        float ex = (j < end) ? __expf(v - m) : 0.f;
        float den = ex;
#pragma unroll
        for (int o = 32; o > 0; o >>= 1) den += __shfl_xor(den, o);
        if (j < end) ep[j] = ex / den;
    } else {
        float m = -INFINITY;
        for (int j = beg + lane; j < end; j += 64) m = fmaxf(m, ep[j]);
#pragma unroll
        for (int o = 32; o > 0; o >>= 1) m = fmaxf(m, __shfl_xor(m, o));
        float den = 0.f;
        for (int j = beg + lane; j < end; j += 64) den += __expf(ep[j] - m);
#pragma unroll
        for (int o = 32; o > 0; o >>= 1) den += __shfl_xor(den, o);
        for (int j = beg + lane; j < end; j += 64) ep[j] = __expf(ep[j] - m) / den;
    }
}

// ---- weighted gather + bias + ELU: one wave per (node,head), lane = channel ----
template<int H, int C>
__global__ void gather_k(const int* __restrict__ rowptr, const int* __restrict__ csrc,
                         const float* __restrict__ Alpha, const float* __restrict__ Hm,
                         const float* __restrict__ bias, float* __restrict__ Out,
                         int etot, int nnodes) {
    int c = threadIdx.x & 63;
    int gw = blockIdx.x * (blockDim.x >> 6) + (threadIdx.x >> 6);
    int node = gw / H, h = gw % H;
    if (node >= nnodes) return;
    int beg = rowptr[node], end = rowptr[node + 1];
    const float* al = Alpha + (size_t)h * etot;
    float acc = 0.f;
    int j = beg;
    for (; j + 4 <= end; j += 4) {
        int s0 = csrc[j], s1 = csrc[j + 1], s2 = csrc[j + 2], s3 = csrc[j + 3];
        float a0 = al[j], a1 = al[j + 1], a2 = al[j + 2], a3 = al[j + 3];
        float v0 = Hm[((size_t)s0 * H + h) * C + c];
        float v1 = Hm[((size_t)s1 * H + h) * C + c];
        float v2 = Hm[((size_t)s2 * H + h) * C + c];
        float v3 = Hm[((size_t)s3 * H + h) * C + c];
        acc += a0 * v0 + a1 * v1 + a2 * v2 + a3 * v3;
    }
    for (; j < end; j++) {
        acc += al[j] * Hm[((size_t)csrc[j] * H + h) * C + c];
    }
    float v = acc + bias[h * C + c];
    v = v > 0.f ? v : expm1f(v);
    Out[((size_t)node * H + h) * C + c] = v;
}

// ---- global mean pool (accumulate) ----
__global__ void pool_k(const float* __restrict__ Out2, const int* __restrict__ batch,
                       float* __restrict__ pooled, float* __restrict__ cnt) {
    int i = blockIdx.x * blockDim.x + threadIdx.x;
    if (i >= N_NODES * 64) return;
    int node = i >> 6, c = i & 63;
    int g = batch[node];
    atomicAdd(&pooled[g * 64 + c], Out2[i]);
    if (c == 0) atomicAdd(&cnt[g], 1.f);
}

// ---- final: out[g,:] = (pooled[g,:]/cnt) @ Wl + bl ----
__global__ void final_k(const float* __restrict__ pooled, const float* __restrict__ cnt,
                        const float* __restrict__ Wl, const float* __restrict__ bl,
                        float* __restrict__ out) {
    int g = blockIdx.x;
    int t = threadIdx.x;  // 64
    __shared__ float s[64];
    float c = cnt[g];
    c = c > 1.f ? c : 1.f;
    s[t] = pooled[g * 64 + t] / c;
    __syncthreads();
    if (t < OUT_CH) {
        float acc = bl[t];
        for (int k = 0; k < 64; k++) acc += s[k] * Wl[k * OUT_CH + t];
        out[g * OUT_CH + t] = acc;
    }
}

extern "C" void kernel_launch(void* const* d_in, const int* in_sizes, int n_in,
                              void* d_out, int out_size, void* d_ws, size_t ws_size,
                              hipStream_t stream) {
    const float* x    = (const float*)d_in[0];
    const int*   ei   = (const int*)d_in[1];
    const int*   batch= (const int*)d_in[2];
    const float* W1   = (const float*)d_in[3];
    const float* as1  = (const float*)d_in[4];
    const float* ad1  = (const float*)d_in[5];
    const float* b1   = (const float*)d_in[6];
    const float* W2   = (const float*)d_in[7];
    const float* as2  = (const float*)d_in[8];
    const float* ad2  = (const float*)d_in[9];
    const float* b2   = (const float*)d_in[10];
    const float* Wl   = (const float*)d_in[11];
    const float* bl   = (const float*)d_in[12];
    float* out = (float*)d_out;

    const int* src = ei;
    const int* dst = ei + N_EDGES;
    const int ETOT = N_EDGES + N_NODES;

    char* ws = (char*)d_ws;
    size_t off = 0;
    auto alloc = [&](size_t bytes) {
        void* p = ws + off;
        off = (off + bytes + 255) & ~((size_t)255);
        return p;
    };
    float* h1     = (float*)alloc((size_t)N_NODES * 256 * 4);
    float* out1   = (float*)alloc((size_t)N_NODES * 256 * 4);
    float* h2     = (float*)alloc((size_t)N_NODES * 64 * 4);
    float* out2   = (float*)alloc((size_t)N_NODES * 64 * 4);
    float* As1    = (float*)alloc((size_t)N_NODES * 4 * 4);
    float* Ad1    = (float*)alloc((size_t)N_NODES * 4 * 4);
    float* As2    = (float*)alloc((size_t)N_NODES * 4);
    float* Ad2    = (float*)alloc((size_t)N_NODES * 4);
    int*   deg    = (int*)  alloc((size_t)N_NODES * 4);
    int*   rowptr = (int*)  alloc((size_t)(N_NODES + 1) * 4);
    int*   cursor = (int*)  alloc((size_t)N_NODES * 4);
    int*   csrc   = (int*)  alloc((size_t)ETOT * 4);
    int*   cdst   = (int*)  alloc((size_t)ETOT * 4);
    float* E      = (float*)alloc((size_t)ETOT * HEADS * 4);  // reused by layer 2 (H=1)
    float* pooled = (float*)alloc((size_t)N_GRAPHS * 64 * 4);
    float* cnt    = (float*)alloc((size_t)N_GRAPHS * 4);

    // zero accumulators (every call — harness does not re-poison)
    hipMemsetAsync(deg,    0, (size_t)N_NODES * 4, stream);
    hipMemsetAsync(cursor, 0, (size_t)N_NODES * 4, stream);
    hipMemsetAsync(pooled, 0, (size_t)N_GRAPHS * 64 * 4, stream);
    hipMemsetAsync(cnt,    0, (size_t)N_GRAPHS * 4, stream);

    // ---- CSR build (shared by both layers) ----
    hist_k<<<(ETOT + 255) / 256, 256, 0, stream>>>(dst, deg, ETOT);
    scan_k<<<1, 1024, 0, stream>>>(deg, rowptr, N_NODES);
    scatter_k<<<(ETOT + 255) / 256, 256, 0, stream>>>(src, dst, rowptr, cursor, csrc, cdst, ETOT);

    // ---- layer 1 (H=4) ----
    gemm_k<IN_CH, 256, 16><<<N_NODES / 16, 256, 0, stream>>>(x, W1, h1, N_NODES);
    attn_k<4, 64><<<N_NODES, 256, 0, stream>>>(h1, as1, ad1, As1, Ad1);
    edge_e_k<4><<<(ETOT + 255) / 256, 256, 0, stream>>>(csrc, cdst, As1, Ad1, E, ETOT);
    softmax_k<4><<<(N_NODES * 4 + 3) / 4, 256, 0, stream>>>(rowptr, E, ETOT, N_NODES);
    gather_k<4, 64><<<(N_NODES * 4 + 3) / 4, 256, 0, stream>>>(rowptr, csrc, E, h1, b1, out1, ETOT, N_NODES);

    // ---- layer 2 (H=1) ----
    gemm_k<256, 64, 16><<<N_NODES / 16, 64, 0, stream>>>(out1, W2, h2, N_NODES);
    attn_k<1, 64><<<N_NODES, 64, 0, stream>>>(h2, as2, ad2, As2, Ad2);
    edge_e_k<1><<<(ETOT + 255) / 256, 256, 0, stream>>>(csrc, cdst, As2, Ad2, E, ETOT);
    softmax_k<1><<<(N_NODES + 3) / 4, 256, 0, stream>>>(rowptr, E, ETOT, N_NODES);
    gather_k<1, 64><<<(N_NODES + 3) / 4, 256, 0, stream>>>(rowptr, csrc, E, h2, b2, out2, ETOT, N_NODES);

    // ---- pool + head ----
    pool_k<<<(N_NODES * 64 + 255) / 256, 256, 0, stream>>>(out2, batch, pooled, cnt);
    final_k<<<N_GRAPHS, 64, 0, stream>>>(pooled, cnt, Wl, bl, out);
}

// Round 4
// 698.462 us; speedup vs baseline: 2.1340x; 1.0372x over previous
//
#include <hip/hip_runtime.h>
#include <math.h>

#define N_NODES 50000
#define N_EDGES 800000
#define IN_CH 128
#define HID 64
#define HEADS 4
#define OUT_CH 10
#define N_GRAPHS 512
#define NEG_SLOPE 0.2f

// ---- register-tiled fp32 GEMM: Y[M,N] = X[M,K] @ W[K,N] ----
// grid: (ceil(M/BM), N/BN); block: (BM/TM)*(BN/TN) == 256 threads
// X staged transposed in LDS so compute reads are ds_read_b128.
template<int BM, int BN, int BK, int TM, int TN, int K, int N>
__global__ __launch_bounds__(256) void rt_gemm(const float* __restrict__ X,
                                               const float* __restrict__ W,
                                               float* __restrict__ Y, int M) {
    __shared__ float xs[BK][BM + 4];   // transposed: xs[k][row]
    __shared__ float ws[BK][BN];
    const int t = threadIdx.x;
    const int row0 = blockIdx.x * BM;
    const int cb0 = blockIdx.y * BN;
    const int ty = t / (BN / TN);
    const int tx = t % (BN / TN);

    float acc[TM][TN];
#pragma unroll
    for (int i = 0; i < TM; i++)
#pragma unroll
        for (int j = 0; j < TN; j++) acc[i][j] = 0.f;

    const int XV = BM * BK / 4;   // float4 slots of X tile
    const int WV = BK * BN / 4;

    for (int k0 = 0; k0 < K; k0 += BK) {
        // stage X (transposed)
#pragma unroll
        for (int s = t; s < XV; s += 256) {
            int row = s / (BK / 4);
            int kc = s % (BK / 4);
            int gr = row0 + row;
            float4 v = make_float4(0.f, 0.f, 0.f, 0.f);
            if (gr < M) v = *(const float4*)&X[(size_t)gr * K + k0 + kc * 4];
            xs[kc * 4 + 0][row] = v.x;
            xs[kc * 4 + 1][row] = v.y;
            xs[kc * 4 + 2][row] = v.z;
            xs[kc * 4 + 3][row] = v.w;
        }
        // stage W (as-is)
#pragma unroll
        for (int s = t; s < WV; s += 256) {
            int kr = s / (BN / 4);
            int c4 = s % (BN / 4);
            *(float4*)&ws[kr][c4 * 4] = *(const float4*)&W[(size_t)(k0 + kr) * N + cb0 + c4 * 4];
        }
        __syncthreads();

#pragma unroll
        for (int k = 0; k < BK; k++) {
            float xv[TM], wv[TN];
#pragma unroll
            for (int i = 0; i < TM / 4; i++)
                *(float4*)&xv[i * 4] = *(const float4*)&xs[k][ty * TM + i * 4];
#pragma unroll
            for (int j = 0; j < TN / 4; j++)
                *(float4*)&wv[j * 4] = *(const float4*)&ws[k][tx * TN + j * 4];
#pragma unroll
            for (int i = 0; i < TM; i++)
#pragma unroll
                for (int j = 0; j < TN; j++) acc[i][j] += xv[i] * wv[j];
        }
        __syncthreads();
    }

#pragma unroll
    for (int i = 0; i < TM; i++) {
        int gr = row0 + ty * TM + i;
        if (gr < M) {
#pragma unroll
            for (int j4 = 0; j4 < TN / 4; j4++) {
                float4 v = make_float4(acc[i][j4 * 4], acc[i][j4 * 4 + 1],
                                       acc[i][j4 * 4 + 2], acc[i][j4 * 4 + 3]);
                *(float4*)&Y[(size_t)gr * N + cb0 + tx * TN + j4 * 4] = v;
            }
        }
    }
}

// ---- per-node attention coefficients: a_s[n,h], a_d[n,h] ----
template<int H, int C>
__global__ void attn_k(const float* __restrict__ Hm,
                       const float* __restrict__ asrc, const float* __restrict__ adst,
                       float* __restrict__ As, float* __restrict__ Ad) {
    int node = blockIdx.x;
    int t = threadIdx.x;
    int hd = t / C;
    int lane = t & 63;
    float v = Hm[(size_t)node * H * C + t];
    float s = v * asrc[t];
    float d = v * adst[t];
#pragma unroll
    for (int o = 32; o > 0; o >>= 1) { s += __shfl_xor(s, o); d += __shfl_xor(d, o); }
    if (lane == 0) { As[node * H + hd] = s; Ad[node * H + hd] = d; }
}

// ---- CSR build: histogram of dst (incl. self loops) ----
__global__ void hist_k(const int* __restrict__ dst, int* __restrict__ deg, int etot) {
    int i = blockIdx.x * blockDim.x + threadIdx.x;
    if (i >= etot) return;
    int d = (i < N_EDGES) ? dst[i] : i - N_EDGES;
    atomicAdd(&deg[d], 1);
}

// ---- single-block exclusive scan of deg[n] -> rowptr[n+1] ----
__global__ void scan_k(const int* __restrict__ deg, int* __restrict__ rowptr, int n) {
    __shared__ int part[1024];
    int t = threadIdx.x;
    const int CH = (n + 1023) / 1024;
    int b = t * CH;
    int sum = 0;
    for (int i = 0; i < CH; i++) if (b + i < n) sum += deg[b + i];
    part[t] = sum;
    for (int o = 1; o < 1024; o <<= 1) {
        __syncthreads();
        int v = (t >= o) ? part[t - o] : 0;
        __syncthreads();
        part[t] += v;
    }
    __syncthreads();
    int ex = (t == 0) ? 0 : part[t - 1];
    for (int i = 0; i < CH; i++) if (b + i < n) { rowptr[b + i] = ex; ex += deg[b + i]; }
    if (t == 1023) rowptr[n] = ex;
}

// ---- scatter src AND dst ids into CSR slots ----
__global__ void scatter_k(const int* __restrict__ src, const int* __restrict__ dst,
                          const int* __restrict__ rowptr, int* __restrict__ cursor,
                          int* __restrict__ csrc, int* __restrict__ cdst, int etot) {
    int i = blockIdx.x * blockDim.x + threadIdx.x;
    if (i >= etot) return;
    int s, d;
    if (i < N_EDGES) { s = src[i]; d = dst[i]; } else { s = d = i - N_EDGES; }
    int pos = rowptr[d] + atomicAdd(&cursor[d], 1);
    csrc[pos] = s;
    cdst[pos] = d;
}

// ---- per-edge raw attention logits into head-planes: E[h*ETOT + j] ----
template<int H>
__global__ void edge_e_k(const int* __restrict__ csrc, const int* __restrict__ cdst,
                         const float* __restrict__ As, const float* __restrict__ Ad,
                         float* __restrict__ E, int etot) {
    int j = blockIdx.x * blockDim.x + threadIdx.x;
    if (j >= etot) return;
    int s = csrc[j], d = cdst[j];
    if (H == 4) {
        float4 a = *(const float4*)&As[s * 4];
        float4 b = *(const float4*)&Ad[d * 4];
        float e0 = a.x + b.x, e1 = a.y + b.y, e2 = a.z + b.z, e3 = a.w + b.w;
        E[0 * (size_t)etot + j] = e0 > 0.f ? e0 : NEG_SLOPE * e0;
        E[1 * (size_t)etot + j] = e1 > 0.f ? e1 : NEG_SLOPE * e1;
        E[2 * (size_t)etot + j] = e2 > 0.f ? e2 : NEG_SLOPE * e2;
        E[3 * (size_t)etot + j] = e3 > 0.f ? e3 : NEG_SLOPE * e3;
    } else {
        float e = As[s] + Ad[d];
        E[j] = e > 0.f ? e : NEG_SLOPE * e;
    }
}

// ---- segment softmax in CSR order: overwrite E plane with alpha ----
template<int H>
__global__ void softmax_k(const int* __restrict__ rowptr, float* __restrict__ E,
                          int etot, int nnodes) {
    int lane = threadIdx.x & 63;
    int gw = blockIdx.x * (blockDim.x >> 6) + (threadIdx.x >> 6);
    int node = gw / H, h = gw % H;
    if (node >= nnodes) return;
    int beg = rowptr[node], end = rowptr[node + 1];
    float* ep = E + (size_t)h * etot;
    int deg = end - beg;
    if (deg <= 64) {
        int j = beg + lane;
        float v = (j < end) ? ep[j] : -INFINITY;
        float m = v;
#pragma unroll
        for (int o = 32; o > 0; o >>= 1) m = fmaxf(m, __shfl_xor(m, o));
        float ex = (j < end) ? __expf(v - m) : 0.f;
        float den = ex;
#pragma unroll
        for (int o = 32; o > 0; o >>= 1) den += __shfl_xor(den, o);
        if (j < end) ep[j] = ex / den;
    } else {
        float m = -INFINITY;
        for (int j = beg + lane; j < end; j += 64) m = fmaxf(m, ep[j]);
#pragma unroll
        for (int o = 32; o > 0; o >>= 1) m = fmaxf(m, __shfl_xor(m, o));
        float den = 0.f;
        for (int j = beg + lane; j < end; j += 64) den += __expf(ep[j] - m);
#pragma unroll
        for (int o = 32; o > 0; o >>= 1) den += __shfl_xor(den, o);
        for (int j = beg + lane; j < end; j += 64) ep[j] = __expf(ep[j] - m) / den;
    }
}

// ---- weighted gather + bias + ELU: one wave per (node,head), lane = channel ----
template<int H, int C>
__global__ void gather_k(const int* __restrict__ rowptr, const int* __restrict__ csrc,
                         const float* __restrict__ Alpha, const float* __restrict__ Hm,
                         const float* __restrict__ bias, float* __restrict__ Out,
                         int etot, int nnodes) {
    int c = threadIdx.x & 63;
    int gw = blockIdx.x * (blockDim.x >> 6) + (threadIdx.x >> 6);
    int node = gw / H, h = gw % H;
    if (node >= nnodes) return;
    int beg = rowptr[node], end = rowptr[node + 1];
    const float* al = Alpha + (size_t)h * etot;
    float acc = 0.f;
    int j = beg;
    for (; j + 4 <= end; j += 4) {
        int s0 = csrc[j], s1 = csrc[j + 1], s2 = csrc[j + 2], s3 = csrc[j + 3];
        float a0 = al[j], a1 = al[j + 1], a2 = al[j + 2], a3 = al[j + 3];
        float v0 = Hm[((size_t)s0 * H + h) * C + c];
        float v1 = Hm[((size_t)s1 * H + h) * C + c];
        float v2 = Hm[((size_t)s2 * H + h) * C + c];
        float v3 = Hm[((size_t)s3 * H + h) * C + c];
        acc += a0 * v0 + a1 * v1 + a2 * v2 + a3 * v3;
    }
    for (; j < end; j++) {
        acc += al[j] * Hm[((size_t)csrc[j] * H + h) * C + c];
    }
    float v = acc + bias[h * C + c];
    v = v > 0.f ? v : expm1f(v);
    Out[((size_t)node * H + h) * C + c] = v;
}

// ---- global mean pool (accumulate) ----
__global__ void pool_k(const float* __restrict__ Out2, const int* __restrict__ batch,
                       float* __restrict__ pooled, float* __restrict__ cnt) {
    int i = blockIdx.x * blockDim.x + threadIdx.x;
    if (i >= N_NODES * 64) return;
    int node = i >> 6, c = i & 63;
    int g = batch[node];
    atomicAdd(&pooled[g * 64 + c], Out2[i]);
    if (c == 0) atomicAdd(&cnt[g], 1.f);
}

// ---- final: out[g,:] = (pooled[g,:]/cnt) @ Wl + bl ----
__global__ void final_k(const float* __restrict__ pooled, const float* __restrict__ cnt,
                        const float* __restrict__ Wl, const float* __restrict__ bl,
                        float* __restrict__ out) {
    int g = blockIdx.x;
    int t = threadIdx.x;  // 64
    __shared__ float s[64];
    float c = cnt[g];
    c = c > 1.f ? c : 1.f;
    s[t] = pooled[g * 64 + t] / c;
    __syncthreads();
    if (t < OUT_CH) {
        float acc = bl[t];
        for (int k = 0; k < 64; k++) acc += s[k] * Wl[k * OUT_CH + t];
        out[g * OUT_CH + t] = acc;
    }
}

extern "C" void kernel_launch(void* const* d_in, const int* in_sizes, int n_in,
                              void* d_out, int out_size, void* d_ws, size_t ws_size,
                              hipStream_t stream) {
    const float* x    = (const float*)d_in[0];
    const int*   ei   = (const int*)d_in[1];
    const int*   batch= (const int*)d_in[2];
    const float* W1   = (const float*)d_in[3];
    const float* as1  = (const float*)d_in[4];
    const float* ad1  = (const float*)d_in[5];
    const float* b1   = (const float*)d_in[6];
    const float* W2   = (const float*)d_in[7];
    const float* as2  = (const float*)d_in[8];
    const float* ad2  = (const float*)d_in[9];
    const float* b2   = (const float*)d_in[10];
    const float* Wl   = (const float*)d_in[11];
    const float* bl   = (const float*)d_in[12];
    float* out = (float*)d_out;

    const int* src = ei;
    const int* dst = ei + N_EDGES;
    const int ETOT = N_EDGES + N_NODES;

    char* ws = (char*)d_ws;
    size_t off = 0;
    auto alloc = [&](size_t bytes) {
        void* p = ws + off;
        off = (off + bytes + 255) & ~((size_t)255);
        return p;
    };
    float* h1     = (float*)alloc((size_t)N_NODES * 256 * 4);
    float* out1   = (float*)alloc((size_t)N_NODES * 256 * 4);
    float* h2     = (float*)alloc((size_t)N_NODES * 64 * 4);
    float* out2   = (float*)alloc((size_t)N_NODES * 64 * 4);
    float* As1    = (float*)alloc((size_t)N_NODES * 4 * 4);
    float* Ad1    = (float*)alloc((size_t)N_NODES * 4 * 4);
    float* As2    = (float*)alloc((size_t)N_NODES * 4);
    float* Ad2    = (float*)alloc((size_t)N_NODES * 4);
    int*   deg    = (int*)  alloc((size_t)N_NODES * 4);
    int*   rowptr = (int*)  alloc((size_t)(N_NODES + 1) * 4);
    int*   cursor = (int*)  alloc((size_t)N_NODES * 4);
    int*   csrc   = (int*)  alloc((size_t)ETOT * 4);
    int*   cdst   = (int*)  alloc((size_t)ETOT * 4);
    float* E      = (float*)alloc((size_t)ETOT * HEADS * 4);  // reused by layer 2 (H=1)
    float* pooled = (float*)alloc((size_t)N_GRAPHS * 64 * 4);
    float* cnt    = (float*)alloc((size_t)N_GRAPHS * 4);

    // zero accumulators (every call — harness does not re-poison)
    hipMemsetAsync(deg,    0, (size_t)N_NODES * 4, stream);
    hipMemsetAsync(cursor, 0, (size_t)N_NODES * 4, stream);
    hipMemsetAsync(pooled, 0, (size_t)N_GRAPHS * 64 * 4, stream);
    hipMemsetAsync(cnt,    0, (size_t)N_GRAPHS * 4, stream);

    // ---- CSR build (shared by both layers) ----
    hist_k<<<(ETOT + 255) / 256, 256, 0, stream>>>(dst, deg, ETOT);
    scan_k<<<1, 1024, 0, stream>>>(deg, rowptr, N_NODES);
    scatter_k<<<(ETOT + 255) / 256, 256, 0, stream>>>(src, dst, rowptr, cursor, csrc, cdst, ETOT);

    // ---- layer 1 (H=4) ----
    {
        dim3 g((N_NODES + 127) / 128, 256 / 128);
        rt_gemm<128, 128, 16, 8, 8, IN_CH, 256><<<g, 256, 0, stream>>>(x, W1, h1, N_NODES);
    }
    attn_k<4, 64><<<N_NODES, 256, 0, stream>>>(h1, as1, ad1, As1, Ad1);
    edge_e_k<4><<<(ETOT + 255) / 256, 256, 0, stream>>>(csrc, cdst, As1, Ad1, E, ETOT);
    softmax_k<4><<<(N_NODES * 4 + 3) / 4, 256, 0, stream>>>(rowptr, E, ETOT, N_NODES);
    gather_k<4, 64><<<(N_NODES * 4 + 3) / 4, 256, 0, stream>>>(rowptr, csrc, E, h1, b1, out1, ETOT, N_NODES);

    // ---- layer 2 (H=1) ----
    {
        dim3 g((N_NODES + 127) / 128, 1);
        rt_gemm<128, 64, 16, 8, 4, 256, 64><<<g, 256, 0, stream>>>(out1, W2, h2, N_NODES);
    }
    attn_k<1, 64><<<N_NODES, 64, 0, stream>>>(h2, as2, ad2, As2, Ad2);
    edge_e_k<1><<<(ETOT + 255) / 256, 256, 0, stream>>>(csrc, cdst, As2, Ad2, E, ETOT);
    softmax_k<1><<<(N_NODES + 3) / 4, 256, 0, stream>>>(rowptr, E, ETOT, N_NODES);
    gather_k<1, 64><<<(N_NODES + 3) / 4, 256, 0, stream>>>(rowptr, csrc, E, h2, b2, out2, ETOT, N_NODES);

    // ---- pool + head ----
    pool_k<<<(N_NODES * 64 + 255) / 256, 256, 0, stream>>>(out2, batch, pooled, cnt);
    final_k<<<N_GRAPHS, 64, 0, stream>>>(pooled, cnt, Wl, bl, out);
}

// Round 5
// 549.397 us; speedup vs baseline: 2.7130x; 1.2713x over previous
//
#include <hip/hip_runtime.h>
#include <hip/hip_bf16.h>
#include <math.h>

#define N_NODES 50000
#define N_EDGES 800000
#define IN_CH 128
#define HID 64
#define HEADS 4
#define OUT_CH 10
#define N_GRAPHS 512
#define NEG_SLOPE 0.2f

__device__ __forceinline__ float b2f(unsigned short u) {
    return __uint_as_float(((unsigned)u) << 16);
}

// ---- register-tiled fp32 GEMM: Y[M,N] = X[M,K] @ W[K,N] ----
template<int BM, int BN, int BK, int TM, int TN, int K, int N>
__global__ __launch_bounds__(256) void rt_gemm(const float* __restrict__ X,
                                               const float* __restrict__ W,
                                               float* __restrict__ Y, int M) {
    __shared__ float xs[BK][BM + 4];   // transposed: xs[k][row]
    __shared__ float ws[BK][BN];
    const int t = threadIdx.x;
    const int row0 = blockIdx.x * BM;
    const int cb0 = blockIdx.y * BN;
    const int ty = t / (BN / TN);
    const int tx = t % (BN / TN);

    float acc[TM][TN];
#pragma unroll
    for (int i = 0; i < TM; i++)
#pragma unroll
        for (int j = 0; j < TN; j++) acc[i][j] = 0.f;

    const int XV = BM * BK / 4;
    const int WV = BK * BN / 4;

    for (int k0 = 0; k0 < K; k0 += BK) {
#pragma unroll
        for (int s = t; s < XV; s += 256) {
            int row = s / (BK / 4);
            int kc = s % (BK / 4);
            int gr = row0 + row;
            float4 v = make_float4(0.f, 0.f, 0.f, 0.f);
            if (gr < M) v = *(const float4*)&X[(size_t)gr * K + k0 + kc * 4];
            xs[kc * 4 + 0][row] = v.x;
            xs[kc * 4 + 1][row] = v.y;
            xs[kc * 4 + 2][row] = v.z;
            xs[kc * 4 + 3][row] = v.w;
        }
#pragma unroll
        for (int s = t; s < WV; s += 256) {
            int kr = s / (BN / 4);
            int c4 = s % (BN / 4);
            *(float4*)&ws[kr][c4 * 4] = *(const float4*)&W[(size_t)(k0 + kr) * N + cb0 + c4 * 4];
        }
        __syncthreads();

#pragma unroll
        for (int k = 0; k < BK; k++) {
            float xv[TM], wv[TN];
#pragma unroll
            for (int i = 0; i < TM / 4; i++)
                *(float4*)&xv[i * 4] = *(const float4*)&xs[k][ty * TM + i * 4];
#pragma unroll
            for (int j = 0; j < TN / 4; j++)
                *(float4*)&wv[j * 4] = *(const float4*)&ws[k][tx * TN + j * 4];
#pragma unroll
            for (int i = 0; i < TM; i++)
#pragma unroll
                for (int j = 0; j < TN; j++) acc[i][j] += xv[i] * wv[j];
        }
        __syncthreads();
    }

#pragma unroll
    for (int i = 0; i < TM; i++) {
        int gr = row0 + ty * TM + i;
        if (gr < M) {
#pragma unroll
            for (int j4 = 0; j4 < TN / 4; j4++) {
                float4 v = make_float4(acc[i][j4 * 4], acc[i][j4 * 4 + 1],
                                       acc[i][j4 * 4 + 2], acc[i][j4 * 4 + 3]);
                *(float4*)&Y[(size_t)gr * N + cb0 + tx * TN + j4 * 4] = v;
            }
        }
    }
}

// ---- attention coefficients + bf16 copy (layout [n][c][H]) ----
// block = H*C threads; wave w = head w
template<int H, int C>
__global__ void attn_k(const float* __restrict__ Hm,
                       const float* __restrict__ asrc, const float* __restrict__ adst,
                       float* __restrict__ As, float* __restrict__ Ad,
                       __hip_bfloat16* __restrict__ Hb) {
    int node = blockIdx.x;
    int t = threadIdx.x;
    int hd = t / C;
    int c = t % C;
    int lane = t & 63;
    float v = Hm[(size_t)node * H * C + t];
    Hb[(size_t)node * H * C + c * H + hd] = __float2bfloat16(v);
    float s = v * asrc[t];
    float d = v * adst[t];
#pragma unroll
    for (int o = 32; o > 0; o >>= 1) { s += __shfl_xor(s, o); d += __shfl_xor(d, o); }
    if (lane == 0) { As[node * H + hd] = s; Ad[node * H + hd] = d; }
}

// ---- CSR build: histogram of dst (incl. self loops) + per-graph node count ----
__global__ void hist_k(const int* __restrict__ dst, const int* __restrict__ batch,
                       int* __restrict__ deg, float* __restrict__ cntf, int etot) {
    int i = blockIdx.x * blockDim.x + threadIdx.x;
    if (i < etot) {
        int d = (i < N_EDGES) ? dst[i] : i - N_EDGES;
        atomicAdd(&deg[d], 1);
    }
    if (i < N_NODES) atomicAdd(&cntf[batch[i]], 1.f);
}

// ---- single-block exclusive scan of deg[n] -> rowptr[n+1] ----
__global__ void scan_k(const int* __restrict__ deg, int* __restrict__ rowptr, int n) {
    __shared__ int part[1024];
    int t = threadIdx.x;
    const int CH = (n + 1023) / 1024;
    int b = t * CH;
    int sum = 0;
    for (int i = 0; i < CH; i++) if (b + i < n) sum += deg[b + i];
    part[t] = sum;
    for (int o = 1; o < 1024; o <<= 1) {
        __syncthreads();
        int v = (t >= o) ? part[t - o] : 0;
        __syncthreads();
        part[t] += v;
    }
    __syncthreads();
    int ex = (t == 0) ? 0 : part[t - 1];
    for (int i = 0; i < CH; i++) if (b + i < n) { rowptr[b + i] = ex; ex += deg[b + i]; }
    if (t == 1023) rowptr[n] = ex;
}

// ---- scatter src ids into CSR slots ----
__global__ void scatter_k(const int* __restrict__ src, const int* __restrict__ dst,
                          const int* __restrict__ rowptr, int* __restrict__ cursor,
                          int* __restrict__ csrc, int etot) {
    int i = blockIdx.x * blockDim.x + threadIdx.x;
    if (i >= etot) return;
    int s, d;
    if (i < N_EDGES) { s = src[i]; d = dst[i]; } else { s = d = i - N_EDGES; }
    int pos = rowptr[d] + atomicAdd(&cursor[d], 1);
    csrc[pos] = s;
}

// ---- fused edge-logit + segment softmax: write alpha, layout E[j][H] ----
// one wave per node; blockDim = 256 (4 nodes/block)
template<int H>
__global__ void alpha_k(const int* __restrict__ rowptr, const int* __restrict__ csrc,
                        const float* __restrict__ As, const float* __restrict__ Ad,
                        float* __restrict__ E, int nnodes) {
    int lane = threadIdx.x & 63;
    int node = blockIdx.x * (blockDim.x >> 6) + (threadIdx.x >> 6);
    if (node >= nnodes) return;
    int beg = rowptr[node], end = rowptr[node + 1];
    int deg = end - beg;
    if (deg <= 64) {
        int j = beg + lane;
        bool act = j < end;
        int s = act ? csrc[j] : 0;
        float e[H];
        if (H == 4) {
            float4 a = *(const float4*)&As[s * 4];
            float4 b = *(const float4*)&Ad[node * 4];
            e[0] = a.x + b.x; e[1] = a.y + b.y; e[2] = a.z + b.z; e[3] = a.w + b.w;
        } else {
            e[0] = As[s] + Ad[node];
        }
        float al[H];
#pragma unroll
        for (int h = 0; h < H; h++) {
            float v = e[h];
            v = v > 0.f ? v : NEG_SLOPE * v;
            v = act ? v : -INFINITY;
            float m = v;
#pragma unroll
            for (int o = 32; o > 0; o >>= 1) m = fmaxf(m, __shfl_xor(m, o));
            float ex = act ? __expf(v - m) : 0.f;
            float den = ex;
#pragma unroll
            for (int o = 32; o > 0; o >>= 1) den += __shfl_xor(den, o);
            al[h] = ex / den;
        }
        if (act) {
            if (H == 4) {
                float4 w = make_float4(al[0], al[1], al[2], al[3]);
                *(float4*)&E[(size_t)j * 4] = w;
            } else {
                E[j] = al[0];
            }
        }
    } else {
        // rare fallback: strided two-pass per head, recompute logits on the fly
        for (int h = 0; h < H; h++) {
            float m = -INFINITY;
            for (int j = beg + lane; j < end; j += 64) {
                float v = As[csrc[j] * H + h] + Ad[node * H + h];
                v = v > 0.f ? v : NEG_SLOPE * v;
                m = fmaxf(m, v);
            }
#pragma unroll
            for (int o = 32; o > 0; o >>= 1) m = fmaxf(m, __shfl_xor(m, o));
            float den = 0.f;
            for (int j = beg + lane; j < end; j += 64) {
                float v = As[csrc[j] * H + h] + Ad[node * H + h];
                v = v > 0.f ? v : NEG_SLOPE * v;
                den += __expf(v - m);
            }
#pragma unroll
            for (int o = 32; o > 0; o >>= 1) den += __shfl_xor(den, o);
            for (int j = beg + lane; j < end; j += 64) {
                float v = As[csrc[j] * H + h] + Ad[node * H + h];
                v = v > 0.f ? v : NEG_SLOPE * v;
                E[(size_t)j * H + h] = __expf(v - m) / den;
            }
        }
    }
}

// ---- layer-1 gather: one wave per node, all 4 heads; bf16 values; bias+ELU ----
__global__ void gather1_k(const int* __restrict__ rowptr, const int* __restrict__ csrc,
                          const float* __restrict__ E, const __hip_bfloat16* __restrict__ Hb,
                          const float* __restrict__ bias, float* __restrict__ Out,
                          int nnodes) {
    int c = threadIdx.x & 63;
    int node = blockIdx.x * (blockDim.x >> 6) + (threadIdx.x >> 6);
    if (node >= nnodes) return;
    int beg = rowptr[node], end = rowptr[node + 1];
    const unsigned short* hb = (const unsigned short*)Hb;
    float a0 = 0.f, a1 = 0.f, a2 = 0.f, a3 = 0.f;
    int j = beg;
    for (; j + 2 <= end; j += 2) {
        int s0 = csrc[j], s1 = csrc[j + 1];
        float4 w0 = *(const float4*)&E[(size_t)j * 4];
        float4 w1 = *(const float4*)&E[(size_t)(j + 1) * 4];
        ushort4 v0 = *(const ushort4*)&hb[(size_t)s0 * 256 + c * 4];
        ushort4 v1 = *(const ushort4*)&hb[(size_t)s1 * 256 + c * 4];
        a0 += w0.x * b2f(v0.x) + w1.x * b2f(v1.x);
        a1 += w0.y * b2f(v0.y) + w1.y * b2f(v1.y);
        a2 += w0.z * b2f(v0.z) + w1.z * b2f(v1.z);
        a3 += w0.w * b2f(v0.w) + w1.w * b2f(v1.w);
    }
    for (; j < end; j++) {
        int s0 = csrc[j];
        float4 w0 = *(const float4*)&E[(size_t)j * 4];
        ushort4 v0 = *(const ushort4*)&hb[(size_t)s0 * 256 + c * 4];
        a0 += w0.x * b2f(v0.x);
        a1 += w0.y * b2f(v0.y);
        a2 += w0.z * b2f(v0.z);
        a3 += w0.w * b2f(v0.w);
    }
    float r0 = a0 + bias[0 * 64 + c];
    float r1 = a1 + bias[1 * 64 + c];
    float r2 = a2 + bias[2 * 64 + c];
    float r3 = a3 + bias[3 * 64 + c];
    r0 = r0 > 0.f ? r0 : expm1f(r0);
    r1 = r1 > 0.f ? r1 : expm1f(r1);
    r2 = r2 > 0.f ? r2 : expm1f(r2);
    r3 = r3 > 0.f ? r3 : expm1f(r3);
    size_t base = (size_t)node * 256;
    Out[base + 0 * 64 + c] = r0;
    Out[base + 1 * 64 + c] = r1;
    Out[base + 2 * 64 + c] = r2;
    Out[base + 3 * 64 + c] = r3;
}

// ---- layer-2 gather + bias + ELU + fused mean-pool accumulation ----
__global__ void gather2_k(const int* __restrict__ rowptr, const int* __restrict__ csrc,
                          const float* __restrict__ E, const __hip_bfloat16* __restrict__ Hb,
                          const float* __restrict__ bias, const int* __restrict__ batch,
                          float* __restrict__ pooled, int nnodes) {
    int c = threadIdx.x & 63;
    int node = blockIdx.x * (blockDim.x >> 6) + (threadIdx.x >> 6);
    if (node >= nnodes) return;
    int beg = rowptr[node], end = rowptr[node + 1];
    const unsigned short* hb = (const unsigned short*)Hb;
    float acc = 0.f;
    int j = beg;
    for (; j + 4 <= end; j += 4) {
        int s0 = csrc[j], s1 = csrc[j + 1], s2 = csrc[j + 2], s3 = csrc[j + 3];
        float w0 = E[j], w1 = E[j + 1], w2 = E[j + 2], w3 = E[j + 3];
        acc += w0 * b2f(hb[(size_t)s0 * 64 + c]) + w1 * b2f(hb[(size_t)s1 * 64 + c])
             + w2 * b2f(hb[(size_t)s2 * 64 + c]) + w3 * b2f(hb[(size_t)s3 * 64 + c]);
    }
    for (; j < end; j++) {
        acc += E[j] * b2f(hb[(size_t)csrc[j] * 64 + c]);
    }
    float v = acc + bias[c];
    v = v > 0.f ? v : expm1f(v);
    atomicAdd(&pooled[batch[node] * 64 + c], v);
}

// ---- final: out[g,:] = (pooled[g,:]/cnt) @ Wl + bl ----
__global__ void final_k(const float* __restrict__ pooled, const float* __restrict__ cnt,
                        const float* __restrict__ Wl, const float* __restrict__ bl,
                        float* __restrict__ out) {
    int g = blockIdx.x;
    int t = threadIdx.x;  // 64
    __shared__ float s[64];
    float c = cnt[g];
    c = c > 1.f ? c : 1.f;
    s[t] = pooled[g * 64 + t] / c;
    __syncthreads();
    if (t < OUT_CH) {
        float acc = bl[t];
        for (int k = 0; k < 64; k++) acc += s[k] * Wl[k * OUT_CH + t];
        out[g * OUT_CH + t] = acc;
    }
}

extern "C" void kernel_launch(void* const* d_in, const int* in_sizes, int n_in,
                              void* d_out, int out_size, void* d_ws, size_t ws_size,
                              hipStream_t stream) {
    const float* x    = (const float*)d_in[0];
    const int*   ei   = (const int*)d_in[1];
    const int*   batch= (const int*)d_in[2];
    const float* W1   = (const float*)d_in[3];
    const float* as1  = (const float*)d_in[4];
    const float* ad1  = (const float*)d_in[5];
    const float* b1   = (const float*)d_in[6];
    const float* W2   = (const float*)d_in[7];
    const float* as2  = (const float*)d_in[8];
    const float* ad2  = (const float*)d_in[9];
    const float* b2   = (const float*)d_in[10];
    const float* Wl   = (const float*)d_in[11];
    const float* bl   = (const float*)d_in[12];
    float* out = (float*)d_out;

    const int* src = ei;
    const int* dst = ei + N_EDGES;
    const int ETOT = N_EDGES + N_NODES;

    char* ws = (char*)d_ws;
    size_t off = 0;
    auto alloc = [&](size_t bytes) {
        void* p = ws + off;
        off = (off + bytes + 255) & ~((size_t)255);
        return p;
    };
    float* h1     = (float*)alloc((size_t)N_NODES * 256 * 4);
    float* out1   = (float*)alloc((size_t)N_NODES * 256 * 4);
    float* h2     = (float*)alloc((size_t)N_NODES * 64 * 4);
    __hip_bfloat16* h1b = (__hip_bfloat16*)alloc((size_t)N_NODES * 256 * 2);
    float* As1    = (float*)alloc((size_t)N_NODES * 4 * 4);
    float* Ad1    = (float*)alloc((size_t)N_NODES * 4 * 4);
    float* As2    = (float*)alloc((size_t)N_NODES * 4);
    float* Ad2    = (float*)alloc((size_t)N_NODES * 4);
    int*   deg    = (int*)  alloc((size_t)N_NODES * 4);
    int*   rowptr = (int*)  alloc((size_t)(N_NODES + 1) * 4);
    int*   cursor = (int*)  alloc((size_t)N_NODES * 4);
    int*   csrc   = (int*)  alloc((size_t)ETOT * 4);
    float* E      = (float*)alloc((size_t)ETOT * HEADS * 4);  // reused by layer 2 (H=1)
    float* pooled = (float*)alloc((size_t)N_GRAPHS * 64 * 4);
    float* cntf   = (float*)alloc((size_t)N_GRAPHS * 4);
    // h2b aliases h1b (h1b dead after gather1_k; attn_k L2 runs later)
    __hip_bfloat16* h2b = h1b;

    hipMemsetAsync(deg,    0, (size_t)N_NODES * 4, stream);
    hipMemsetAsync(cursor, 0, (size_t)N_NODES * 4, stream);
    hipMemsetAsync(pooled, 0, (size_t)N_GRAPHS * 64 * 4, stream);
    hipMemsetAsync(cntf,   0, (size_t)N_GRAPHS * 4, stream);

    // ---- CSR build (shared by both layers) + per-graph counts ----
    hist_k<<<(ETOT + 255) / 256, 256, 0, stream>>>(dst, batch, deg, cntf, ETOT);
    scan_k<<<1, 1024, 0, stream>>>(deg, rowptr, N_NODES);
    scatter_k<<<(ETOT + 255) / 256, 256, 0, stream>>>(src, dst, rowptr, cursor, csrc, ETOT);

    // ---- layer 1 (H=4) ----
    {
        dim3 g((N_NODES + 127) / 128, 256 / 128);
        rt_gemm<128, 128, 16, 8, 8, IN_CH, 256><<<g, 256, 0, stream>>>(x, W1, h1, N_NODES);
    }
    attn_k<4, 64><<<N_NODES, 256, 0, stream>>>(h1, as1, ad1, As1, Ad1, h1b);
    alpha_k<4><<<(N_NODES + 3) / 4, 256, 0, stream>>>(rowptr, csrc, As1, Ad1, E, N_NODES);
    gather1_k<<<(N_NODES + 3) / 4, 256, 0, stream>>>(rowptr, csrc, E, h1b, b1, out1, N_NODES);

    // ---- layer 2 (H=1) ----
    {
        dim3 g((N_NODES + 127) / 128, 1);
        rt_gemm<128, 64, 16, 8, 4, 256, 64><<<g, 256, 0, stream>>>(out1, W2, h2, N_NODES);
    }
    attn_k<1, 64><<<N_NODES, 64, 0, stream>>>(h2, as2, ad2, As2, Ad2, h2b);
    alpha_k<1><<<(N_NODES + 3) / 4, 256, 0, stream>>>(rowptr, csrc, As2, Ad2, E, N_NODES);
    gather2_k<<<(N_NODES + 3) / 4, 256, 0, stream>>>(rowptr, csrc, E, h2b, b2, batch, pooled, N_NODES);

    // ---- head ----
    final_k<<<N_GRAPHS, 64, 0, stream>>>(pooled, cntf, Wl, bl, out);
}

// Round 6
// 512.767 us; speedup vs baseline: 2.9068x; 1.0714x over previous
//
#include <hip/hip_runtime.h>
#include <hip/hip_bf16.h>
#include <math.h>

#define N_NODES 50000
#define N_EDGES 800000
#define IN_CH 128
#define HID 64
#define HEADS 4
#define OUT_CH 10
#define N_GRAPHS 512
#define NEG_SLOPE 0.2f

__device__ __forceinline__ float b2f(unsigned short u) {
    return __uint_as_float(((unsigned)u) << 16);
}

// ---- register-tiled fp32 GEMM, bf16 head-interleaved output ----
// Yb[m*N + c*H + head]  where col = head*64 + c
// grid: (ceil(M/BM), N/BN); 256 threads; TM=4; TN in {4,8}
// Fragment reads: xv = one float4 at ty*4; wv = TN/4 float4 chunks at
// tx*4 + cc*(BN/2)  -> stride-4 banks, worst 2-way conflict (free).
template<int BM, int BN, int BK, int TM, int TN, int K, int N, int H>
__global__ __launch_bounds__(256) void rt_gemm_bf(const float* __restrict__ X,
                                                  const float* __restrict__ W,
                                                  __hip_bfloat16* __restrict__ Yb, int M) {
    __shared__ float xs[BK][BM + 4];   // transposed: xs[k][row]
    __shared__ float ws[BK][BN];
    const int t = threadIdx.x;
    const int row0 = blockIdx.x * BM;
    const int cb0 = blockIdx.y * BN;
    const int NTX = BN / TN;           // 16
    const int ty = t / NTX;            // 0..15
    const int tx = t % NTX;            // 0..15
    const int CHUNKS = TN / 4;

    float acc[TM][TN];
#pragma unroll
    for (int i = 0; i < TM; i++)
#pragma unroll
        for (int j = 0; j < TN; j++) acc[i][j] = 0.f;

    const int XV = BM * BK / 4;
    const int WV = BK * BN / 4;

    for (int k0 = 0; k0 < K; k0 += BK) {
#pragma unroll
        for (int s = t; s < XV; s += 256) {
            int row = s / (BK / 4);
            int kc = s % (BK / 4);
            int gr = row0 + row;
            float4 v = make_float4(0.f, 0.f, 0.f, 0.f);
            if (gr < M) v = *(const float4*)&X[(size_t)gr * K + k0 + kc * 4];
            xs[kc * 4 + 0][row] = v.x;
            xs[kc * 4 + 1][row] = v.y;
            xs[kc * 4 + 2][row] = v.z;
            xs[kc * 4 + 3][row] = v.w;
        }
#pragma unroll
        for (int s = t; s < WV; s += 256) {
            int kr = s / (BN / 4);
            int c4 = s % (BN / 4);
            *(float4*)&ws[kr][c4 * 4] = *(const float4*)&W[(size_t)(k0 + kr) * N + cb0 + c4 * 4];
        }
        __syncthreads();

#pragma unroll
        for (int k = 0; k < BK; k++) {
            float xv[TM], wv[TN];
            *(float4*)&xv[0] = *(const float4*)&xs[k][ty * TM];
#pragma unroll
            for (int cc = 0; cc < CHUNKS; cc++)
                *(float4*)&wv[cc * 4] = *(const float4*)&ws[k][tx * 4 + cc * (BN / 2)];
#pragma unroll
            for (int i = 0; i < TM; i++)
#pragma unroll
                for (int j = 0; j < TN; j++) acc[i][j] += xv[i] * wv[j];
        }
        __syncthreads();
    }

    unsigned short* yb = (unsigned short*)Yb;
#pragma unroll
    for (int i = 0; i < TM; i++) {
        int gr = row0 + ty * TM + i;
        if (gr < M) {
#pragma unroll
            for (int cc = 0; cc < CHUNKS; cc++) {
#pragma unroll
                for (int j = 0; j < 4; j++) {
                    int col = cb0 + cc * (BN / 2) + tx * 4 + j;
                    int head = col >> 6;
                    int c = col & 63;
                    __hip_bfloat16 bv = __float2bfloat16(acc[i][cc * 4 + j]);
                    yb[(size_t)gr * N + c * H + head] = *(unsigned short*)&bv;
                }
            }
        }
    }
}

// ---- attention coefficients from bf16 h (layout [n][c][H]) ----
// one wave per node; blockDim = 256
template<int H>
__global__ void attn_k(const __hip_bfloat16* __restrict__ Hb,
                       const float* __restrict__ asrc, const float* __restrict__ adst,
                       float* __restrict__ As, float* __restrict__ Ad) {
    int lane = threadIdx.x & 63;
    int node = blockIdx.x * (blockDim.x >> 6) + (threadIdx.x >> 6);
    if (node >= N_NODES) return;
    const unsigned short* hb = (const unsigned short*)Hb;
    if (H == 4) {
        ushort4 v = *(const ushort4*)&hb[(size_t)node * 256 + lane * 4];
        float f0 = b2f(v.x), f1 = b2f(v.y), f2 = b2f(v.z), f3 = b2f(v.w);
        float s0 = f0 * asrc[0 * 64 + lane], d0 = f0 * adst[0 * 64 + lane];
        float s1 = f1 * asrc[1 * 64 + lane], d1 = f1 * adst[1 * 64 + lane];
        float s2 = f2 * asrc[2 * 64 + lane], d2 = f2 * adst[2 * 64 + lane];
        float s3 = f3 * asrc[3 * 64 + lane], d3 = f3 * adst[3 * 64 + lane];
#pragma unroll
        for (int o = 32; o > 0; o >>= 1) {
            s0 += __shfl_xor(s0, o); d0 += __shfl_xor(d0, o);
            s1 += __shfl_xor(s1, o); d1 += __shfl_xor(d1, o);
            s2 += __shfl_xor(s2, o); d2 += __shfl_xor(d2, o);
            s3 += __shfl_xor(s3, o); d3 += __shfl_xor(d3, o);
        }
        if (lane == 0) {
            *(float4*)&As[node * 4] = make_float4(s0, s1, s2, s3);
            *(float4*)&Ad[node * 4] = make_float4(d0, d1, d2, d3);
        }
    } else {
        float f = b2f(hb[(size_t)node * 64 + lane]);
        float s = f * asrc[lane];
        float d = f * adst[lane];
#pragma unroll
        for (int o = 32; o > 0; o >>= 1) { s += __shfl_xor(s, o); d += __shfl_xor(d, o); }
        if (lane == 0) { As[node] = s; Ad[node] = d; }
    }
}

// ---- CSR build: histogram of dst (incl. self loops) + per-graph node count ----
__global__ void hist_k(const int* __restrict__ dst, const int* __restrict__ batch,
                       int* __restrict__ deg, float* __restrict__ cntf, int etot) {
    int i = blockIdx.x * blockDim.x + threadIdx.x;
    if (i < etot) {
        int d = (i < N_EDGES) ? dst[i] : i - N_EDGES;
        atomicAdd(&deg[d], 1);
    }
    if (i < N_NODES) atomicAdd(&cntf[batch[i]], 1.f);
}

// ---- single-block exclusive scan of deg[n] -> rowptr[n+1] ----
__global__ void scan_k(const int* __restrict__ deg, int* __restrict__ rowptr, int n) {
    __shared__ int part[1024];
    int t = threadIdx.x;
    const int CH = (n + 1023) / 1024;
    int b = t * CH;
    int sum = 0;
    for (int i = 0; i < CH; i++) if (b + i < n) sum += deg[b + i];
    part[t] = sum;
    for (int o = 1; o < 1024; o <<= 1) {
        __syncthreads();
        int v = (t >= o) ? part[t - o] : 0;
        __syncthreads();
        part[t] += v;
    }
    __syncthreads();
    int ex = (t == 0) ? 0 : part[t - 1];
    for (int i = 0; i < CH; i++) if (b + i < n) { rowptr[b + i] = ex; ex += deg[b + i]; }
    if (t == 1023) rowptr[n] = ex;
}

// ---- scatter src ids into CSR slots ----
__global__ void scatter_k(const int* __restrict__ src, const int* __restrict__ dst,
                          const int* __restrict__ rowptr, int* __restrict__ cursor,
                          int* __restrict__ csrc, int etot) {
    int i = blockIdx.x * blockDim.x + threadIdx.x;
    if (i >= etot) return;
    int s, d;
    if (i < N_EDGES) { s = src[i]; d = dst[i]; } else { s = d = i - N_EDGES; }
    int pos = rowptr[d] + atomicAdd(&cursor[d], 1);
    csrc[pos] = s;
}

// ---- fused edge-logit + segment softmax: write alpha, layout E[j][H] ----
// one wave per node; blockDim = 256 (4 nodes/block)
template<int H>
__global__ void alpha_k(const int* __restrict__ rowptr, const int* __restrict__ csrc,
                        const float* __restrict__ As, const float* __restrict__ Ad,
                        float* __restrict__ E, int nnodes) {
    int lane = threadIdx.x & 63;
    int node = blockIdx.x * (blockDim.x >> 6) + (threadIdx.x >> 6);
    if (node >= nnodes) return;
    int beg = rowptr[node], end = rowptr[node + 1];
    int deg = end - beg;
    if (deg <= 64) {
        int j = beg + lane;
        bool act = j < end;
        int s = act ? csrc[j] : 0;
        float e[H];
        if (H == 4) {
            float4 a = *(const float4*)&As[s * 4];
            float4 b = *(const float4*)&Ad[node * 4];
            e[0] = a.x + b.x; e[1] = a.y + b.y; e[2] = a.z + b.z; e[3] = a.w + b.w;
        } else {
            e[0] = As[s] + Ad[node];
        }
        float al[H];
#pragma unroll
        for (int h = 0; h < H; h++) {
            float v = e[h];
            v = v > 0.f ? v : NEG_SLOPE * v;
            v = act ? v : -INFINITY;
            float m = v;
#pragma unroll
            for (int o = 32; o > 0; o >>= 1) m = fmaxf(m, __shfl_xor(m, o));
            float ex = act ? __expf(v - m) : 0.f;
            float den = ex;
#pragma unroll
            for (int o = 32; o > 0; o >>= 1) den += __shfl_xor(den, o);
            al[h] = ex / den;
        }
        if (act) {
            if (H == 4) {
                float4 w = make_float4(al[0], al[1], al[2], al[3]);
                *(float4*)&E[(size_t)j * 4] = w;
            } else {
                E[j] = al[0];
            }
        }
    } else {
        for (int h = 0; h < H; h++) {
            float m = -INFINITY;
            for (int j = beg + lane; j < end; j += 64) {
                float v = As[csrc[j] * H + h] + Ad[node * H + h];
                v = v > 0.f ? v : NEG_SLOPE * v;
                m = fmaxf(m, v);
            }
#pragma unroll
            for (int o = 32; o > 0; o >>= 1) m = fmaxf(m, __shfl_xor(m, o));
            float den = 0.f;
            for (int j = beg + lane; j < end; j += 64) {
                float v = As[csrc[j] * H + h] + Ad[node * H + h];
                v = v > 0.f ? v : NEG_SLOPE * v;
                den += __expf(v - m);
            }
#pragma unroll
            for (int o = 32; o > 0; o >>= 1) den += __shfl_xor(den, o);
            for (int j = beg + lane; j < end; j += 64) {
                float v = As[csrc[j] * H + h] + Ad[node * H + h];
                v = v > 0.f ? v : NEG_SLOPE * v;
                E[(size_t)j * H + h] = __expf(v - m) / den;
            }
        }
    }
}

// ---- layer-1 gather: one wave per node, all 4 heads; bf16 values; bias+ELU ----
__global__ void gather1_k(const int* __restrict__ rowptr, const int* __restrict__ csrc,
                          const float* __restrict__ E, const __hip_bfloat16* __restrict__ Hb,
                          const float* __restrict__ bias, float* __restrict__ Out,
                          int nnodes) {
    int c = threadIdx.x & 63;
    int node = blockIdx.x * (blockDim.x >> 6) + (threadIdx.x >> 6);
    if (node >= nnodes) return;
    int beg = rowptr[node], end = rowptr[node + 1];
    const unsigned short* hb = (const unsigned short*)Hb;
    float a0 = 0.f, a1 = 0.f, a2 = 0.f, a3 = 0.f;
    int j = beg;
    for (; j + 2 <= end; j += 2) {
        int s0 = csrc[j], s1 = csrc[j + 1];
        float4 w0 = *(const float4*)&E[(size_t)j * 4];
        float4 w1 = *(const float4*)&E[(size_t)(j + 1) * 4];
        ushort4 v0 = *(const ushort4*)&hb[(size_t)s0 * 256 + c * 4];
        ushort4 v1 = *(const ushort4*)&hb[(size_t)s1 * 256 + c * 4];
        a0 += w0.x * b2f(v0.x) + w1.x * b2f(v1.x);
        a1 += w0.y * b2f(v0.y) + w1.y * b2f(v1.y);
        a2 += w0.z * b2f(v0.z) + w1.z * b2f(v1.z);
        a3 += w0.w * b2f(v0.w) + w1.w * b2f(v1.w);
    }
    for (; j < end; j++) {
        int s0 = csrc[j];
        float4 w0 = *(const float4*)&E[(size_t)j * 4];
        ushort4 v0 = *(const ushort4*)&hb[(size_t)s0 * 256 + c * 4];
        a0 += w0.x * b2f(v0.x);
        a1 += w0.y * b2f(v0.y);
        a2 += w0.z * b2f(v0.z);
        a3 += w0.w * b2f(v0.w);
    }
    float r0 = a0 + bias[0 * 64 + c];
    float r1 = a1 + bias[1 * 64 + c];
    float r2 = a2 + bias[2 * 64 + c];
    float r3 = a3 + bias[3 * 64 + c];
    r0 = r0 > 0.f ? r0 : expm1f(r0);
    r1 = r1 > 0.f ? r1 : expm1f(r1);
    r2 = r2 > 0.f ? r2 : expm1f(r2);
    r3 = r3 > 0.f ? r3 : expm1f(r3);
    size_t base = (size_t)node * 256;
    Out[base + 0 * 64 + c] = r0;
    Out[base + 1 * 64 + c] = r1;
    Out[base + 2 * 64 + c] = r2;
    Out[base + 3 * 64 + c] = r3;
}

// ---- layer-2 gather + bias + ELU + fused mean-pool accumulation ----
__global__ void gather2_k(const int* __restrict__ rowptr, const int* __restrict__ csrc,
                          const float* __restrict__ E, const __hip_bfloat16* __restrict__ Hb,
                          const float* __restrict__ bias, const int* __restrict__ batch,
                          float* __restrict__ pooled, int nnodes) {
    int c = threadIdx.x & 63;
    int node = blockIdx.x * (blockDim.x >> 6) + (threadIdx.x >> 6);
    if (node >= nnodes) return;
    int beg = rowptr[node], end = rowptr[node + 1];
    const unsigned short* hb = (const unsigned short*)Hb;
    float acc = 0.f;
    int j = beg;
    for (; j + 4 <= end; j += 4) {
        int s0 = csrc[j], s1 = csrc[j + 1], s2 = csrc[j + 2], s3 = csrc[j + 3];
        float w0 = E[j], w1 = E[j + 1], w2 = E[j + 2], w3 = E[j + 3];
        acc += w0 * b2f(hb[(size_t)s0 * 64 + c]) + w1 * b2f(hb[(size_t)s1 * 64 + c])
             + w2 * b2f(hb[(size_t)s2 * 64 + c]) + w3 * b2f(hb[(size_t)s3 * 64 + c]);
    }
    for (; j < end; j++) {
        acc += E[j] * b2f(hb[(size_t)csrc[j] * 64 + c]);
    }
    float v = acc + bias[c];
    v = v > 0.f ? v : expm1f(v);
    atomicAdd(&pooled[batch[node] * 64 + c], v);
}

// ---- final: out[g,:] = (pooled[g,:]/cnt) @ Wl + bl ----
__global__ void final_k(const float* __restrict__ pooled, const float* __restrict__ cnt,
                        const float* __restrict__ Wl, const float* __restrict__ bl,
                        float* __restrict__ out) {
    int g = blockIdx.x;
    int t = threadIdx.x;  // 64
    __shared__ float s[64];
    float c = cnt[g];
    c = c > 1.f ? c : 1.f;
    s[t] = pooled[g * 64 + t] / c;
    __syncthreads();
    if (t < OUT_CH) {
        float acc = bl[t];
        for (int k = 0; k < 64; k++) acc += s[k] * Wl[k * OUT_CH + t];
        out[g * OUT_CH + t] = acc;
    }
}

extern "C" void kernel_launch(void* const* d_in, const int* in_sizes, int n_in,
                              void* d_out, int out_size, void* d_ws, size_t ws_size,
                              hipStream_t stream) {
    const float* x    = (const float*)d_in[0];
    const int*   ei   = (const int*)d_in[1];
    const int*   batch= (const int*)d_in[2];
    const float* W1   = (const float*)d_in[3];
    const float* as1  = (const float*)d_in[4];
    const float* ad1  = (const float*)d_in[5];
    const float* b1   = (const float*)d_in[6];
    const float* W2   = (const float*)d_in[7];
    const float* as2  = (const float*)d_in[8];
    const float* ad2  = (const float*)d_in[9];
    const float* b2   = (const float*)d_in[10];
    const float* Wl   = (const float*)d_in[11];
    const float* bl   = (const float*)d_in[12];
    float* out = (float*)d_out;

    const int* src = ei;
    const int* dst = ei + N_EDGES;
    const int ETOT = N_EDGES + N_NODES;

    char* ws = (char*)d_ws;
    size_t off = 0;
    auto alloc = [&](size_t bytes) {
        void* p = ws + off;
        off = (off + bytes + 255) & ~((size_t)255);
        return p;
    };
    __hip_bfloat16* h1b = (__hip_bfloat16*)alloc((size_t)N_NODES * 256 * 2);
    float* out1   = (float*)alloc((size_t)N_NODES * 256 * 4);
    float* As1    = (float*)alloc((size_t)N_NODES * 4 * 4);
    float* Ad1    = (float*)alloc((size_t)N_NODES * 4 * 4);
    float* As2    = (float*)alloc((size_t)N_NODES * 4);
    float* Ad2    = (float*)alloc((size_t)N_NODES * 4);
    int*   deg    = (int*)  alloc((size_t)N_NODES * 4);
    int*   rowptr = (int*)  alloc((size_t)(N_NODES + 1) * 4);
    int*   cursor = (int*)  alloc((size_t)N_NODES * 4);
    int*   csrc   = (int*)  alloc((size_t)ETOT * 4);
    float* E      = (float*)alloc((size_t)ETOT * HEADS * 4);  // reused by layer 2 (H=1)
    float* pooled = (float*)alloc((size_t)N_GRAPHS * 64 * 4);
    float* cntf   = (float*)alloc((size_t)N_GRAPHS * 4);
    // h2b aliases h1b (h1b dead after gather1_k)
    __hip_bfloat16* h2b = h1b;

    hipMemsetAsync(deg,    0, (size_t)N_NODES * 4, stream);
    hipMemsetAsync(cursor, 0, (size_t)N_NODES * 4, stream);
    hipMemsetAsync(pooled, 0, (size_t)N_GRAPHS * 64 * 4, stream);
    hipMemsetAsync(cntf,   0, (size_t)N_GRAPHS * 4, stream);

    // ---- CSR build (shared by both layers) + per-graph counts ----
    hist_k<<<(ETOT + 255) / 256, 256, 0, stream>>>(dst, batch, deg, cntf, ETOT);
    scan_k<<<1, 1024, 0, stream>>>(deg, rowptr, N_NODES);
    scatter_k<<<(ETOT + 255) / 256, 256, 0, stream>>>(src, dst, rowptr, cursor, csrc, ETOT);

    // ---- layer 1 (H=4) ----
    {
        dim3 g((N_NODES + 63) / 64, 2);
        rt_gemm_bf<64, 128, 16, 4, 8, IN_CH, 256, 4><<<g, 256, 0, stream>>>(x, W1, h1b, N_NODES);
    }
    attn_k<4><<<(N_NODES + 3) / 4, 256, 0, stream>>>(h1b, as1, ad1, As1, Ad1);
    alpha_k<4><<<(N_NODES + 3) / 4, 256, 0, stream>>>(rowptr, csrc, As1, Ad1, E, N_NODES);
    gather1_k<<<(N_NODES + 3) / 4, 256, 0, stream>>>(rowptr, csrc, E, h1b, b1, out1, N_NODES);

    // ---- layer 2 (H=1) ----
    {
        dim3 g((N_NODES + 63) / 64, 1);
        rt_gemm_bf<64, 64, 16, 4, 4, 256, 64, 1><<<g, 256, 0, stream>>>(out1, W2, h2b, N_NODES);
    }
    attn_k<1><<<(N_NODES + 3) / 4, 256, 0, stream>>>(h2b, as2, ad2, As2, Ad2);
    alpha_k<1><<<(N_NODES + 3) / 4, 256, 0, stream>>>(rowptr, csrc, As2, Ad2, E, N_NODES);
    gather2_k<<<(N_NODES + 3) / 4, 256, 0, stream>>>(rowptr, csrc, E, h2b, b2, batch, pooled, N_NODES);

    // ---- head ----
    final_k<<<N_GRAPHS, 64, 0, stream>>>(pooled, cntf, Wl, bl, out);
}

// Round 7
// 383.577 us; speedup vs baseline: 3.8858x; 1.3368x over previous
//
#include <hip/hip_runtime.h>
#include <hip/hip_bf16.h>
#include <math.h>

#define N_NODES 50000
#define N_EDGES 800000
#define IN_CH 128
#define HID 64
#define HEADS 4
#define OUT_CH 10
#define N_GRAPHS 512
#define NEG_SLOPE 0.2f

__device__ __forceinline__ float b2f(unsigned short u) {
    return __uint_as_float(((unsigned)u) << 16);
}
__device__ __forceinline__ float lrelu(float x) { return x > 0.f ? x : NEG_SLOPE * x; }

// ---- register-tiled fp32 GEMM, bf16 head-interleaved output ----
// Yb[m*N + c*H + head]  where col = head*64 + c
template<int BM, int BN, int BK, int TM, int TN, int K, int N, int H>
__global__ __launch_bounds__(256) void rt_gemm_bf(const float* __restrict__ X,
                                                  const float* __restrict__ W,
                                                  __hip_bfloat16* __restrict__ Yb, int M) {
    __shared__ float xs[BK][BM + 4];   // transposed: xs[k][row]
    __shared__ float ws[BK][BN];
    const int t = threadIdx.x;
    const int row0 = blockIdx.x * BM;
    const int cb0 = blockIdx.y * BN;
    const int NTX = BN / TN;           // 16
    const int ty = t / NTX;
    const int tx = t % NTX;
    const int CHUNKS = TN / 4;

    float acc[TM][TN];
#pragma unroll
    for (int i = 0; i < TM; i++)
#pragma unroll
        for (int j = 0; j < TN; j++) acc[i][j] = 0.f;

    const int XV = BM * BK / 4;
    const int WV = BK * BN / 4;

    for (int k0 = 0; k0 < K; k0 += BK) {
#pragma unroll
        for (int s = t; s < XV; s += 256) {
            int row = s / (BK / 4);
            int kc = s % (BK / 4);
            int gr = row0 + row;
            float4 v = make_float4(0.f, 0.f, 0.f, 0.f);
            if (gr < M) v = *(const float4*)&X[(size_t)gr * K + k0 + kc * 4];
            xs[kc * 4 + 0][row] = v.x;
            xs[kc * 4 + 1][row] = v.y;
            xs[kc * 4 + 2][row] = v.z;
            xs[kc * 4 + 3][row] = v.w;
        }
#pragma unroll
        for (int s = t; s < WV; s += 256) {
            int kr = s / (BN / 4);
            int c4 = s % (BN / 4);
            *(float4*)&ws[kr][c4 * 4] = *(const float4*)&W[(size_t)(k0 + kr) * N + cb0 + c4 * 4];
        }
        __syncthreads();

#pragma unroll
        for (int k = 0; k < BK; k++) {
            float xv[TM], wv[TN];
            *(float4*)&xv[0] = *(const float4*)&xs[k][ty * TM];
#pragma unroll
            for (int cc = 0; cc < CHUNKS; cc++)
                *(float4*)&wv[cc * 4] = *(const float4*)&ws[k][tx * 4 + cc * (BN / 2)];
#pragma unroll
            for (int i = 0; i < TM; i++)
#pragma unroll
                for (int j = 0; j < TN; j++) acc[i][j] += xv[i] * wv[j];
        }
        __syncthreads();
    }

    unsigned short* yb = (unsigned short*)Yb;
#pragma unroll
    for (int i = 0; i < TM; i++) {
        int gr = row0 + ty * TM + i;
        if (gr < M) {
#pragma unroll
            for (int cc = 0; cc < CHUNKS; cc++) {
#pragma unroll
                for (int j = 0; j < 4; j++) {
                    int col = cb0 + cc * (BN / 2) + tx * 4 + j;
                    int head = col >> 6;
                    int c = col & 63;
                    __hip_bfloat16 bv = __float2bfloat16(acc[i][cc * 4 + j]);
                    yb[(size_t)gr * N + c * H + head] = *(unsigned short*)&bv;
                }
            }
        }
    }
}

// ---- attention coefficients from bf16 h (layout [n][c][H]) ----
template<int H>
__global__ void attn_k(const __hip_bfloat16* __restrict__ Hb,
                       const float* __restrict__ asrc, const float* __restrict__ adst,
                       float* __restrict__ As, float* __restrict__ Ad) {
    int lane = threadIdx.x & 63;
    int node = blockIdx.x * (blockDim.x >> 6) + (threadIdx.x >> 6);
    if (node >= N_NODES) return;
    const unsigned short* hb = (const unsigned short*)Hb;
    if (H == 4) {
        ushort4 v = *(const ushort4*)&hb[(size_t)node * 256 + lane * 4];
        float f0 = b2f(v.x), f1 = b2f(v.y), f2 = b2f(v.z), f3 = b2f(v.w);
        float s0 = f0 * asrc[0 * 64 + lane], d0 = f0 * adst[0 * 64 + lane];
        float s1 = f1 * asrc[1 * 64 + lane], d1 = f1 * adst[1 * 64 + lane];
        float s2 = f2 * asrc[2 * 64 + lane], d2 = f2 * adst[2 * 64 + lane];
        float s3 = f3 * asrc[3 * 64 + lane], d3 = f3 * adst[3 * 64 + lane];
#pragma unroll
        for (int o = 32; o > 0; o >>= 1) {
            s0 += __shfl_xor(s0, o); d0 += __shfl_xor(d0, o);
            s1 += __shfl_xor(s1, o); d1 += __shfl_xor(d1, o);
            s2 += __shfl_xor(s2, o); d2 += __shfl_xor(d2, o);
            s3 += __shfl_xor(s3, o); d3 += __shfl_xor(d3, o);
        }
        if (lane == 0) {
            *(float4*)&As[node * 4] = make_float4(s0, s1, s2, s3);
            *(float4*)&Ad[node * 4] = make_float4(d0, d1, d2, d3);
        }
    } else {
        float f = b2f(hb[(size_t)node * 64 + lane]);
        float s = f * asrc[lane];
        float d = f * adst[lane];
#pragma unroll
        for (int o = 32; o > 0; o >>= 1) { s += __shfl_xor(s, o); d += __shfl_xor(d, o); }
        if (lane == 0) { As[node] = s; Ad[node] = d; }
    }
}

// ---- CSR build: histogram of dst (incl. self loops) + per-graph node count ----
__global__ void hist_k(const int* __restrict__ dst, const int* __restrict__ batch,
                       int* __restrict__ deg, float* __restrict__ cntf, int etot) {
    int i = blockIdx.x * blockDim.x + threadIdx.x;
    if (i < etot) {
        int d = (i < N_EDGES) ? dst[i] : i - N_EDGES;
        atomicAdd(&deg[d], 1);
    }
    if (i < N_NODES) atomicAdd(&cntf[batch[i]], 1.f);
}

// ---- 3-phase multi-block exclusive scan ----
__global__ void blksum_k(const int* __restrict__ deg, int* __restrict__ bsum, int n) {
    int t = threadIdx.x;
    int i = blockIdx.x * 256 + t;
    int v = (i < n) ? deg[i] : 0;
#pragma unroll
    for (int o = 32; o > 0; o >>= 1) v += __shfl_xor(v, o);
    __shared__ int wsum[4];
    if ((t & 63) == 0) wsum[t >> 6] = v;
    __syncthreads();
    if (t == 0) bsum[blockIdx.x] = wsum[0] + wsum[1] + wsum[2] + wsum[3];
}

__global__ void scanb_k(int* __restrict__ bsum, int nb) {
    __shared__ int tmp[256];
    int t = threadIdx.x;
    int v = (t < nb) ? bsum[t] : 0;
    tmp[t] = v;
    __syncthreads();
    for (int o = 1; o < 256; o <<= 1) {
        int u = (t >= o) ? tmp[t - o] : 0;
        __syncthreads();
        tmp[t] += u;
        __syncthreads();
    }
    if (t < nb) bsum[t] = tmp[t] - v;   // exclusive
}

__global__ void scanapply_k(const int* __restrict__ deg, const int* __restrict__ bsum,
                            int* __restrict__ rowptr, int n) {
    __shared__ int tmp[256];
    int t = threadIdx.x;
    int i = blockIdx.x * 256 + t;
    int v = (i < n) ? deg[i] : 0;
    tmp[t] = v;
    __syncthreads();
    for (int o = 1; o < 256; o <<= 1) {
        int u = (t >= o) ? tmp[t - o] : 0;
        __syncthreads();
        tmp[t] += u;
        __syncthreads();
    }
    int boff = bsum[blockIdx.x];
    if (i < n) rowptr[i] = boff + tmp[t] - v;
    if (i == n - 1) rowptr[n] = boff + tmp[t];
}

// ---- scatter src ids into CSR slots ----
__global__ void scatter_k(const int* __restrict__ src, const int* __restrict__ dst,
                          const int* __restrict__ rowptr, int* __restrict__ cursor,
                          int* __restrict__ csrc, int etot) {
    int i = blockIdx.x * blockDim.x + threadIdx.x;
    if (i >= etot) return;
    int s, d;
    if (i < N_EDGES) { s = src[i]; d = dst[i]; } else { s = d = i - N_EDGES; }
    int pos = rowptr[d] + atomicAdd(&cursor[d], 1);
    csrc[pos] = s;
}

// ---- layer-1 fused softmax + gather + bias + ELU (H=4) ----
// one wave per node; blockDim=256; grid exact (N_NODES % 4 == 0)
__global__ void agg1_k(const int* __restrict__ rowptr, const int* __restrict__ csrc,
                       const float* __restrict__ As, const float* __restrict__ Ad,
                       const __hip_bfloat16* __restrict__ Hb,
                       const float* __restrict__ bias, float* __restrict__ Out,
                       int nnodes) {
    __shared__ int ssh[4][64];
    __shared__ float4 wsh[4][64];
    int lane = threadIdx.x & 63;
    int w = threadIdx.x >> 6;
    int node = blockIdx.x * 4 + w;
    int beg = rowptr[node], end = rowptr[node + 1];
    int deg = end - beg;
    const unsigned short* hb = (const unsigned short*)Hb;
    float4 bv = *(const float4*)&Ad[node * 4];
    bool fast = (deg <= 64);
    if (fast) {
        bool act = lane < deg;
        int s = act ? csrc[beg + lane] : 0;
        float4 a = *(const float4*)&As[s * 4];
        float e0 = lrelu(a.x + bv.x), e1 = lrelu(a.y + bv.y);
        float e2 = lrelu(a.z + bv.z), e3 = lrelu(a.w + bv.w);
        if (!act) { e0 = e1 = e2 = e3 = -INFINITY; }
        float m0 = e0, m1 = e1, m2 = e2, m3 = e3;
#pragma unroll
        for (int o = 32; o > 0; o >>= 1) {
            m0 = fmaxf(m0, __shfl_xor(m0, o)); m1 = fmaxf(m1, __shfl_xor(m1, o));
            m2 = fmaxf(m2, __shfl_xor(m2, o)); m3 = fmaxf(m3, __shfl_xor(m3, o));
        }
        float x0 = act ? __expf(e0 - m0) : 0.f;
        float x1 = act ? __expf(e1 - m1) : 0.f;
        float x2 = act ? __expf(e2 - m2) : 0.f;
        float x3 = act ? __expf(e3 - m3) : 0.f;
        float d0 = x0, d1 = x1, d2 = x2, d3 = x3;
#pragma unroll
        for (int o = 32; o > 0; o >>= 1) {
            d0 += __shfl_xor(d0, o); d1 += __shfl_xor(d1, o);
            d2 += __shfl_xor(d2, o); d3 += __shfl_xor(d3, o);
        }
        ssh[w][lane] = s;
        wsh[w][lane] = make_float4(x0 / d0, x1 / d1, x2 / d2, x3 / d3);
    }
    __syncthreads();
    float acc0 = 0.f, acc1 = 0.f, acc2 = 0.f, acc3 = 0.f;
    if (fast) {
        for (int j = 0; j < deg; j++) {
            int s = ssh[w][j];
            float4 wt = wsh[w][j];
            ushort4 v = *(const ushort4*)&hb[(size_t)s * 256 + lane * 4];
            acc0 += wt.x * b2f(v.x);
            acc1 += wt.y * b2f(v.y);
            acc2 += wt.z * b2f(v.z);
            acc3 += wt.w * b2f(v.w);
        }
    } else {
        float m0 = -INFINITY, m1 = -INFINITY, m2 = -INFINITY, m3 = -INFINITY;
        for (int j = beg + lane; j < end; j += 64) {
            float4 a = *(const float4*)&As[csrc[j] * 4];
            m0 = fmaxf(m0, lrelu(a.x + bv.x)); m1 = fmaxf(m1, lrelu(a.y + bv.y));
            m2 = fmaxf(m2, lrelu(a.z + bv.z)); m3 = fmaxf(m3, lrelu(a.w + bv.w));
        }
#pragma unroll
        for (int o = 32; o > 0; o >>= 1) {
            m0 = fmaxf(m0, __shfl_xor(m0, o)); m1 = fmaxf(m1, __shfl_xor(m1, o));
            m2 = fmaxf(m2, __shfl_xor(m2, o)); m3 = fmaxf(m3, __shfl_xor(m3, o));
        }
        float d0 = 0.f, d1 = 0.f, d2 = 0.f, d3 = 0.f;
        for (int j = beg + lane; j < end; j += 64) {
            float4 a = *(const float4*)&As[csrc[j] * 4];
            d0 += __expf(lrelu(a.x + bv.x) - m0); d1 += __expf(lrelu(a.y + bv.y) - m1);
            d2 += __expf(lrelu(a.z + bv.z) - m2); d3 += __expf(lrelu(a.w + bv.w) - m3);
        }
#pragma unroll
        for (int o = 32; o > 0; o >>= 1) {
            d0 += __shfl_xor(d0, o); d1 += __shfl_xor(d1, o);
            d2 += __shfl_xor(d2, o); d3 += __shfl_xor(d3, o);
        }
        for (int j = beg; j < end; j++) {
            int s = csrc[j];
            float4 a = *(const float4*)&As[s * 4];
            float w0 = __expf(lrelu(a.x + bv.x) - m0) / d0;
            float w1 = __expf(lrelu(a.y + bv.y) - m1) / d1;
            float w2 = __expf(lrelu(a.z + bv.z) - m2) / d2;
            float w3 = __expf(lrelu(a.w + bv.w) - m3) / d3;
            ushort4 v = *(const ushort4*)&hb[(size_t)s * 256 + lane * 4];
            acc0 += w0 * b2f(v.x); acc1 += w1 * b2f(v.y);
            acc2 += w2 * b2f(v.z); acc3 += w3 * b2f(v.w);
        }
    }
    float r0 = acc0 + bias[0 * 64 + lane];
    float r1 = acc1 + bias[1 * 64 + lane];
    float r2 = acc2 + bias[2 * 64 + lane];
    float r3 = acc3 + bias[3 * 64 + lane];
    r0 = r0 > 0.f ? r0 : expm1f(r0);
    r1 = r1 > 0.f ? r1 : expm1f(r1);
    r2 = r2 > 0.f ? r2 : expm1f(r2);
    r3 = r3 > 0.f ? r3 : expm1f(r3);
    size_t base = (size_t)node * 256;
    Out[base + 0 * 64 + lane] = r0;
    Out[base + 1 * 64 + lane] = r1;
    Out[base + 2 * 64 + lane] = r2;
    Out[base + 3 * 64 + lane] = r3;
}

// ---- layer-2 fused softmax + gather + bias + ELU + mean-pool accum (H=1) ----
__global__ void agg2_k(const int* __restrict__ rowptr, const int* __restrict__ csrc,
                       const float* __restrict__ As, const float* __restrict__ Ad,
                       const __hip_bfloat16* __restrict__ Hb,
                       const float* __restrict__ bias, const int* __restrict__ batch,
                       float* __restrict__ pooled, int nnodes) {
    __shared__ int ssh[4][64];
    __shared__ float wsh[4][64];
    int lane = threadIdx.x & 63;
    int w = threadIdx.x >> 6;
    int node = blockIdx.x * 4 + w;
    int beg = rowptr[node], end = rowptr[node + 1];
    int deg = end - beg;
    const unsigned short* hb = (const unsigned short*)Hb;
    float ad = Ad[node];
    bool fast = (deg <= 64);
    if (fast) {
        bool act = lane < deg;
        int s = act ? csrc[beg + lane] : 0;
        float e = lrelu(As[s] + ad);
        if (!act) e = -INFINITY;
        float m = e;
#pragma unroll
        for (int o = 32; o > 0; o >>= 1) m = fmaxf(m, __shfl_xor(m, o));
        float x = act ? __expf(e - m) : 0.f;
        float d = x;
#pragma unroll
        for (int o = 32; o > 0; o >>= 1) d += __shfl_xor(d, o);
        ssh[w][lane] = s;
        wsh[w][lane] = x / d;
    }
    __syncthreads();
    float acc = 0.f;
    if (fast) {
        for (int j = 0; j < deg; j++) {
            int s = ssh[w][j];
            float wt = wsh[w][j];
            acc += wt * b2f(hb[(size_t)s * 64 + lane]);
        }
    } else {
        float m = -INFINITY;
        for (int j = beg + lane; j < end; j += 64) m = fmaxf(m, lrelu(As[csrc[j]] + ad));
#pragma unroll
        for (int o = 32; o > 0; o >>= 1) m = fmaxf(m, __shfl_xor(m, o));
        float d = 0.f;
        for (int j = beg + lane; j < end; j += 64) d += __expf(lrelu(As[csrc[j]] + ad) - m);
#pragma unroll
        for (int o = 32; o > 0; o >>= 1) d += __shfl_xor(d, o);
        for (int j = beg; j < end; j++) {
            int s = csrc[j];
            float wt = __expf(lrelu(As[s] + ad) - m) / d;
            acc += wt * b2f(hb[(size_t)s * 64 + lane]);
        }
    }
    float v = acc + bias[lane];
    v = v > 0.f ? v : expm1f(v);
    atomicAdd(&pooled[batch[node] * 64 + lane], v);
}

// ---- final: out[g,:] = (pooled[g,:]/cnt) @ Wl + bl ----
__global__ void final_k(const float* __restrict__ pooled, const float* __restrict__ cnt,
                        const float* __restrict__ Wl, const float* __restrict__ bl,
                        float* __restrict__ out) {
    int g = blockIdx.x;
    int t = threadIdx.x;  // 64
    __shared__ float s[64];
    float c = cnt[g];
    c = c > 1.f ? c : 1.f;
    s[t] = pooled[g * 64 + t] / c;
    __syncthreads();
    if (t < OUT_CH) {
        float acc = bl[t];
        for (int k = 0; k < 64; k++) acc += s[k] * Wl[k * OUT_CH + t];
        out[g * OUT_CH + t] = acc;
    }
}

extern "C" void kernel_launch(void* const* d_in, const int* in_sizes, int n_in,
                              void* d_out, int out_size, void* d_ws, size_t ws_size,
                              hipStream_t stream) {
    const float* x    = (const float*)d_in[0];
    const int*   ei   = (const int*)d_in[1];
    const int*   batch= (const int*)d_in[2];
    const float* W1   = (const float*)d_in[3];
    const float* as1  = (const float*)d_in[4];
    const float* ad1  = (const float*)d_in[5];
    const float* b1   = (const float*)d_in[6];
    const float* W2   = (const float*)d_in[7];
    const float* as2  = (const float*)d_in[8];
    const float* ad2  = (const float*)d_in[9];
    const float* b2   = (const float*)d_in[10];
    const float* Wl   = (const float*)d_in[11];
    const float* bl   = (const float*)d_in[12];
    float* out = (float*)d_out;

    const int* src = ei;
    const int* dst = ei + N_EDGES;
    const int ETOT = N_EDGES + N_NODES;
    const int NB = (N_NODES + 255) / 256;   // 196

    char* ws = (char*)d_ws;
    size_t off = 0;
    auto alloc = [&](size_t bytes) {
        void* p = ws + off;
        off = (off + bytes + 255) & ~((size_t)255);
        return p;
    };
    __hip_bfloat16* h1b = (__hip_bfloat16*)alloc((size_t)N_NODES * 256 * 2);
    float* out1   = (float*)alloc((size_t)N_NODES * 256 * 4);
    float* As1    = (float*)alloc((size_t)N_NODES * 4 * 4);
    float* Ad1    = (float*)alloc((size_t)N_NODES * 4 * 4);
    float* As2    = (float*)alloc((size_t)N_NODES * 4);
    float* Ad2    = (float*)alloc((size_t)N_NODES * 4);
    int*   deg    = (int*)  alloc((size_t)N_NODES * 4);
    int*   rowptr = (int*)  alloc((size_t)(N_NODES + 1) * 4);
    int*   cursor = (int*)  alloc((size_t)N_NODES * 4);
    int*   csrc   = (int*)  alloc((size_t)ETOT * 4);
    int*   bsum   = (int*)  alloc((size_t)NB * 4);
    float* pooled = (float*)alloc((size_t)N_GRAPHS * 64 * 4);
    float* cntf   = (float*)alloc((size_t)N_GRAPHS * 4);
    __hip_bfloat16* h2b = h1b;   // aliases h1b (dead after agg1_k)

    hipMemsetAsync(deg,    0, (size_t)N_NODES * 4, stream);
    hipMemsetAsync(cursor, 0, (size_t)N_NODES * 4, stream);
    hipMemsetAsync(pooled, 0, (size_t)N_GRAPHS * 64 * 4, stream);
    hipMemsetAsync(cntf,   0, (size_t)N_GRAPHS * 4, stream);

    // ---- CSR build (shared by both layers) + per-graph counts ----
    hist_k<<<(ETOT + 255) / 256, 256, 0, stream>>>(dst, batch, deg, cntf, ETOT);
    blksum_k<<<NB, 256, 0, stream>>>(deg, bsum, N_NODES);
    scanb_k<<<1, 256, 0, stream>>>(bsum, NB);
    scanapply_k<<<NB, 256, 0, stream>>>(deg, bsum, rowptr, N_NODES);
    scatter_k<<<(ETOT + 255) / 256, 256, 0, stream>>>(src, dst, rowptr, cursor, csrc, ETOT);

    // ---- layer 1 (H=4) ----
    {
        dim3 g((N_NODES + 63) / 64, 2);
        rt_gemm_bf<64, 128, 16, 4, 8, IN_CH, 256, 4><<<g, 256, 0, stream>>>(x, W1, h1b, N_NODES);
    }
    attn_k<4><<<(N_NODES + 3) / 4, 256, 0, stream>>>(h1b, as1, ad1, As1, Ad1);
    agg1_k<<<N_NODES / 4, 256, 0, stream>>>(rowptr, csrc, As1, Ad1, h1b, b1, out1, N_NODES);

    // ---- layer 2 (H=1) ----
    {
        dim3 g((N_NODES + 63) / 64, 1);
        rt_gemm_bf<64, 64, 16, 4, 4, 256, 64, 1><<<g, 256, 0, stream>>>(out1, W2, h2b, N_NODES);
    }
    attn_k<1><<<(N_NODES + 3) / 4, 256, 0, stream>>>(h2b, as2, ad2, As2, Ad2);
    agg2_k<<<N_NODES / 4, 256, 0, stream>>>(rowptr, csrc, As2, Ad2, h2b, b2, batch, pooled, N_NODES);

    // ---- head ----
    final_k<<<N_GRAPHS, 64, 0, stream>>>(pooled, cntf, Wl, bl, out);
}

// Round 8
// 368.937 us; speedup vs baseline: 4.0400x; 1.0397x over previous
//
#include <hip/hip_runtime.h>
#include <hip/hip_bf16.h>
#include <math.h>

#define N_NODES 50000
#define N_EDGES 800000
#define IN_CH 128
#define HID 64
#define HEADS 4
#define OUT_CH 10
#define N_GRAPHS 512
#define NEG_SLOPE 0.2f

__device__ __forceinline__ float b2f(unsigned short u) {
    return __uint_as_float(((unsigned)u) << 16);
}
__device__ __forceinline__ float lrelu(float x) { return x > 0.f ? x : NEG_SLOPE * x; }

// ---- register-tiled GEMM + fused attention coefficients + bf16 output ----
// Yb[m*N + c*H + head] (head-interleaved); As/Ad written from fp32 accumulators.
// TM=8 rows (two float4 chunks at ty*4 and ty*4+BM/2), TN cols (chunks at
// tx*4 + cc*BN/2) -> all LDS fragment reads are stride-4-bank (<=2-way, free).
template<int BM, int BN, int BK, int TM, int TN, int K, int N, int H, bool XBF>
__global__ __launch_bounds__(256) void gemm_att_k(const void* __restrict__ Xv,
                                                  const float* __restrict__ W,
                                                  unsigned short* __restrict__ Yb,
                                                  const float* __restrict__ asrc,
                                                  const float* __restrict__ adst,
                                                  float* __restrict__ As,
                                                  float* __restrict__ Ad, int M) {
    __shared__ float xs[BK][BM + 4];   // transposed: xs[k][row]
    __shared__ float ws[BK][BN];
    const int t = threadIdx.x;
    const int row0 = blockIdx.x * BM;
    const int cb0 = blockIdx.y * BN;
    const int NTX = BN / TN;           // 16
    const int ty = t / NTX;
    const int tx = t % NTX;
    const int RC = TM / 4;             // 2
    const int CC = TN / 4;             // 1 or 2

    float acc[TM][TN];
#pragma unroll
    for (int i = 0; i < TM; i++)
#pragma unroll
        for (int j = 0; j < TN; j++) acc[i][j] = 0.f;

    for (int k0 = 0; k0 < K; k0 += BK) {
        // stage X (transposed)
#pragma unroll
        for (int s = t; s < BM * BK / 4; s += 256) {
            int row = s / (BK / 4);
            int kc = s % (BK / 4);
            int gr = row0 + row;
            float f0 = 0.f, f1 = 0.f, f2 = 0.f, f3 = 0.f;
            if (gr < M) {
                if (XBF) {
                    ushort4 v = *(const ushort4*)((const unsigned short*)Xv + (size_t)gr * K + k0 + kc * 4);
                    f0 = b2f(v.x); f1 = b2f(v.y); f2 = b2f(v.z); f3 = b2f(v.w);
                } else {
                    float4 v = *(const float4*)((const float*)Xv + (size_t)gr * K + k0 + kc * 4);
                    f0 = v.x; f1 = v.y; f2 = v.z; f3 = v.w;
                }
            }
            xs[kc * 4 + 0][row] = f0;
            xs[kc * 4 + 1][row] = f1;
            xs[kc * 4 + 2][row] = f2;
            xs[kc * 4 + 3][row] = f3;
        }
        // stage W
#pragma unroll
        for (int s = t; s < BK * BN / 4; s += 256) {
            int kr = s / (BN / 4);
            int c4 = s % (BN / 4);
            *(float4*)&ws[kr][c4 * 4] = *(const float4*)&W[(size_t)(k0 + kr) * N + cb0 + c4 * 4];
        }
        __syncthreads();

#pragma unroll
        for (int k = 0; k < BK; k++) {
            float xv[TM], wv[TN];
#pragma unroll
            for (int rc = 0; rc < RC; rc++)
                *(float4*)&xv[rc * 4] = *(const float4*)&xs[k][ty * 4 + rc * (BM / 2)];
#pragma unroll
            for (int cc = 0; cc < CC; cc++)
                *(float4*)&wv[cc * 4] = *(const float4*)&ws[k][tx * 4 + cc * (BN / 2)];
#pragma unroll
            for (int i = 0; i < TM; i++)
#pragma unroll
                for (int j = 0; j < TN; j++) acc[i][j] += xv[i] * wv[j];
        }
        __syncthreads();
    }

    // ---- fused attention coefficients (per-row dot + 16-lane reduce) ----
    const int hA = cb0 >> 6;
#pragma unroll
    for (int rc = 0; rc < RC; rc++) {
#pragma unroll
        for (int i = 0; i < 4; i++) {
            int r = rc * 4 + i;
            float sA = 0.f, dA = 0.f, sB = 0.f, dB = 0.f;
#pragma unroll
            for (int j = 0; j < 4; j++) {
                sA += acc[r][j] * asrc[hA * 64 + tx * 4 + j];
                dA += acc[r][j] * adst[hA * 64 + tx * 4 + j];
                if (CC == 2) {
                    sB += acc[r][(CC == 2 ? 4 : 0) + j] * asrc[(hA + 1) * 64 + tx * 4 + j];
                    dB += acc[r][(CC == 2 ? 4 : 0) + j] * adst[(hA + 1) * 64 + tx * 4 + j];
                }
            }
#pragma unroll
            for (int o = 8; o > 0; o >>= 1) {
                sA += __shfl_xor(sA, o); dA += __shfl_xor(dA, o);
                if (CC == 2) { sB += __shfl_xor(sB, o); dB += __shfl_xor(dB, o); }
            }
            if (tx == 0) {
                int gr = row0 + ty * 4 + rc * (BM / 2) + i;
                if (gr < M) {
                    if (H == 4) {
                        As[gr * 4 + hA] = sA; Ad[gr * 4 + hA] = dA;
                        As[gr * 4 + hA + 1] = sB; Ad[gr * 4 + hA + 1] = dB;
                    } else {
                        As[gr] = sA; Ad[gr] = dA;
                    }
                }
            }
        }
    }

    // ---- bf16 head-interleaved store ----
#pragma unroll
    for (int rc = 0; rc < RC; rc++) {
#pragma unroll
        for (int i = 0; i < 4; i++) {
            int gr = row0 + ty * 4 + rc * (BM / 2) + i;
            if (gr >= M) continue;
            int r = rc * 4 + i;
#pragma unroll
            for (int cc = 0; cc < CC; cc++) {
#pragma unroll
                for (int j = 0; j < 4; j++) {
                    int col = cb0 + cc * (BN / 2) + tx * 4 + j;
                    int head = col >> 6;
                    int c = col & 63;
                    __hip_bfloat16 bv = __float2bfloat16(acc[r][cc * 4 + j]);
                    Yb[(size_t)gr * N + c * H + head] = *(unsigned short*)&bv;
                }
            }
        }
    }
}

// ---- CSR build: histogram of dst (incl. self loops) + per-graph node count ----
__global__ void hist_k(const int* __restrict__ dst, const int* __restrict__ batch,
                       int* __restrict__ deg, float* __restrict__ cntf, int etot) {
    int i = blockIdx.x * blockDim.x + threadIdx.x;
    if (i < etot) {
        int d = (i < N_EDGES) ? dst[i] : i - N_EDGES;
        atomicAdd(&deg[d], 1);
    }
    if (i < N_NODES) atomicAdd(&cntf[batch[i]], 1.f);
}

// ---- 3-phase multi-block exclusive scan ----
__global__ void blksum_k(const int* __restrict__ deg, int* __restrict__ bsum, int n) {
    int t = threadIdx.x;
    int i = blockIdx.x * 256 + t;
    int v = (i < n) ? deg[i] : 0;
#pragma unroll
    for (int o = 32; o > 0; o >>= 1) v += __shfl_xor(v, o);
    __shared__ int wsum[4];
    if ((t & 63) == 0) wsum[t >> 6] = v;
    __syncthreads();
    if (t == 0) bsum[blockIdx.x] = wsum[0] + wsum[1] + wsum[2] + wsum[3];
}

__global__ void scanb_k(int* __restrict__ bsum, int nb) {
    __shared__ int tmp[256];
    int t = threadIdx.x;
    int v = (t < nb) ? bsum[t] : 0;
    tmp[t] = v;
    __syncthreads();
    for (int o = 1; o < 256; o <<= 1) {
        int u = (t >= o) ? tmp[t - o] : 0;
        __syncthreads();
        tmp[t] += u;
        __syncthreads();
    }
    if (t < nb) bsum[t] = tmp[t] - v;   // exclusive
}

__global__ void scanapply_k(const int* __restrict__ deg, const int* __restrict__ bsum,
                            int* __restrict__ rowptr, int n) {
    __shared__ int tmp[256];
    int t = threadIdx.x;
    int i = blockIdx.x * 256 + t;
    int v = (i < n) ? deg[i] : 0;
    tmp[t] = v;
    __syncthreads();
    for (int o = 1; o < 256; o <<= 1) {
        int u = (t >= o) ? tmp[t - o] : 0;
        __syncthreads();
        tmp[t] += u;
        __syncthreads();
    }
    int boff = bsum[blockIdx.x];
    if (i < n) rowptr[i] = boff + tmp[t] - v;
    if (i == n - 1) rowptr[n] = boff + tmp[t];
}

// ---- scatter src ids into CSR slots ----
__global__ void scatter_k(const int* __restrict__ src, const int* __restrict__ dst,
                          const int* __restrict__ rowptr, int* __restrict__ cursor,
                          int* __restrict__ csrc, int etot) {
    int i = blockIdx.x * blockDim.x + threadIdx.x;
    if (i >= etot) return;
    int s, d;
    if (i < N_EDGES) { s = src[i]; d = dst[i]; } else { s = d = i - N_EDGES; }
    int pos = rowptr[d] + atomicAdd(&cursor[d], 1);
    csrc[pos] = s;
}

// ---- layer-1 fused softmax + gather + bias + ELU (H=4), bf16 output ----
// one wave per node; blockDim=256; grid exact (N_NODES % 4 == 0)
__global__ void agg1_k(const int* __restrict__ rowptr, const int* __restrict__ csrc,
                       const float* __restrict__ As, const float* __restrict__ Ad,
                       const __hip_bfloat16* __restrict__ Hb,
                       const float* __restrict__ bias,
                       unsigned short* __restrict__ Outb, int nnodes) {
    __shared__ int ssh[4][64];
    __shared__ float4 wsh[4][64];
    int lane = threadIdx.x & 63;
    int w = threadIdx.x >> 6;
    int node = blockIdx.x * 4 + w;
    int beg = rowptr[node], end = rowptr[node + 1];
    int deg = end - beg;
    const unsigned short* hb = (const unsigned short*)Hb;
    float4 bv = *(const float4*)&Ad[node * 4];
    bool fast = (deg <= 64);
    if (fast) {
        bool act = lane < deg;
        int s = act ? csrc[beg + lane] : 0;
        float4 a = *(const float4*)&As[s * 4];
        float e0 = lrelu(a.x + bv.x), e1 = lrelu(a.y + bv.y);
        float e2 = lrelu(a.z + bv.z), e3 = lrelu(a.w + bv.w);
        if (!act) { e0 = e1 = e2 = e3 = -INFINITY; }
        float m0 = e0, m1 = e1, m2 = e2, m3 = e3;
#pragma unroll
        for (int o = 32; o > 0; o >>= 1) {
            m0 = fmaxf(m0, __shfl_xor(m0, o)); m1 = fmaxf(m1, __shfl_xor(m1, o));
            m2 = fmaxf(m2, __shfl_xor(m2, o)); m3 = fmaxf(m3, __shfl_xor(m3, o));
        }
        float x0 = act ? __expf(e0 - m0) : 0.f;
        float x1 = act ? __expf(e1 - m1) : 0.f;
        float x2 = act ? __expf(e2 - m2) : 0.f;
        float x3 = act ? __expf(e3 - m3) : 0.f;
        float d0 = x0, d1 = x1, d2 = x2, d3 = x3;
#pragma unroll
        for (int o = 32; o > 0; o >>= 1) {
            d0 += __shfl_xor(d0, o); d1 += __shfl_xor(d1, o);
            d2 += __shfl_xor(d2, o); d3 += __shfl_xor(d3, o);
        }
        ssh[w][lane] = s;
        wsh[w][lane] = make_float4(x0 / d0, x1 / d1, x2 / d2, x3 / d3);
    }
    __syncthreads();
    float acc0 = 0.f, acc1 = 0.f, acc2 = 0.f, acc3 = 0.f;
    if (fast) {
        float p0 = 0.f, p1 = 0.f, p2 = 0.f, p3 = 0.f;
        int j = 0;
        for (; j + 2 <= deg; j += 2) {
            int sA = ssh[w][j], sB = ssh[w][j + 1];
            float4 wA = wsh[w][j], wB = wsh[w][j + 1];
            ushort4 vA = *(const ushort4*)&hb[(size_t)sA * 256 + lane * 4];
            ushort4 vB = *(const ushort4*)&hb[(size_t)sB * 256 + lane * 4];
            acc0 += wA.x * b2f(vA.x); p0 += wB.x * b2f(vB.x);
            acc1 += wA.y * b2f(vA.y); p1 += wB.y * b2f(vB.y);
            acc2 += wA.z * b2f(vA.z); p2 += wB.z * b2f(vB.z);
            acc3 += wA.w * b2f(vA.w); p3 += wB.w * b2f(vB.w);
        }
        if (j < deg) {
            int s = ssh[w][j];
            float4 wt = wsh[w][j];
            ushort4 v = *(const ushort4*)&hb[(size_t)s * 256 + lane * 4];
            acc0 += wt.x * b2f(v.x); acc1 += wt.y * b2f(v.y);
            acc2 += wt.z * b2f(v.z); acc3 += wt.w * b2f(v.w);
        }
        acc0 += p0; acc1 += p1; acc2 += p2; acc3 += p3;
    } else {
        float m0 = -INFINITY, m1 = -INFINITY, m2 = -INFINITY, m3 = -INFINITY;
        for (int j = beg + lane; j < end; j += 64) {
            float4 a = *(const float4*)&As[csrc[j] * 4];
            m0 = fmaxf(m0, lrelu(a.x + bv.x)); m1 = fmaxf(m1, lrelu(a.y + bv.y));
            m2 = fmaxf(m2, lrelu(a.z + bv.z)); m3 = fmaxf(m3, lrelu(a.w + bv.w));
        }
#pragma unroll
        for (int o = 32; o > 0; o >>= 1) {
            m0 = fmaxf(m0, __shfl_xor(m0, o)); m1 = fmaxf(m1, __shfl_xor(m1, o));
            m2 = fmaxf(m2, __shfl_xor(m2, o)); m3 = fmaxf(m3, __shfl_xor(m3, o));
        }
        float d0 = 0.f, d1 = 0.f, d2 = 0.f, d3 = 0.f;
        for (int j = beg + lane; j < end; j += 64) {
            float4 a = *(const float4*)&As[csrc[j] * 4];
            d0 += __expf(lrelu(a.x + bv.x) - m0); d1 += __expf(lrelu(a.y + bv.y) - m1);
            d2 += __expf(lrelu(a.z + bv.z) - m2); d3 += __expf(lrelu(a.w + bv.w) - m3);
        }
#pragma unroll
        for (int o = 32; o > 0; o >>= 1) {
            d0 += __shfl_xor(d0, o); d1 += __shfl_xor(d1, o);
            d2 += __shfl_xor(d2, o); d3 += __shfl_xor(d3, o);
        }
        for (int j = beg; j < end; j++) {
            int s = csrc[j];
            float4 a = *(const float4*)&As[s * 4];
            float w0 = __expf(lrelu(a.x + bv.x) - m0) / d0;
            float w1 = __expf(lrelu(a.y + bv.y) - m1) / d1;
            float w2 = __expf(lrelu(a.z + bv.z) - m2) / d2;
            float w3 = __expf(lrelu(a.w + bv.w) - m3) / d3;
            ushort4 v = *(const ushort4*)&hb[(size_t)s * 256 + lane * 4];
            acc0 += w0 * b2f(v.x); acc1 += w1 * b2f(v.y);
            acc2 += w2 * b2f(v.z); acc3 += w3 * b2f(v.w);
        }
    }
    float r0 = acc0 + bias[0 * 64 + lane];
    float r1 = acc1 + bias[1 * 64 + lane];
    float r2 = acc2 + bias[2 * 64 + lane];
    float r3 = acc3 + bias[3 * 64 + lane];
    r0 = r0 > 0.f ? r0 : expm1f(r0);
    r1 = r1 > 0.f ? r1 : expm1f(r1);
    r2 = r2 > 0.f ? r2 : expm1f(r2);
    r3 = r3 > 0.f ? r3 : expm1f(r3);
    size_t base = (size_t)node * 256;
    __hip_bfloat16 o0 = __float2bfloat16(r0), o1 = __float2bfloat16(r1);
    __hip_bfloat16 o2 = __float2bfloat16(r2), o3 = __float2bfloat16(r3);
    Outb[base + 0 * 64 + lane] = *(unsigned short*)&o0;
    Outb[base + 1 * 64 + lane] = *(unsigned short*)&o1;
    Outb[base + 2 * 64 + lane] = *(unsigned short*)&o2;
    Outb[base + 3 * 64 + lane] = *(unsigned short*)&o3;
}

// ---- layer-2 fused softmax + gather + bias + ELU + mean-pool accum (H=1) ----
__global__ void agg2_k(const int* __restrict__ rowptr, const int* __restrict__ csrc,
                       const float* __restrict__ As, const float* __restrict__ Ad,
                       const __hip_bfloat16* __restrict__ Hb,
                       const float* __restrict__ bias, const int* __restrict__ batch,
                       float* __restrict__ pooled, int nnodes) {
    __shared__ int ssh[4][64];
    __shared__ float wsh[4][64];
    int lane = threadIdx.x & 63;
    int w = threadIdx.x >> 6;
    int node = blockIdx.x * 4 + w;
    int beg = rowptr[node], end = rowptr[node + 1];
    int deg = end - beg;
    const unsigned short* hb = (const unsigned short*)Hb;
    float ad = Ad[node];
    bool fast = (deg <= 64);
    if (fast) {
        bool act = lane < deg;
        int s = act ? csrc[beg + lane] : 0;
        float e = lrelu(As[s] + ad);
        if (!act) e = -INFINITY;
        float m = e;
#pragma unroll
        for (int o = 32; o > 0; o >>= 1) m = fmaxf(m, __shfl_xor(m, o));
        float x = act ? __expf(e - m) : 0.f;
        float d = x;
#pragma unroll
        for (int o = 32; o > 0; o >>= 1) d += __shfl_xor(d, o);
        ssh[w][lane] = s;
        wsh[w][lane] = x / d;
    }
    __syncthreads();
    float acc = 0.f;
    if (fast) {
        float p = 0.f;
        int j = 0;
        for (; j + 2 <= deg; j += 2) {
            int sA = ssh[w][j], sB = ssh[w][j + 1];
            float wA = wsh[w][j], wB = wsh[w][j + 1];
            acc += wA * b2f(hb[(size_t)sA * 64 + lane]);
            p   += wB * b2f(hb[(size_t)sB * 64 + lane]);
        }
        if (j < deg) acc += wsh[w][j] * b2f(hb[(size_t)ssh[w][j] * 64 + lane]);
        acc += p;
    } else {
        float m = -INFINITY;
        for (int j = beg + lane; j < end; j += 64) m = fmaxf(m, lrelu(As[csrc[j]] + ad));
#pragma unroll
        for (int o = 32; o > 0; o >>= 1) m = fmaxf(m, __shfl_xor(m, o));
        float d = 0.f;
        for (int j = beg + lane; j < end; j += 64) d += __expf(lrelu(As[csrc[j]] + ad) - m);
#pragma unroll
        for (int o = 32; o > 0; o >>= 1) d += __shfl_xor(d, o);
        for (int j = beg; j < end; j++) {
            int s = csrc[j];
            float wt = __expf(lrelu(As[s] + ad) - m) / d;
            acc += wt * b2f(hb[(size_t)s * 64 + lane]);
        }
    }
    float v = acc + bias[lane];
    v = v > 0.f ? v : expm1f(v);
    atomicAdd(&pooled[batch[node] * 64 + lane], v);
}

// ---- final: out[g,:] = (pooled[g,:]/cnt) @ Wl + bl ----
__global__ void final_k(const float* __restrict__ pooled, const float* __restrict__ cnt,
                        const float* __restrict__ Wl, const float* __restrict__ bl,
                        float* __restrict__ out) {
    int g = blockIdx.x;
    int t = threadIdx.x;  // 64
    __shared__ float s[64];
    float c = cnt[g];
    c = c > 1.f ? c : 1.f;
    s[t] = pooled[g * 64 + t] / c;
    __syncthreads();
    if (t < OUT_CH) {
        float acc = bl[t];
        for (int k = 0; k < 64; k++) acc += s[k] * Wl[k * OUT_CH + t];
        out[g * OUT_CH + t] = acc;
    }
}

extern "C" void kernel_launch(void* const* d_in, const int* in_sizes, int n_in,
                              void* d_out, int out_size, void* d_ws, size_t ws_size,
                              hipStream_t stream) {
    const float* x    = (const float*)d_in[0];
    const int*   ei   = (const int*)d_in[1];
    const int*   batch= (const int*)d_in[2];
    const float* W1   = (const float*)d_in[3];
    const float* as1  = (const float*)d_in[4];
    const float* ad1  = (const float*)d_in[5];
    const float* b1   = (const float*)d_in[6];
    const float* W2   = (const float*)d_in[7];
    const float* as2  = (const float*)d_in[8];
    const float* ad2  = (const float*)d_in[9];
    const float* b2   = (const float*)d_in[10];
    const float* Wl   = (const float*)d_in[11];
    const float* bl   = (const float*)d_in[12];
    float* out = (float*)d_out;

    const int* src = ei;
    const int* dst = ei + N_EDGES;
    const int ETOT = N_EDGES + N_NODES;
    const int NB = (N_NODES + 255) / 256;   // 196

    char* ws = (char*)d_ws;
    size_t off = 0;
    auto alloc = [&](size_t bytes) {
        void* p = ws + off;
        off = (off + bytes + 255) & ~((size_t)255);
        return p;
    };
    unsigned short* h1b  = (unsigned short*)alloc((size_t)N_NODES * 256 * 2);
    unsigned short* out1b= (unsigned short*)alloc((size_t)N_NODES * 256 * 2);
    float* As1    = (float*)alloc((size_t)N_NODES * 4 * 4);
    float* Ad1    = (float*)alloc((size_t)N_NODES * 4 * 4);
    float* As2    = (float*)alloc((size_t)N_NODES * 4);
    float* Ad2    = (float*)alloc((size_t)N_NODES * 4);
    int*   deg    = (int*)  alloc((size_t)N_NODES * 4);
    int*   rowptr = (int*)  alloc((size_t)(N_NODES + 1) * 4);
    int*   cursor = (int*)  alloc((size_t)N_NODES * 4);
    int*   csrc   = (int*)  alloc((size_t)ETOT * 4);
    int*   bsum   = (int*)  alloc((size_t)NB * 4);
    float* pooled = (float*)alloc((size_t)N_GRAPHS * 64 * 4);
    float* cntf   = (float*)alloc((size_t)N_GRAPHS * 4);
    unsigned short* h2b = h1b;   // aliases h1b (dead after agg1_k)

    hipMemsetAsync(deg,    0, (size_t)N_NODES * 4, stream);
    hipMemsetAsync(cursor, 0, (size_t)N_NODES * 4, stream);
    hipMemsetAsync(pooled, 0, (size_t)N_GRAPHS * 64 * 4, stream);
    hipMemsetAsync(cntf,   0, (size_t)N_GRAPHS * 4, stream);

    // ---- CSR build (shared by both layers) + per-graph counts ----
    hist_k<<<(ETOT + 255) / 256, 256, 0, stream>>>(dst, batch, deg, cntf, ETOT);
    blksum_k<<<NB, 256, 0, stream>>>(deg, bsum, N_NODES);
    scanb_k<<<1, 256, 0, stream>>>(bsum, NB);
    scanapply_k<<<NB, 256, 0, stream>>>(deg, bsum, rowptr, N_NODES);
    scatter_k<<<(ETOT + 255) / 256, 256, 0, stream>>>(src, dst, rowptr, cursor, csrc, ETOT);

    // ---- layer 1 (H=4): GEMM + fused attn coeffs ----
    {
        dim3 g((N_NODES + 127) / 128, 2);
        gemm_att_k<128, 128, 16, 8, 8, IN_CH, 256, 4, false>
            <<<g, 256, 0, stream>>>(x, W1, h1b, as1, ad1, As1, Ad1, N_NODES);
    }
    agg1_k<<<N_NODES / 4, 256, 0, stream>>>(rowptr, csrc, As1, Ad1,
                                            (const __hip_bfloat16*)h1b, b1, out1b, N_NODES);

    // ---- layer 2 (H=1): bf16-input GEMM + fused attn coeffs ----
    {
        dim3 g((N_NODES + 127) / 128, 1);
        gemm_att_k<128, 64, 16, 8, 4, 256, 64, 1, true>
            <<<g, 256, 0, stream>>>(out1b, W2, h2b, as2, ad2, As2, Ad2, N_NODES);
    }
    agg2_k<<<N_NODES / 4, 256, 0, stream>>>(rowptr, csrc, As2, Ad2,
                                            (const __hip_bfloat16*)h2b, b2, batch, pooled, N_NODES);

    // ---- head ----
    final_k<<<N_GRAPHS, 64, 0, stream>>>(pooled, cntf, Wl, bl, out);
}

// Round 9
// 354.378 us; speedup vs baseline: 4.2060x; 1.0411x over previous
//
#include <hip/hip_runtime.h>
#include <hip/hip_bf16.h>
#include <math.h>

#define N_NODES 50000
#define N_EDGES 800000
#define IN_CH 128
#define HID 64
#define HEADS 4
#define OUT_CH 10
#define N_GRAPHS 512
#define NEG_SLOPE 0.2f

__device__ __forceinline__ float b2f(unsigned short u) {
    return __uint_as_float(((unsigned)u) << 16);
}
__device__ __forceinline__ unsigned short f2b(float f) {
    __hip_bfloat16 b = __float2bfloat16(f);
    return *(unsigned short*)&b;
}
__device__ __forceinline__ float lrelu(float x) { return x > 0.f ? x : NEG_SLOPE * x; }

// ---- register-tiled GEMM + fused attention coefficients + bf16 output ----
// Yb[m*N + c*H + head] (head-interleaved). TM=4 rows at ty*4; TN cols in
// TN/4 float4 chunks at tx*4 + cc*(BN/2) -> all LDS reads <=2-way (free).
// 64-row tiles keep the grid large (occupancy > per-block efficiency here).
template<int BM, int BN, int BK, int TN, int K, int N, int H, bool XBF>
__global__ __launch_bounds__(256) void gemm_att_k(const void* __restrict__ Xv,
                                                  const float* __restrict__ W,
                                                  unsigned short* __restrict__ Yb,
                                                  const float* __restrict__ asrc,
                                                  const float* __restrict__ adst,
                                                  float* __restrict__ As,
                                                  float* __restrict__ Ad, int M) {
    __shared__ float xs[BK][BM + 4];   // transposed: xs[k][row]
    __shared__ float ws[BK][BN];
    const int t = threadIdx.x;
    const int row0 = blockIdx.x * BM;
    const int cb0 = blockIdx.y * BN;
    const int ty = t / 16;             // 0..15 -> rows ty*4..ty*4+3
    const int tx = t % 16;
    const int CC = TN / 4;             // 1 or 2

    float acc[4][TN];
#pragma unroll
    for (int i = 0; i < 4; i++)
#pragma unroll
        for (int j = 0; j < TN; j++) acc[i][j] = 0.f;

    for (int k0 = 0; k0 < K; k0 += BK) {
        // stage X (transposed); BM*BK/4 == 256 -> one float4 per thread
        {
            int row = t / (BK / 4);
            int kc = t % (BK / 4);
            int gr = row0 + row;
            float f0 = 0.f, f1 = 0.f, f2 = 0.f, f3 = 0.f;
            if (gr < M) {
                if (XBF) {
                    ushort4 v = *(const ushort4*)((const unsigned short*)Xv + (size_t)gr * K + k0 + kc * 4);
                    f0 = b2f(v.x); f1 = b2f(v.y); f2 = b2f(v.z); f3 = b2f(v.w);
                } else {
                    float4 v = *(const float4*)((const float*)Xv + (size_t)gr * K + k0 + kc * 4);
                    f0 = v.x; f1 = v.y; f2 = v.z; f3 = v.w;
                }
            }
            xs[kc * 4 + 0][row] = f0;
            xs[kc * 4 + 1][row] = f1;
            xs[kc * 4 + 2][row] = f2;
            xs[kc * 4 + 3][row] = f3;
        }
        // stage W
#pragma unroll
        for (int s = t; s < BK * BN / 4; s += 256) {
            int kr = s / (BN / 4);
            int c4 = s % (BN / 4);
            *(float4*)&ws[kr][c4 * 4] = *(const float4*)&W[(size_t)(k0 + kr) * N + cb0 + c4 * 4];
        }
        __syncthreads();

#pragma unroll
        for (int k = 0; k < BK; k++) {
            float xv[4], wv[TN];
            *(float4*)&xv[0] = *(const float4*)&xs[k][ty * 4];
#pragma unroll
            for (int cc = 0; cc < CC; cc++)
                *(float4*)&wv[cc * 4] = *(const float4*)&ws[k][tx * 4 + cc * (BN / 2)];
#pragma unroll
            for (int i = 0; i < 4; i++)
#pragma unroll
                for (int j = 0; j < TN; j++) acc[i][j] += xv[i] * wv[j];
        }
        __syncthreads();
    }

    // ---- fused attention coefficients (per-row dot + 16-lane reduce) ----
    const int hA = cb0 >> 6;
#pragma unroll
    for (int i = 0; i < 4; i++) {
        float sA = 0.f, dA = 0.f, sB = 0.f, dB = 0.f;
#pragma unroll
        for (int j = 0; j < 4; j++) {
            sA += acc[i][j] * asrc[hA * 64 + tx * 4 + j];
            dA += acc[i][j] * adst[hA * 64 + tx * 4 + j];
            if (CC == 2) {
                sB += acc[i][4 + j] * asrc[(hA + 1) * 64 + tx * 4 + j];
                dB += acc[i][4 + j] * adst[(hA + 1) * 64 + tx * 4 + j];
            }
        }
#pragma unroll
        for (int o = 8; o > 0; o >>= 1) {
            sA += __shfl_xor(sA, o); dA += __shfl_xor(dA, o);
            if (CC == 2) { sB += __shfl_xor(sB, o); dB += __shfl_xor(dB, o); }
        }
        if (tx == 0) {
            int gr = row0 + ty * 4 + i;
            if (gr < M) {
                if (H == 4) {
                    As[gr * 4 + hA] = sA; Ad[gr * 4 + hA] = dA;
                    As[gr * 4 + hA + 1] = sB; Ad[gr * 4 + hA + 1] = dB;
                } else {
                    As[gr] = sA; Ad[gr] = dA;
                }
            }
        }
    }

    // ---- bf16 head-interleaved store (packed) ----
#pragma unroll
    for (int i = 0; i < 4; i++) {
        int gr = row0 + ty * 4 + i;
        if (gr >= M) continue;
        if (H == 4) {
            // heads hA, hA+1 are adjacent in [c][H]: one ushort2 per (c)
#pragma unroll
            for (int j = 0; j < 4; j++) {
                ushort2 p;
                p.x = f2b(acc[i][j]);
                p.y = f2b(acc[i][4 + j]);
                *(ushort2*)&Yb[(size_t)gr * N + (tx * 4 + j) * 4 + hA] = p;
            }
        } else {
            ushort4 p;
            p.x = f2b(acc[i][0]); p.y = f2b(acc[i][1]);
            p.z = f2b(acc[i][2]); p.w = f2b(acc[i][3]);
            *(ushort4*)&Yb[(size_t)gr * N + tx * 4] = p;
        }
    }
}

// ---- CSR build: histogram of dst (incl. self loops) + per-graph node count ----
__global__ void hist_k(const int* __restrict__ dst, const int* __restrict__ batch,
                       int* __restrict__ deg, float* __restrict__ cntf, int etot) {
    int i = blockIdx.x * blockDim.x + threadIdx.x;
    if (i < etot) {
        int d = (i < N_EDGES) ? dst[i] : i - N_EDGES;
        atomicAdd(&deg[d], 1);
    }
    if (i < N_NODES) atomicAdd(&cntf[batch[i]], 1.f);
}

// ---- 3-phase multi-block exclusive scan ----
__global__ void blksum_k(const int* __restrict__ deg, int* __restrict__ bsum, int n) {
    int t = threadIdx.x;
    int i = blockIdx.x * 256 + t;
    int v = (i < n) ? deg[i] : 0;
#pragma unroll
    for (int o = 32; o > 0; o >>= 1) v += __shfl_xor(v, o);
    __shared__ int wsum[4];
    if ((t & 63) == 0) wsum[t >> 6] = v;
    __syncthreads();
    if (t == 0) bsum[blockIdx.x] = wsum[0] + wsum[1] + wsum[2] + wsum[3];
}

__global__ void scanb_k(int* __restrict__ bsum, int nb) {
    __shared__ int tmp[256];
    int t = threadIdx.x;
    int v = (t < nb) ? bsum[t] : 0;
    tmp[t] = v;
    __syncthreads();
    for (int o = 1; o < 256; o <<= 1) {
        int u = (t >= o) ? tmp[t - o] : 0;
        __syncthreads();
        tmp[t] += u;
        __syncthreads();
    }
    if (t < nb) bsum[t] = tmp[t] - v;   // exclusive
}

__global__ void scanapply_k(const int* __restrict__ deg, const int* __restrict__ bsum,
                            int* __restrict__ rowptr, int n) {
    __shared__ int tmp[256];
    int t = threadIdx.x;
    int i = blockIdx.x * 256 + t;
    int v = (i < n) ? deg[i] : 0;
    tmp[t] = v;
    __syncthreads();
    for (int o = 1; o < 256; o <<= 1) {
        int u = (t >= o) ? tmp[t - o] : 0;
        __syncthreads();
        tmp[t] += u;
        __syncthreads();
    }
    int boff = bsum[blockIdx.x];
    if (i < n) rowptr[i] = boff + tmp[t] - v;
    if (i == n - 1) rowptr[n] = boff + tmp[t];
}

// ---- scatter src ids into CSR slots ----
__global__ void scatter_k(const int* __restrict__ src, const int* __restrict__ dst,
                          const int* __restrict__ rowptr, int* __restrict__ cursor,
                          int* __restrict__ csrc, int etot) {
    int i = blockIdx.x * blockDim.x + threadIdx.x;
    if (i >= etot) return;
    int s, d;
    if (i < N_EDGES) { s = src[i]; d = dst[i]; } else { s = d = i - N_EDGES; }
    int pos = rowptr[d] + atomicAdd(&cursor[d], 1);
    csrc[pos] = s;
}

// ---- layer-1 fused softmax + gather + bias + ELU (H=4), bf16 output ----
__global__ void agg1_k(const int* __restrict__ rowptr, const int* __restrict__ csrc,
                       const float* __restrict__ As, const float* __restrict__ Ad,
                       const __hip_bfloat16* __restrict__ Hb,
                       const float* __restrict__ bias,
                       unsigned short* __restrict__ Outb, int nnodes) {
    __shared__ int ssh[4][64];
    __shared__ float4 wsh[4][64];
    int lane = threadIdx.x & 63;
    int w = threadIdx.x >> 6;
    int node = blockIdx.x * 4 + w;
    int beg = rowptr[node], end = rowptr[node + 1];
    int deg = end - beg;
    const unsigned short* hb = (const unsigned short*)Hb;
    float4 bv = *(const float4*)&Ad[node * 4];
    bool fast = (deg <= 64);
    if (fast) {
        bool act = lane < deg;
        int s = act ? csrc[beg + lane] : 0;
        float4 a = *(const float4*)&As[s * 4];
        float e0 = lrelu(a.x + bv.x), e1 = lrelu(a.y + bv.y);
        float e2 = lrelu(a.z + bv.z), e3 = lrelu(a.w + bv.w);
        if (!act) { e0 = e1 = e2 = e3 = -INFINITY; }
        float m0 = e0, m1 = e1, m2 = e2, m3 = e3;
#pragma unroll
        for (int o = 32; o > 0; o >>= 1) {
            m0 = fmaxf(m0, __shfl_xor(m0, o)); m1 = fmaxf(m1, __shfl_xor(m1, o));
            m2 = fmaxf(m2, __shfl_xor(m2, o)); m3 = fmaxf(m3, __shfl_xor(m3, o));
        }
        float x0 = act ? __expf(e0 - m0) : 0.f;
        float x1 = act ? __expf(e1 - m1) : 0.f;
        float x2 = act ? __expf(e2 - m2) : 0.f;
        float x3 = act ? __expf(e3 - m3) : 0.f;
        float d0 = x0, d1 = x1, d2 = x2, d3 = x3;
#pragma unroll
        for (int o = 32; o > 0; o >>= 1) {
            d0 += __shfl_xor(d0, o); d1 += __shfl_xor(d1, o);
            d2 += __shfl_xor(d2, o); d3 += __shfl_xor(d3, o);
        }
        ssh[w][lane] = s;
        wsh[w][lane] = make_float4(x0 / d0, x1 / d1, x2 / d2, x3 / d3);
    }
    __syncthreads();
    float acc0 = 0.f, acc1 = 0.f, acc2 = 0.f, acc3 = 0.f;
    if (fast) {
        float p0 = 0.f, p1 = 0.f, p2 = 0.f, p3 = 0.f;
        int j = 0;
        for (; j + 2 <= deg; j += 2) {
            int sA = ssh[w][j], sB = ssh[w][j + 1];
            float4 wA = wsh[w][j], wB = wsh[w][j + 1];
            ushort4 vA = *(const ushort4*)&hb[(size_t)sA * 256 + lane * 4];
            ushort4 vB = *(const ushort4*)&hb[(size_t)sB * 256 + lane * 4];
            acc0 += wA.x * b2f(vA.x); p0 += wB.x * b2f(vB.x);
            acc1 += wA.y * b2f(vA.y); p1 += wB.y * b2f(vB.y);
            acc2 += wA.z * b2f(vA.z); p2 += wB.z * b2f(vB.z);
            acc3 += wA.w * b2f(vA.w); p3 += wB.w * b2f(vB.w);
        }
        if (j < deg) {
            int s = ssh[w][j];
            float4 wt = wsh[w][j];
            ushort4 v = *(const ushort4*)&hb[(size_t)s * 256 + lane * 4];
            acc0 += wt.x * b2f(v.x); acc1 += wt.y * b2f(v.y);
            acc2 += wt.z * b2f(v.z); acc3 += wt.w * b2f(v.w);
        }
        acc0 += p0; acc1 += p1; acc2 += p2; acc3 += p3;
    } else {
        float m0 = -INFINITY, m1 = -INFINITY, m2 = -INFINITY, m3 = -INFINITY;
        for (int j = beg + lane; j < end; j += 64) {
            float4 a = *(const float4*)&As[csrc[j] * 4];
            m0 = fmaxf(m0, lrelu(a.x + bv.x)); m1 = fmaxf(m1, lrelu(a.y + bv.y));
            m2 = fmaxf(m2, lrelu(a.z + bv.z)); m3 = fmaxf(m3, lrelu(a.w + bv.w));
        }
#pragma unroll
        for (int o = 32; o > 0; o >>= 1) {
            m0 = fmaxf(m0, __shfl_xor(m0, o)); m1 = fmaxf(m1, __shfl_xor(m1, o));
            m2 = fmaxf(m2, __shfl_xor(m2, o)); m3 = fmaxf(m3, __shfl_xor(m3, o));
        }
        float d0 = 0.f, d1 = 0.f, d2 = 0.f, d3 = 0.f;
        for (int j = beg + lane; j < end; j += 64) {
            float4 a = *(const float4*)&As[csrc[j] * 4];
            d0 += __expf(lrelu(a.x + bv.x) - m0); d1 += __expf(lrelu(a.y + bv.y) - m1);
            d2 += __expf(lrelu(a.z + bv.z) - m2); d3 += __expf(lrelu(a.w + bv.w) - m3);
        }
#pragma unroll
        for (int o = 32; o > 0; o >>= 1) {
            d0 += __shfl_xor(d0, o); d1 += __shfl_xor(d1, o);
            d2 += __shfl_xor(d2, o); d3 += __shfl_xor(d3, o);
        }
        for (int j = beg; j < end; j++) {
            int s = csrc[j];
            float4 a = *(const float4*)&As[s * 4];
            float w0 = __expf(lrelu(a.x + bv.x) - m0) / d0;
            float w1 = __expf(lrelu(a.y + bv.y) - m1) / d1;
            float w2 = __expf(lrelu(a.z + bv.z) - m2) / d2;
            float w3 = __expf(lrelu(a.w + bv.w) - m3) / d3;
            ushort4 v = *(const ushort4*)&hb[(size_t)s * 256 + lane * 4];
            acc0 += w0 * b2f(v.x); acc1 += w1 * b2f(v.y);
            acc2 += w2 * b2f(v.z); acc3 += w3 * b2f(v.w);
        }
    }
    float r0 = acc0 + bias[0 * 64 + lane];
    float r1 = acc1 + bias[1 * 64 + lane];
    float r2 = acc2 + bias[2 * 64 + lane];
    float r3 = acc3 + bias[3 * 64 + lane];
    r0 = r0 > 0.f ? r0 : expm1f(r0);
    r1 = r1 > 0.f ? r1 : expm1f(r1);
    r2 = r2 > 0.f ? r2 : expm1f(r2);
    r3 = r3 > 0.f ? r3 : expm1f(r3);
    size_t base = (size_t)node * 256;
    Outb[base + 0 * 64 + lane] = f2b(r0);
    Outb[base + 1 * 64 + lane] = f2b(r1);
    Outb[base + 2 * 64 + lane] = f2b(r2);
    Outb[base + 3 * 64 + lane] = f2b(r3);
}

// ---- layer-2 fused softmax + gather + bias + ELU + mean-pool accum (H=1) ----
__global__ void agg2_k(const int* __restrict__ rowptr, const int* __restrict__ csrc,
                       const float* __restrict__ As, const float* __restrict__ Ad,
                       const __hip_bfloat16* __restrict__ Hb,
                       const float* __restrict__ bias, const int* __restrict__ batch,
                       float* __restrict__ pooled, int nnodes) {
    __shared__ int ssh[4][64];
    __shared__ float wsh[4][64];
    int lane = threadIdx.x & 63;
    int w = threadIdx.x >> 6;
    int node = blockIdx.x * 4 + w;
    int beg = rowptr[node], end = rowptr[node + 1];
    int deg = end - beg;
    const unsigned short* hb = (const unsigned short*)Hb;
    float ad = Ad[node];
    bool fast = (deg <= 64);
    if (fast) {
        bool act = lane < deg;
        int s = act ? csrc[beg + lane] : 0;
        float e = lrelu(As[s] + ad);
        if (!act) e = -INFINITY;
        float m = e;
#pragma unroll
        for (int o = 32; o > 0; o >>= 1) m = fmaxf(m, __shfl_xor(m, o));
        float x = act ? __expf(e - m) : 0.f;
        float d = x;
#pragma unroll
        for (int o = 32; o > 0; o >>= 1) d += __shfl_xor(d, o);
        ssh[w][lane] = s;
        wsh[w][lane] = x / d;
    }
    __syncthreads();
    float acc = 0.f;
    if (fast) {
        float p = 0.f;
        int j = 0;
        for (; j + 2 <= deg; j += 2) {
            int sA = ssh[w][j], sB = ssh[w][j + 1];
            float wA = wsh[w][j], wB = wsh[w][j + 1];
            acc += wA * b2f(hb[(size_t)sA * 64 + lane]);
            p   += wB * b2f(hb[(size_t)sB * 64 + lane]);
        }
        if (j < deg) acc += wsh[w][j] * b2f(hb[(size_t)ssh[w][j] * 64 + lane]);
        acc += p;
    } else {
        float m = -INFINITY;
        for (int j = beg + lane; j < end; j += 64) m = fmaxf(m, lrelu(As[csrc[j]] + ad));
#pragma unroll
        for (int o = 32; o > 0; o >>= 1) m = fmaxf(m, __shfl_xor(m, o));
        float d = 0.f;
        for (int j = beg + lane; j < end; j += 64) d += __expf(lrelu(As[csrc[j]] + ad) - m);
#pragma unroll
        for (int o = 32; o > 0; o >>= 1) d += __shfl_xor(d, o);
        for (int j = beg; j < end; j++) {
            int s = csrc[j];
            float wt = __expf(lrelu(As[s] + ad) - m) / d;
            acc += wt * b2f(hb[(size_t)s * 64 + lane]);
        }
    }
    float v = acc + bias[lane];
    v = v > 0.f ? v : expm1f(v);
    atomicAdd(&pooled[batch[node] * 64 + lane], v);
}

// ---- final: out[g,:] = (pooled[g,:]/cnt) @ Wl + bl ----
__global__ void final_k(const float* __restrict__ pooled, const float* __restrict__ cnt,
                        const float* __restrict__ Wl, const float* __restrict__ bl,
                        float* __restrict__ out) {
    int g = blockIdx.x;
    int t = threadIdx.x;  // 64
    __shared__ float s[64];
    float c = cnt[g];
    c = c > 1.f ? c : 1.f;
    s[t] = pooled[g * 64 + t] / c;
    __syncthreads();
    if (t < OUT_CH) {
        float acc = bl[t];
        for (int k = 0; k < 64; k++) acc += s[k] * Wl[k * OUT_CH + t];
        out[g * OUT_CH + t] = acc;
    }
}

extern "C" void kernel_launch(void* const* d_in, const int* in_sizes, int n_in,
                              void* d_out, int out_size, void* d_ws, size_t ws_size,
                              hipStream_t stream) {
    const float* x    = (const float*)d_in[0];
    const int*   ei   = (const int*)d_in[1];
    const int*   batch= (const int*)d_in[2];
    const float* W1   = (const float*)d_in[3];
    const float* as1  = (const float*)d_in[4];
    const float* ad1  = (const float*)d_in[5];
    const float* b1   = (const float*)d_in[6];
    const float* W2   = (const float*)d_in[7];
    const float* as2  = (const float*)d_in[8];
    const float* ad2  = (const float*)d_in[9];
    const float* b2   = (const float*)d_in[10];
    const float* Wl   = (const float*)d_in[11];
    const float* bl   = (const float*)d_in[12];
    float* out = (float*)d_out;

    const int* src = ei;
    const int* dst = ei + N_EDGES;
    const int ETOT = N_EDGES + N_NODES;
    const int NB = (N_NODES + 255) / 256;   // 196

    char* ws = (char*)d_ws;
    size_t off = 0;
    auto alloc = [&](size_t bytes) {
        void* p = ws + off;
        off = (off + bytes + 255) & ~((size_t)255);
        return p;
    };
    unsigned short* h1b  = (unsigned short*)alloc((size_t)N_NODES * 256 * 2);
    unsigned short* out1b= (unsigned short*)alloc((size_t)N_NODES * 256 * 2);
    float* As1    = (float*)alloc((size_t)N_NODES * 4 * 4);
    float* Ad1    = (float*)alloc((size_t)N_NODES * 4 * 4);
    float* As2    = (float*)alloc((size_t)N_NODES * 4);
    float* Ad2    = (float*)alloc((size_t)N_NODES * 4);
    int*   deg    = (int*)  alloc((size_t)N_NODES * 4);
    int*   cursor = (int*)  alloc((size_t)N_NODES * 4);
    size_t zero1  = (char*)cursor + (size_t)N_NODES * 4 - (char*)deg;
    int*   rowptr = (int*)  alloc((size_t)(N_NODES + 1) * 4);
    int*   csrc   = (int*)  alloc((size_t)ETOT * 4);
    int*   bsum   = (int*)  alloc((size_t)NB * 4);
    float* pooled = (float*)alloc((size_t)N_GRAPHS * 64 * 4);
    float* cntf   = (float*)alloc((size_t)N_GRAPHS * 4);
    size_t zero2  = (char*)cntf + (size_t)N_GRAPHS * 4 - (char*)pooled;
    unsigned short* h2b = h1b;   // aliases h1b (dead after agg1_k)

    hipMemsetAsync(deg,    0, zero1, stream);   // deg + cursor (adjacent)
    hipMemsetAsync(pooled, 0, zero2, stream);   // pooled + cntf (adjacent)

    // ---- CSR build (shared by both layers) + per-graph counts ----
    hist_k<<<(ETOT + 255) / 256, 256, 0, stream>>>(dst, batch, deg, cntf, ETOT);
    blksum_k<<<NB, 256, 0, stream>>>(deg, bsum, N_NODES);
    scanb_k<<<1, 256, 0, stream>>>(bsum, NB);
    scanapply_k<<<NB, 256, 0, stream>>>(deg, bsum, rowptr, N_NODES);
    scatter_k<<<(ETOT + 255) / 256, 256, 0, stream>>>(src, dst, rowptr, cursor, csrc, ETOT);

    // ---- layer 1 (H=4): GEMM + fused attn coeffs ----
    {
        dim3 g((N_NODES + 63) / 64, 2);
        gemm_att_k<64, 128, 16, 8, IN_CH, 256, 4, false>
            <<<g, 256, 0, stream>>>(x, W1, h1b, as1, ad1, As1, Ad1, N_NODES);
    }
    agg1_k<<<N_NODES / 4, 256, 0, stream>>>(rowptr, csrc, As1, Ad1,
                                            (const __hip_bfloat16*)h1b, b1, out1b, N_NODES);

    // ---- layer 2 (H=1): bf16-input GEMM + fused attn coeffs ----
    {
        dim3 g((N_NODES + 63) / 64, 1);
        gemm_att_k<64, 64, 16, 4, 256, 64, 1, true>
            <<<g, 256, 0, stream>>>(out1b, W2, h2b, as2, ad2, As2, Ad2, N_NODES);
    }
    agg2_k<<<N_NODES / 4, 256, 0, stream>>>(rowptr, csrc, As2, Ad2,
                                            (const __hip_bfloat16*)h2b, b2, batch, pooled, N_NODES);

    // ---- head ----
    final_k<<<N_GRAPHS, 64, 0, stream>>>(pooled, cntf, Wl, bl, out);
}

// Round 10
// 319.035 us; speedup vs baseline: 4.6719x; 1.1108x over previous
//
#include <hip/hip_runtime.h>
#include <hip/hip_bf16.h>
#include <math.h>

#define N_NODES 50000
#define N_EDGES 800000
#define IN_CH 128
#define HID 64
#define HEADS 4
#define OUT_CH 10
#define N_GRAPHS 512
#define NEG_SLOPE 0.2f

using short8_t = __attribute__((ext_vector_type(8))) short;
using f32x4 = __attribute__((ext_vector_type(4))) float;

__device__ __forceinline__ float b2f(unsigned short u) {
    return __uint_as_float(((unsigned)u) << 16);
}
__device__ __forceinline__ unsigned short f2b(float f) {
    __hip_bfloat16 b = __float2bfloat16(f);
    return *(unsigned short*)&b;
}
__device__ __forceinline__ short f2bs(float f) {
    __hip_bfloat16 b = __float2bfloat16(f);
    return *(short*)&b;
}
__device__ __forceinline__ float lrelu(float x) { return x > 0.f ? x : NEG_SLOPE * x; }

// ---- convert+transpose weights: Wt1[n][k]=bf16(W1[k][n]), Wt2 likewise ----
__global__ void convw_k(const float* __restrict__ W1, const float* __restrict__ W2,
                        unsigned short* __restrict__ Wt1, unsigned short* __restrict__ Wt2) {
    int idx = blockIdx.x * 256 + threadIdx.x;
    if (idx < 256 * 128) {               // Wt1: [256][128]
        int n = idx / 128, k = idx % 128;
        Wt1[idx] = f2b(W1[(size_t)k * 256 + n]);
    }
    int j = idx - 256 * 128;
    if (j >= 0 && j < 64 * 256) {        // Wt2: [64][256]
        int n = j / 256, k = j % 256;
        Wt2[j] = f2b(W2[(size_t)k * 64 + n]);
    }
}

// ---- layer-1 MFMA GEMM (M x 256 = x[M][128] @ W1) + attn coeffs + bf16 out ----
// Per wave: 16 rows x 256 cols; 16 col-tiles x 4 k-chunks of 16x16x32 MFMA.
// A-frag: row=lane&15, k=(lane>>4)*8+j (fp32 load + cvt). B from Wt1[n][k].
// C/D: col=lane&15, row=(lane>>4)*4+reg [m89]. Output Yb[m][c*4+head] (ushort4).
__global__ __launch_bounds__(256) void mfma_gemm1_k(
        const float* __restrict__ X, const unsigned short* __restrict__ Wt,
        unsigned short* __restrict__ Yb,
        const float* __restrict__ asrc, const float* __restrict__ adst,
        float* __restrict__ As, float* __restrict__ Ad, int M) {
    const int lane = threadIdx.x & 63;
    const int w = threadIdx.x >> 6;
    const int r0 = blockIdx.x * 64 + w * 16;
    const int l15 = lane & 15;
    const int rc = min(r0 + l15, M - 1);
    const int kg = (lane >> 4) * 8;

    f32x4 acc[16] = {};
#pragma unroll
    for (int kc = 0; kc < 4; kc++) {
        int k0 = kc * 32 + kg;
        float4 xa = *(const float4*)&X[(size_t)rc * 128 + k0];
        float4 xb = *(const float4*)&X[(size_t)rc * 128 + k0 + 4];
        short8_t af;
        af[0] = f2bs(xa.x); af[1] = f2bs(xa.y); af[2] = f2bs(xa.z); af[3] = f2bs(xa.w);
        af[4] = f2bs(xb.x); af[5] = f2bs(xb.y); af[6] = f2bs(xb.z); af[7] = f2bs(xb.w);
#pragma unroll
        for (int ct = 0; ct < 16; ct++) {
            int col = ct * 16 + l15;
            short8_t bf = *(const short8_t*)&Wt[(size_t)col * 128 + k0];
            acc[ct] = __builtin_amdgcn_mfma_f32_16x16x32_bf16(af, bf, acc[ct], 0, 0, 0);
        }
    }

    const int rbase = r0 + (lane >> 4) * 4;
    // attention logits: As[gr][h] = sum_c h[c]*asrc[h][c]  (16-lane reduce)
#pragma unroll
    for (int reg = 0; reg < 4; reg++) {
        int gr = rbase + reg;
        float s0 = 0.f, s1 = 0.f, s2 = 0.f, s3 = 0.f;
        float d0 = 0.f, d1 = 0.f, d2 = 0.f, d3 = 0.f;
#pragma unroll
        for (int cg = 0; cg < 4; cg++) {
            int c = cg * 16 + l15;
            float v0 = acc[0 * 4 + cg][reg], v1 = acc[1 * 4 + cg][reg];
            float v2 = acc[2 * 4 + cg][reg], v3 = acc[3 * 4 + cg][reg];
            s0 += v0 * asrc[0 * 64 + c]; d0 += v0 * adst[0 * 64 + c];
            s1 += v1 * asrc[1 * 64 + c]; d1 += v1 * adst[1 * 64 + c];
            s2 += v2 * asrc[2 * 64 + c]; d2 += v2 * adst[2 * 64 + c];
            s3 += v3 * asrc[3 * 64 + c]; d3 += v3 * adst[3 * 64 + c];
        }
#pragma unroll
        for (int o = 8; o > 0; o >>= 1) {
            s0 += __shfl_xor(s0, o); d0 += __shfl_xor(d0, o);
            s1 += __shfl_xor(s1, o); d1 += __shfl_xor(d1, o);
            s2 += __shfl_xor(s2, o); d2 += __shfl_xor(d2, o);
            s3 += __shfl_xor(s3, o); d3 += __shfl_xor(d3, o);
        }
        if (l15 == 0 && gr < M) {
            *(float4*)&As[gr * 4] = make_float4(s0, s1, s2, s3);
            *(float4*)&Ad[gr * 4] = make_float4(d0, d1, d2, d3);
        }
    }
    // h store: head-interleaved, all 4 heads of channel c live in this lane
#pragma unroll
    for (int reg = 0; reg < 4; reg++) {
        int gr = rbase + reg;
        if (gr >= M) continue;
#pragma unroll
        for (int cg = 0; cg < 4; cg++) {
            int c = cg * 16 + l15;
            ushort4 p;
            p.x = f2b(acc[0 * 4 + cg][reg]);
            p.y = f2b(acc[1 * 4 + cg][reg]);
            p.z = f2b(acc[2 * 4 + cg][reg]);
            p.w = f2b(acc[3 * 4 + cg][reg]);
            *(ushort4*)&Yb[(size_t)gr * 256 + c * 4] = p;
        }
    }
}

// ---- layer-2 MFMA GEMM (M x 64 = out1b[M][256] @ W2) + attn coeffs + bf16 out ----
__global__ __launch_bounds__(256) void mfma_gemm2_k(
        const unsigned short* __restrict__ Xb, const unsigned short* __restrict__ Wt,
        unsigned short* __restrict__ Yb,
        const float* __restrict__ asrc, const float* __restrict__ adst,
        float* __restrict__ As, float* __restrict__ Ad, int M) {
    const int lane = threadIdx.x & 63;
    const int w = threadIdx.x >> 6;
    const int r0 = blockIdx.x * 64 + w * 16;
    const int l15 = lane & 15;
    const int rc = min(r0 + l15, M - 1);
    const int kg = (lane >> 4) * 8;

    f32x4 acc[4] = {};
#pragma unroll
    for (int kc = 0; kc < 8; kc++) {
        int k0 = kc * 32 + kg;
        short8_t af = *(const short8_t*)&Xb[(size_t)rc * 256 + k0];
#pragma unroll
        for (int ct = 0; ct < 4; ct++) {
            int col = ct * 16 + l15;
            short8_t bf = *(const short8_t*)&Wt[(size_t)col * 256 + k0];
            acc[ct] = __builtin_amdgcn_mfma_f32_16x16x32_bf16(af, bf, acc[ct], 0, 0, 0);
        }
    }

    const int rbase = r0 + (lane >> 4) * 4;
#pragma unroll
    for (int reg = 0; reg < 4; reg++) {
        int gr = rbase + reg;
        float sv = 0.f, dv = 0.f;
#pragma unroll
        for (int ct = 0; ct < 4; ct++) {
            int c = ct * 16 + l15;
            float v = acc[ct][reg];
            sv += v * asrc[c];
            dv += v * adst[c];
        }
#pragma unroll
        for (int o = 8; o > 0; o >>= 1) { sv += __shfl_xor(sv, o); dv += __shfl_xor(dv, o); }
        if (l15 == 0 && gr < M) { As[gr] = sv; Ad[gr] = dv; }
        if (gr < M) {
#pragma unroll
            for (int ct = 0; ct < 4; ct++)
                Yb[(size_t)gr * 64 + ct * 16 + l15] = f2b(acc[ct][reg]);
        }
    }
}

// ---- CSR build: histogram of dst (incl. self loops) + per-graph node count ----
__global__ void hist_k(const int* __restrict__ dst, const int* __restrict__ batch,
                       int* __restrict__ deg, float* __restrict__ cntf, int etot) {
    int i = blockIdx.x * blockDim.x + threadIdx.x;
    if (i < etot) {
        int d = (i < N_EDGES) ? dst[i] : i - N_EDGES;
        atomicAdd(&deg[d], 1);
    }
    if (i < N_NODES) atomicAdd(&cntf[batch[i]], 1.f);
}

// ---- 3-phase multi-block exclusive scan ----
__global__ void blksum_k(const int* __restrict__ deg, int* __restrict__ bsum, int n) {
    int t = threadIdx.x;
    int i = blockIdx.x * 256 + t;
    int v = (i < n) ? deg[i] : 0;
#pragma unroll
    for (int o = 32; o > 0; o >>= 1) v += __shfl_xor(v, o);
    __shared__ int wsum[4];
    if ((t & 63) == 0) wsum[t >> 6] = v;
    __syncthreads();
    if (t == 0) bsum[blockIdx.x] = wsum[0] + wsum[1] + wsum[2] + wsum[3];
}

__global__ void scanb_k(int* __restrict__ bsum, int nb) {
    __shared__ int tmp[256];
    int t = threadIdx.x;
    int v = (t < nb) ? bsum[t] : 0;
    tmp[t] = v;
    __syncthreads();
    for (int o = 1; o < 256; o <<= 1) {
        int u = (t >= o) ? tmp[t - o] : 0;
        __syncthreads();
        tmp[t] += u;
        __syncthreads();
    }
    if (t < nb) bsum[t] = tmp[t] - v;   // exclusive
}

__global__ void scanapply_k(const int* __restrict__ deg, const int* __restrict__ bsum,
                            int* __restrict__ rowptr, int n) {
    __shared__ int tmp[256];
    int t = threadIdx.x;
    int i = blockIdx.x * 256 + t;
    int v = (i < n) ? deg[i] : 0;
    tmp[t] = v;
    __syncthreads();
    for (int o = 1; o < 256; o <<= 1) {
        int u = (t >= o) ? tmp[t - o] : 0;
        __syncthreads();
        tmp[t] += u;
        __syncthreads();
    }
    int boff = bsum[blockIdx.x];
    if (i < n) rowptr[i] = boff + tmp[t] - v;
    if (i == n - 1) rowptr[n] = boff + tmp[t];
}

// ---- scatter src ids into CSR slots ----
__global__ void scatter_k(const int* __restrict__ src, const int* __restrict__ dst,
                          const int* __restrict__ rowptr, int* __restrict__ cursor,
                          int* __restrict__ csrc, int etot) {
    int i = blockIdx.x * blockDim.x + threadIdx.x;
    if (i >= etot) return;
    int s, d;
    if (i < N_EDGES) { s = src[i]; d = dst[i]; } else { s = d = i - N_EDGES; }
    int pos = rowptr[d] + atomicAdd(&cursor[d], 1);
    csrc[pos] = s;
}

// ---- layer-1 fused softmax + gather + bias + ELU (H=4), bf16 output ----
__global__ void agg1_k(const int* __restrict__ rowptr, const int* __restrict__ csrc,
                       const float* __restrict__ As, const float* __restrict__ Ad,
                       const __hip_bfloat16* __restrict__ Hb,
                       const float* __restrict__ bias,
                       unsigned short* __restrict__ Outb, int nnodes) {
    __shared__ int ssh[4][64];
    __shared__ float4 wsh[4][64];
    int lane = threadIdx.x & 63;
    int w = threadIdx.x >> 6;
    int node = blockIdx.x * 4 + w;
    int beg = rowptr[node], end = rowptr[node + 1];
    int deg = end - beg;
    const unsigned short* hb = (const unsigned short*)Hb;
    float4 bv = *(const float4*)&Ad[node * 4];
    bool fast = (deg <= 64);
    if (fast) {
        bool act = lane < deg;
        int s = act ? csrc[beg + lane] : 0;
        float4 a = *(const float4*)&As[s * 4];
        float e0 = lrelu(a.x + bv.x), e1 = lrelu(a.y + bv.y);
        float e2 = lrelu(a.z + bv.z), e3 = lrelu(a.w + bv.w);
        if (!act) { e0 = e1 = e2 = e3 = -INFINITY; }
        float m0 = e0, m1 = e1, m2 = e2, m3 = e3;
#pragma unroll
        for (int o = 32; o > 0; o >>= 1) {
            m0 = fmaxf(m0, __shfl_xor(m0, o)); m1 = fmaxf(m1, __shfl_xor(m1, o));
            m2 = fmaxf(m2, __shfl_xor(m2, o)); m3 = fmaxf(m3, __shfl_xor(m3, o));
        }
        float x0 = act ? __expf(e0 - m0) : 0.f;
        float x1 = act ? __expf(e1 - m1) : 0.f;
        float x2 = act ? __expf(e2 - m2) : 0.f;
        float x3 = act ? __expf(e3 - m3) : 0.f;
        float d0 = x0, d1 = x1, d2 = x2, d3 = x3;
#pragma unroll
        for (int o = 32; o > 0; o >>= 1) {
            d0 += __shfl_xor(d0, o); d1 += __shfl_xor(d1, o);
            d2 += __shfl_xor(d2, o); d3 += __shfl_xor(d3, o);
        }
        ssh[w][lane] = s;
        wsh[w][lane] = make_float4(x0 / d0, x1 / d1, x2 / d2, x3 / d3);
    }
    __syncthreads();
    float acc0 = 0.f, acc1 = 0.f, acc2 = 0.f, acc3 = 0.f;
    if (fast) {
        float p0 = 0.f, p1 = 0.f, p2 = 0.f, p3 = 0.f;
        int j = 0;
        for (; j + 2 <= deg; j += 2) {
            int sA = ssh[w][j], sB = ssh[w][j + 1];
            float4 wA = wsh[w][j], wB = wsh[w][j + 1];
            ushort4 vA = *(const ushort4*)&hb[(size_t)sA * 256 + lane * 4];
            ushort4 vB = *(const ushort4*)&hb[(size_t)sB * 256 + lane * 4];
            acc0 += wA.x * b2f(vA.x); p0 += wB.x * b2f(vB.x);
            acc1 += wA.y * b2f(vA.y); p1 += wB.y * b2f(vB.y);
            acc2 += wA.z * b2f(vA.z); p2 += wB.z * b2f(vB.z);
            acc3 += wA.w * b2f(vA.w); p3 += wB.w * b2f(vB.w);
        }
        if (j < deg) {
            int s = ssh[w][j];
            float4 wt = wsh[w][j];
            ushort4 v = *(const ushort4*)&hb[(size_t)s * 256 + lane * 4];
            acc0 += wt.x * b2f(v.x); acc1 += wt.y * b2f(v.y);
            acc2 += wt.z * b2f(v.z); acc3 += wt.w * b2f(v.w);
        }
        acc0 += p0; acc1 += p1; acc2 += p2; acc3 += p3;
    } else {
        float m0 = -INFINITY, m1 = -INFINITY, m2 = -INFINITY, m3 = -INFINITY;
        for (int j = beg + lane; j < end; j += 64) {
            float4 a = *(const float4*)&As[csrc[j] * 4];
            m0 = fmaxf(m0, lrelu(a.x + bv.x)); m1 = fmaxf(m1, lrelu(a.y + bv.y));
            m2 = fmaxf(m2, lrelu(a.z + bv.z)); m3 = fmaxf(m3, lrelu(a.w + bv.w));
        }
#pragma unroll
        for (int o = 32; o > 0; o >>= 1) {
            m0 = fmaxf(m0, __shfl_xor(m0, o)); m1 = fmaxf(m1, __shfl_xor(m1, o));
            m2 = fmaxf(m2, __shfl_xor(m2, o)); m3 = fmaxf(m3, __shfl_xor(m3, o));
        }
        float d0 = 0.f, d1 = 0.f, d2 = 0.f, d3 = 0.f;
        for (int j = beg + lane; j < end; j += 64) {
            float4 a = *(const float4*)&As[csrc[j] * 4];
            d0 += __expf(lrelu(a.x + bv.x) - m0); d1 += __expf(lrelu(a.y + bv.y) - m1);
            d2 += __expf(lrelu(a.z + bv.z) - m2); d3 += __expf(lrelu(a.w + bv.w) - m3);
        }
#pragma unroll
        for (int o = 32; o > 0; o >>= 1) {
            d0 += __shfl_xor(d0, o); d1 += __shfl_xor(d1, o);
            d2 += __shfl_xor(d2, o); d3 += __shfl_xor(d3, o);
        }
        for (int j = beg; j < end; j++) {
            int s = csrc[j];
            float4 a = *(const float4*)&As[s * 4];
            float w0 = __expf(lrelu(a.x + bv.x) - m0) / d0;
            float w1 = __expf(lrelu(a.y + bv.y) - m1) / d1;
            float w2 = __expf(lrelu(a.z + bv.z) - m2) / d2;
            float w3 = __expf(lrelu(a.w + bv.w) - m3) / d3;
            ushort4 v = *(const ushort4*)&hb[(size_t)s * 256 + lane * 4];
            acc0 += w0 * b2f(v.x); acc1 += w1 * b2f(v.y);
            acc2 += w2 * b2f(v.z); acc3 += w3 * b2f(v.w);
        }
    }
    float r0 = acc0 + bias[0 * 64 + lane];
    float r1 = acc1 + bias[1 * 64 + lane];
    float r2 = acc2 + bias[2 * 64 + lane];
    float r3 = acc3 + bias[3 * 64 + lane];
    r0 = r0 > 0.f ? r0 : expm1f(r0);
    r1 = r1 > 0.f ? r1 : expm1f(r1);
    r2 = r2 > 0.f ? r2 : expm1f(r2);
    r3 = r3 > 0.f ? r3 : expm1f(r3);
    size_t base = (size_t)node * 256;
    Outb[base + 0 * 64 + lane] = f2b(r0);
    Outb[base + 1 * 64 + lane] = f2b(r1);
    Outb[base + 2 * 64 + lane] = f2b(r2);
    Outb[base + 3 * 64 + lane] = f2b(r3);
}

// ---- layer-2 fused softmax + gather + bias + ELU + mean-pool accum (H=1) ----
__global__ void agg2_k(const int* __restrict__ rowptr, const int* __restrict__ csrc,
                       const float* __restrict__ As, const float* __restrict__ Ad,
                       const __hip_bfloat16* __restrict__ Hb,
                       const float* __restrict__ bias, const int* __restrict__ batch,
                       float* __restrict__ pooled, int nnodes) {
    __shared__ int ssh[4][64];
    __shared__ float wsh[4][64];
    int lane = threadIdx.x & 63;
    int w = threadIdx.x >> 6;
    int node = blockIdx.x * 4 + w;
    int beg = rowptr[node], end = rowptr[node + 1];
    int deg = end - beg;
    const unsigned short* hb = (const unsigned short*)Hb;
    float ad = Ad[node];
    bool fast = (deg <= 64);
    if (fast) {
        bool act = lane < deg;
        int s = act ? csrc[beg + lane] : 0;
        float e = lrelu(As[s] + ad);
        if (!act) e = -INFINITY;
        float m = e;
#pragma unroll
        for (int o = 32; o > 0; o >>= 1) m = fmaxf(m, __shfl_xor(m, o));
        float x = act ? __expf(e - m) : 0.f;
        float d = x;
#pragma unroll
        for (int o = 32; o > 0; o >>= 1) d += __shfl_xor(d, o);
        ssh[w][lane] = s;
        wsh[w][lane] = x / d;
    }
    __syncthreads();
    float acc = 0.f;
    if (fast) {
        float p = 0.f;
        int j = 0;
        for (; j + 2 <= deg; j += 2) {
            int sA = ssh[w][j], sB = ssh[w][j + 1];
            float wA = wsh[w][j], wB = wsh[w][j + 1];
            acc += wA * b2f(hb[(size_t)sA * 64 + lane]);
            p   += wB * b2f(hb[(size_t)sB * 64 + lane]);
        }
        if (j < deg) acc += wsh[w][j] * b2f(hb[(size_t)ssh[w][j] * 64 + lane]);
        acc += p;
    } else {
        float m = -INFINITY;
        for (int j = beg + lane; j < end; j += 64) m = fmaxf(m, lrelu(As[csrc[j]] + ad));
#pragma unroll
        for (int o = 32; o > 0; o >>= 1) m = fmaxf(m, __shfl_xor(m, o));
        float d = 0.f;
        for (int j = beg + lane; j < end; j += 64) d += __expf(lrelu(As[csrc[j]] + ad) - m);
#pragma unroll
        for (int o = 32; o > 0; o >>= 1) d += __shfl_xor(d, o);
        for (int j = beg; j < end; j++) {
            int s = csrc[j];
            float wt = __expf(lrelu(As[s] + ad) - m) / d;
            acc += wt * b2f(hb[(size_t)s * 64 + lane]);
        }
    }
    float v = acc + bias[lane];
    v = v > 0.f ? v : expm1f(v);
    atomicAdd(&pooled[batch[node] * 64 + lane], v);
}

// ---- final: out[g,:] = (pooled[g,:]/cnt) @ Wl + bl ----
__global__ void final_k(const float* __restrict__ pooled, const float* __restrict__ cnt,
                        const float* __restrict__ Wl, const float* __restrict__ bl,
                        float* __restrict__ out) {
    int g = blockIdx.x;
    int t = threadIdx.x;  // 64
    __shared__ float s[64];
    float c = cnt[g];
    c = c > 1.f ? c : 1.f;
    s[t] = pooled[g * 64 + t] / c;
    __syncthreads();
    if (t < OUT_CH) {
        float acc = bl[t];
        for (int k = 0; k < 64; k++) acc += s[k] * Wl[k * OUT_CH + t];
        out[g * OUT_CH + t] = acc;
    }
}

extern "C" void kernel_launch(void* const* d_in, const int* in_sizes, int n_in,
                              void* d_out, int out_size, void* d_ws, size_t ws_size,
                              hipStream_t stream) {
    const float* x    = (const float*)d_in[0];
    const int*   ei   = (const int*)d_in[1];
    const int*   batch= (const int*)d_in[2];
    const float* W1   = (const float*)d_in[3];
    const float* as1  = (const float*)d_in[4];
    const float* ad1  = (const float*)d_in[5];
    const float* b1   = (const float*)d_in[6];
    const float* W2   = (const float*)d_in[7];
    const float* as2  = (const float*)d_in[8];
    const float* ad2  = (const float*)d_in[9];
    const float* b2   = (const float*)d_in[10];
    const float* Wl   = (const float*)d_in[11];
    const float* bl   = (const float*)d_in[12];
    float* out = (float*)d_out;

    const int* src = ei;
    const int* dst = ei + N_EDGES;
    const int ETOT = N_EDGES + N_NODES;
    const int NB = (N_NODES + 255) / 256;   // 196

    char* ws = (char*)d_ws;
    size_t off = 0;
    auto alloc = [&](size_t bytes) {
        void* p = ws + off;
        off = (off + bytes + 255) & ~((size_t)255);
        return p;
    };
    unsigned short* h1b  = (unsigned short*)alloc((size_t)N_NODES * 256 * 2);
    unsigned short* out1b= (unsigned short*)alloc((size_t)N_NODES * 256 * 2);
    float* As1    = (float*)alloc((size_t)N_NODES * 4 * 4);
    float* Ad1    = (float*)alloc((size_t)N_NODES * 4 * 4);
    float* As2    = (float*)alloc((size_t)N_NODES * 4);
    float* Ad2    = (float*)alloc((size_t)N_NODES * 4);
    int*   deg    = (int*)  alloc((size_t)N_NODES * 4);
    int*   cursor = (int*)  alloc((size_t)N_NODES * 4);
    size_t zero1  = (char*)cursor + (size_t)N_NODES * 4 - (char*)deg;
    int*   rowptr = (int*)  alloc((size_t)(N_NODES + 1) * 4);
    int*   csrc   = (int*)  alloc((size_t)ETOT * 4);
    int*   bsum   = (int*)  alloc((size_t)NB * 4);
    unsigned short* Wt1 = (unsigned short*)alloc((size_t)256 * 128 * 2);
    unsigned short* Wt2 = (unsigned short*)alloc((size_t)64 * 256 * 2);
    float* pooled = (float*)alloc((size_t)N_GRAPHS * 64 * 4);
    float* cntf   = (float*)alloc((size_t)N_GRAPHS * 4);
    size_t zero2  = (char*)cntf + (size_t)N_GRAPHS * 4 - (char*)pooled;
    unsigned short* h2b = h1b;   // aliases h1b (dead after agg1_k)

    hipMemsetAsync(deg,    0, zero1, stream);   // deg + cursor (adjacent)
    hipMemsetAsync(pooled, 0, zero2, stream);   // pooled + cntf (adjacent)

    // ---- CSR build (shared by both layers) + per-graph counts + weight conv ----
    hist_k<<<(ETOT + 255) / 256, 256, 0, stream>>>(dst, batch, deg, cntf, ETOT);
    blksum_k<<<NB, 256, 0, stream>>>(deg, bsum, N_NODES);
    scanb_k<<<1, 256, 0, stream>>>(bsum, NB);
    scanapply_k<<<NB, 256, 0, stream>>>(deg, bsum, rowptr, N_NODES);
    scatter_k<<<(ETOT + 255) / 256, 256, 0, stream>>>(src, dst, rowptr, cursor, csrc, ETOT);
    convw_k<<<192, 256, 0, stream>>>(W1, W2, Wt1, Wt2);

    // ---- layer 1 (H=4): MFMA GEMM + fused attn coeffs ----
    mfma_gemm1_k<<<(N_NODES + 63) / 64, 256, 0, stream>>>(x, Wt1, h1b, as1, ad1,
                                                          As1, Ad1, N_NODES);
    agg1_k<<<N_NODES / 4, 256, 0, stream>>>(rowptr, csrc, As1, Ad1,
                                            (const __hip_bfloat16*)h1b, b1, out1b, N_NODES);

    // ---- layer 2 (H=1): MFMA GEMM + fused attn coeffs ----
    mfma_gemm2_k<<<(N_NODES + 63) / 64, 256, 0, stream>>>(out1b, Wt2, h2b, as2, ad2,
                                                          As2, Ad2, N_NODES);
    agg2_k<<<N_NODES / 4, 256, 0, stream>>>(rowptr, csrc, As2, Ad2,
                                            (const __hip_bfloat16*)h2b, b2, batch, pooled, N_NODES);

    // ---- head ----
    final_k<<<N_GRAPHS, 64, 0, stream>>>(pooled, cntf, Wl, bl, out);
}

// Round 11
// 262.426 us; speedup vs baseline: 5.6797x; 1.2157x over previous
//
#include <hip/hip_runtime.h>
#include <hip/hip_bf16.h>
#include <math.h>

#define N_NODES 50000
#define N_EDGES 800000
#define IN_CH 128
#define HID 64
#define HEADS 4
#define OUT_CH 10
#define N_GRAPHS 512
#define NEG_SLOPE 0.2f

using short8_t = __attribute__((ext_vector_type(8))) short;
using f32x4 = __attribute__((ext_vector_type(4))) float;

__device__ __forceinline__ float b2f(unsigned short u) {
    return __uint_as_float(((unsigned)u) << 16);
}
__device__ __forceinline__ unsigned short f2b(float f) {
    __hip_bfloat16 b = __float2bfloat16(f);
    return *(unsigned short*)&b;
}
__device__ __forceinline__ short f2bs(float f) {
    __hip_bfloat16 b = __float2bfloat16(f);
    return *(short*)&b;
}
__device__ __forceinline__ float lrelu(float x) { return x > 0.f ? x : NEG_SLOPE * x; }

// ---- convert+transpose weights: Wt1[n][k]=bf16(W1[k][n]), Wt2 likewise ----
__global__ void convw_k(const float* __restrict__ W1, const float* __restrict__ W2,
                        unsigned short* __restrict__ Wt1, unsigned short* __restrict__ Wt2) {
    int idx = blockIdx.x * 256 + threadIdx.x;
    if (idx < 256 * 128) {               // Wt1: [256][128]
        int n = idx / 128, k = idx % 128;
        Wt1[idx] = f2b(W1[(size_t)k * 256 + n]);
    }
    int j = idx - 256 * 128;
    if (j >= 0 && j < 64 * 256) {        // Wt2: [64][256]
        int n = j / 256, k = j % 256;
        Wt2[j] = f2b(W2[(size_t)k * 64 + n]);
    }
}

// ---- layer-1 MFMA GEMM (M x 256 = x[M][128] @ W1) + attn coeffs + bf16 out ----
__global__ __launch_bounds__(256) void mfma_gemm1_k(
        const float* __restrict__ X, const unsigned short* __restrict__ Wt,
        unsigned short* __restrict__ Yb,
        const float* __restrict__ asrc, const float* __restrict__ adst,
        float* __restrict__ As, float* __restrict__ Ad, int M) {
    const int lane = threadIdx.x & 63;
    const int w = threadIdx.x >> 6;
    const int r0 = blockIdx.x * 64 + w * 16;
    const int l15 = lane & 15;
    const int rc = min(r0 + l15, M - 1);
    const int kg = (lane >> 4) * 8;

    f32x4 acc[16] = {};
#pragma unroll
    for (int kc = 0; kc < 4; kc++) {
        int k0 = kc * 32 + kg;
        float4 xa = *(const float4*)&X[(size_t)rc * 128 + k0];
        float4 xb = *(const float4*)&X[(size_t)rc * 128 + k0 + 4];
        short8_t af;
        af[0] = f2bs(xa.x); af[1] = f2bs(xa.y); af[2] = f2bs(xa.z); af[3] = f2bs(xa.w);
        af[4] = f2bs(xb.x); af[5] = f2bs(xb.y); af[6] = f2bs(xb.z); af[7] = f2bs(xb.w);
#pragma unroll
        for (int ct = 0; ct < 16; ct++) {
            int col = ct * 16 + l15;
            short8_t bf = *(const short8_t*)&Wt[(size_t)col * 128 + k0];
            acc[ct] = __builtin_amdgcn_mfma_f32_16x16x32_bf16(af, bf, acc[ct], 0, 0, 0);
        }
    }

    const int rbase = r0 + (lane >> 4) * 4;
#pragma unroll
    for (int reg = 0; reg < 4; reg++) {
        int gr = rbase + reg;
        float s0 = 0.f, s1 = 0.f, s2 = 0.f, s3 = 0.f;
        float d0 = 0.f, d1 = 0.f, d2 = 0.f, d3 = 0.f;
#pragma unroll
        for (int cg = 0; cg < 4; cg++) {
            int c = cg * 16 + l15;
            float v0 = acc[0 * 4 + cg][reg], v1 = acc[1 * 4 + cg][reg];
            float v2 = acc[2 * 4 + cg][reg], v3 = acc[3 * 4 + cg][reg];
            s0 += v0 * asrc[0 * 64 + c]; d0 += v0 * adst[0 * 64 + c];
            s1 += v1 * asrc[1 * 64 + c]; d1 += v1 * adst[1 * 64 + c];
            s2 += v2 * asrc[2 * 64 + c]; d2 += v2 * adst[2 * 64 + c];
            s3 += v3 * asrc[3 * 64 + c]; d3 += v3 * adst[3 * 64 + c];
        }
#pragma unroll
        for (int o = 8; o > 0; o >>= 1) {
            s0 += __shfl_xor(s0, o); d0 += __shfl_xor(d0, o);
            s1 += __shfl_xor(s1, o); d1 += __shfl_xor(d1, o);
            s2 += __shfl_xor(s2, o); d2 += __shfl_xor(d2, o);
            s3 += __shfl_xor(s3, o); d3 += __shfl_xor(d3, o);
        }
        if (l15 == 0 && gr < M) {
            *(float4*)&As[gr * 4] = make_float4(s0, s1, s2, s3);
            *(float4*)&Ad[gr * 4] = make_float4(d0, d1, d2, d3);
        }
    }
#pragma unroll
    for (int reg = 0; reg < 4; reg++) {
        int gr = rbase + reg;
        if (gr >= M) continue;
#pragma unroll
        for (int cg = 0; cg < 4; cg++) {
            int c = cg * 16 + l15;
            ushort4 p;
            p.x = f2b(acc[0 * 4 + cg][reg]);
            p.y = f2b(acc[1 * 4 + cg][reg]);
            p.z = f2b(acc[2 * 4 + cg][reg]);
            p.w = f2b(acc[3 * 4 + cg][reg]);
            *(ushort4*)&Yb[(size_t)gr * 256 + c * 4] = p;
        }
    }
}

// ---- layer-2 MFMA GEMM (M x 64 = out1b[M][256] @ W2) + attn coeffs + bf16 out ----
__global__ __launch_bounds__(256) void mfma_gemm2_k(
        const unsigned short* __restrict__ Xb, const unsigned short* __restrict__ Wt,
        unsigned short* __restrict__ Yb,
        const float* __restrict__ asrc, const float* __restrict__ adst,
        float* __restrict__ As, float* __restrict__ Ad, int M) {
    const int lane = threadIdx.x & 63;
    const int w = threadIdx.x >> 6;
    const int r0 = blockIdx.x * 64 + w * 16;
    const int l15 = lane & 15;
    const int rc = min(r0 + l15, M - 1);
    const int kg = (lane >> 4) * 8;

    f32x4 acc[4] = {};
#pragma unroll
    for (int kc = 0; kc < 8; kc++) {
        int k0 = kc * 32 + kg;
        short8_t af = *(const short8_t*)&Xb[(size_t)rc * 256 + k0];
#pragma unroll
        for (int ct = 0; ct < 4; ct++) {
            int col = ct * 16 + l15;
            short8_t bf = *(const short8_t*)&Wt[(size_t)col * 256 + k0];
            acc[ct] = __builtin_amdgcn_mfma_f32_16x16x32_bf16(af, bf, acc[ct], 0, 0, 0);
        }
    }

    const int rbase = r0 + (lane >> 4) * 4;
#pragma unroll
    for (int reg = 0; reg < 4; reg++) {
        int gr = rbase + reg;
        float sv = 0.f, dv = 0.f;
#pragma unroll
        for (int ct = 0; ct < 4; ct++) {
            int c = ct * 16 + l15;
            float v = acc[ct][reg];
            sv += v * asrc[c];
            dv += v * adst[c];
        }
#pragma unroll
        for (int o = 8; o > 0; o >>= 1) { sv += __shfl_xor(sv, o); dv += __shfl_xor(dv, o); }
        if (l15 == 0 && gr < M) { As[gr] = sv; Ad[gr] = dv; }
        if (gr < M) {
#pragma unroll
            for (int ct = 0; ct < 4; ct++)
                Yb[(size_t)gr * 64 + ct * 16 + l15] = f2b(acc[ct][reg]);
        }
    }
}

// ---- CSR build: histogram of dst + per-edge within-node rank (4-way ILP) ----
__global__ void hist_k(const int* __restrict__ dst, int* __restrict__ deg,
                       int* __restrict__ rank, int etot) {
    int nth = gridDim.x * 256;
    int i0 = blockIdx.x * 256 + threadIdx.x;
    int i1 = i0 + nth, i2 = i0 + 2 * nth, i3 = i0 + 3 * nth;
    bool v0 = i0 < etot, v1 = i1 < etot, v2 = i2 < etot, v3 = i3 < etot;
    int d0 = 0, d1 = 0, d2 = 0, d3 = 0;
    if (v0) d0 = (i0 < N_EDGES) ? dst[i0] : i0 - N_EDGES;
    if (v1) d1 = (i1 < N_EDGES) ? dst[i1] : i1 - N_EDGES;
    if (v2) d2 = (i2 < N_EDGES) ? dst[i2] : i2 - N_EDGES;
    if (v3) d3 = (i3 < N_EDGES) ? dst[i3] : i3 - N_EDGES;
    int r0 = 0, r1 = 0, r2 = 0, r3 = 0;
    if (v0) r0 = atomicAdd(&deg[d0], 1);
    if (v1) r1 = atomicAdd(&deg[d1], 1);
    if (v2) r2 = atomicAdd(&deg[d2], 1);
    if (v3) r3 = atomicAdd(&deg[d3], 1);
    if (v0) rank[i0] = r0;
    if (v1) rank[i1] = r1;
    if (v2) rank[i2] = r2;
    if (v3) rank[i3] = r3;
}

// ---- per-graph node counts via binary search on sorted batch ----
__global__ void cntg_k(const int* __restrict__ batch, float* __restrict__ cntf) {
    int g = blockIdx.x * 256 + threadIdx.x;
    if (g >= N_GRAPHS) return;
    int lo = 0, hi = N_NODES;
    while (lo < hi) { int mid = (lo + hi) >> 1; if (batch[mid] < g) lo = mid + 1; else hi = mid; }
    int lo2 = lo, hi2 = N_NODES;
    while (lo2 < hi2) { int mid = (lo2 + hi2) >> 1; if (batch[mid] < g + 1) lo2 = mid + 1; else hi2 = mid; }
    cntf[g] = (float)(lo2 - lo);
}

// ---- 3-phase multi-block exclusive scan ----
__global__ void blksum_k(const int* __restrict__ deg, int* __restrict__ bsum, int n) {
    int t = threadIdx.x;
    int i = blockIdx.x * 256 + t;
    int v = (i < n) ? deg[i] : 0;
#pragma unroll
    for (int o = 32; o > 0; o >>= 1) v += __shfl_xor(v, o);
    __shared__ int wsum[4];
    if ((t & 63) == 0) wsum[t >> 6] = v;
    __syncthreads();
    if (t == 0) bsum[blockIdx.x] = wsum[0] + wsum[1] + wsum[2] + wsum[3];
}

__global__ void scanb_k(int* __restrict__ bsum, int nb) {
    __shared__ int tmp[256];
    int t = threadIdx.x;
    int v = (t < nb) ? bsum[t] : 0;
    tmp[t] = v;
    __syncthreads();
    for (int o = 1; o < 256; o <<= 1) {
        int u = (t >= o) ? tmp[t - o] : 0;
        __syncthreads();
        tmp[t] += u;
        __syncthreads();
    }
    if (t < nb) bsum[t] = tmp[t] - v;   // exclusive
}

__global__ void scanapply_k(const int* __restrict__ deg, const int* __restrict__ bsum,
                            int* __restrict__ rowptr, int n) {
    __shared__ int tmp[256];
    int t = threadIdx.x;
    int i = blockIdx.x * 256 + t;
    int v = (i < n) ? deg[i] : 0;
    tmp[t] = v;
    __syncthreads();
    for (int o = 1; o < 256; o <<= 1) {
        int u = (t >= o) ? tmp[t - o] : 0;
        __syncthreads();
        tmp[t] += u;
        __syncthreads();
    }
    int boff = bsum[blockIdx.x];
    if (i < n) rowptr[i] = boff + tmp[t] - v;
    if (i == n - 1) rowptr[n] = boff + tmp[t];
}

// ---- scatter src ids into CSR slots (atomic-free: uses saved rank) ----
__global__ void scatter_k(const int* __restrict__ src, const int* __restrict__ dst,
                          const int* __restrict__ rowptr, const int* __restrict__ rank,
                          int* __restrict__ csrc, int etot) {
    int i = blockIdx.x * blockDim.x + threadIdx.x;
    if (i >= etot) return;
    int s, d;
    if (i < N_EDGES) { s = src[i]; d = dst[i]; } else { s = d = i - N_EDGES; }
    csrc[rowptr[d] + rank[i]] = s;
}

// ---- layer-1 fused softmax + gather + bias + ELU (H=4), bf16 output ----
__global__ void agg1_k(const int* __restrict__ rowptr, const int* __restrict__ csrc,
                       const float* __restrict__ As, const float* __restrict__ Ad,
                       const __hip_bfloat16* __restrict__ Hb,
                       const float* __restrict__ bias,
                       unsigned short* __restrict__ Outb, int nnodes) {
    __shared__ int ssh[4][64];
    __shared__ float4 wsh[4][64];
    int lane = threadIdx.x & 63;
    int w = threadIdx.x >> 6;
    int node = blockIdx.x * 4 + w;
    int beg = rowptr[node], end = rowptr[node + 1];
    int deg = end - beg;
    const unsigned short* hb = (const unsigned short*)Hb;
    float4 bv = *(const float4*)&Ad[node * 4];
    bool fast = (deg <= 64);
    if (fast) {
        bool act = lane < deg;
        int s = act ? csrc[beg + lane] : 0;
        float4 a = *(const float4*)&As[s * 4];
        float e0 = lrelu(a.x + bv.x), e1 = lrelu(a.y + bv.y);
        float e2 = lrelu(a.z + bv.z), e3 = lrelu(a.w + bv.w);
        if (!act) { e0 = e1 = e2 = e3 = -INFINITY; }
        float m0 = e0, m1 = e1, m2 = e2, m3 = e3;
#pragma unroll
        for (int o = 32; o > 0; o >>= 1) {
            m0 = fmaxf(m0, __shfl_xor(m0, o)); m1 = fmaxf(m1, __shfl_xor(m1, o));
            m2 = fmaxf(m2, __shfl_xor(m2, o)); m3 = fmaxf(m3, __shfl_xor(m3, o));
        }
        float x0 = act ? __expf(e0 - m0) : 0.f;
        float x1 = act ? __expf(e1 - m1) : 0.f;
        float x2 = act ? __expf(e2 - m2) : 0.f;
        float x3 = act ? __expf(e3 - m3) : 0.f;
        float d0 = x0, d1 = x1, d2 = x2, d3 = x3;
#pragma unroll
        for (int o = 32; o > 0; o >>= 1) {
            d0 += __shfl_xor(d0, o); d1 += __shfl_xor(d1, o);
            d2 += __shfl_xor(d2, o); d3 += __shfl_xor(d3, o);
        }
        ssh[w][lane] = s;
        wsh[w][lane] = make_float4(x0 / d0, x1 / d1, x2 / d2, x3 / d3);
    }
    __syncthreads();
    float acc0 = 0.f, acc1 = 0.f, acc2 = 0.f, acc3 = 0.f;
    if (fast) {
        float p0 = 0.f, p1 = 0.f, p2 = 0.f, p3 = 0.f;
        int j = 0;
        for (; j + 2 <= deg; j += 2) {
            int sA = ssh[w][j], sB = ssh[w][j + 1];
            float4 wA = wsh[w][j], wB = wsh[w][j + 1];
            ushort4 vA = *(const ushort4*)&hb[(size_t)sA * 256 + lane * 4];
            ushort4 vB = *(const ushort4*)&hb[(size_t)sB * 256 + lane * 4];
            acc0 += wA.x * b2f(vA.x); p0 += wB.x * b2f(vB.x);
            acc1 += wA.y * b2f(vA.y); p1 += wB.y * b2f(vB.y);
            acc2 += wA.z * b2f(vA.z); p2 += wB.z * b2f(vB.z);
            acc3 += wA.w * b2f(vA.w); p3 += wB.w * b2f(vB.w);
        }
        if (j < deg) {
            int s = ssh[w][j];
            float4 wt = wsh[w][j];
            ushort4 v = *(const ushort4*)&hb[(size_t)s * 256 + lane * 4];
            acc0 += wt.x * b2f(v.x); acc1 += wt.y * b2f(v.y);
            acc2 += wt.z * b2f(v.z); acc3 += wt.w * b2f(v.w);
        }
        acc0 += p0; acc1 += p1; acc2 += p2; acc3 += p3;
    } else {
        float m0 = -INFINITY, m1 = -INFINITY, m2 = -INFINITY, m3 = -INFINITY;
        for (int j = beg + lane; j < end; j += 64) {
            float4 a = *(const float4*)&As[csrc[j] * 4];
            m0 = fmaxf(m0, lrelu(a.x + bv.x)); m1 = fmaxf(m1, lrelu(a.y + bv.y));
            m2 = fmaxf(m2, lrelu(a.z + bv.z)); m3 = fmaxf(m3, lrelu(a.w + bv.w));
        }
#pragma unroll
        for (int o = 32; o > 0; o >>= 1) {
            m0 = fmaxf(m0, __shfl_xor(m0, o)); m1 = fmaxf(m1, __shfl_xor(m1, o));
            m2 = fmaxf(m2, __shfl_xor(m2, o)); m3 = fmaxf(m3, __shfl_xor(m3, o));
        }
        float d0 = 0.f, d1 = 0.f, d2 = 0.f, d3 = 0.f;
        for (int j = beg + lane; j < end; j += 64) {
            float4 a = *(const float4*)&As[csrc[j] * 4];
            d0 += __expf(lrelu(a.x + bv.x) - m0); d1 += __expf(lrelu(a.y + bv.y) - m1);
            d2 += __expf(lrelu(a.z + bv.z) - m2); d3 += __expf(lrelu(a.w + bv.w) - m3);
        }
#pragma unroll
        for (int o = 32; o > 0; o >>= 1) {
            d0 += __shfl_xor(d0, o); d1 += __shfl_xor(d1, o);
            d2 += __shfl_xor(d2, o); d3 += __shfl_xor(d3, o);
        }
        for (int j = beg; j < end; j++) {
            int s = csrc[j];
            float4 a = *(const float4*)&As[s * 4];
            float w0 = __expf(lrelu(a.x + bv.x) - m0) / d0;
            float w1 = __expf(lrelu(a.y + bv.y) - m1) / d1;
            float w2 = __expf(lrelu(a.z + bv.z) - m2) / d2;
            float w3 = __expf(lrelu(a.w + bv.w) - m3) / d3;
            ushort4 v = *(const ushort4*)&hb[(size_t)s * 256 + lane * 4];
            acc0 += w0 * b2f(v.x); acc1 += w1 * b2f(v.y);
            acc2 += w2 * b2f(v.z); acc3 += w3 * b2f(v.w);
        }
    }
    float r0 = acc0 + bias[0 * 64 + lane];
    float r1 = acc1 + bias[1 * 64 + lane];
    float r2 = acc2 + bias[2 * 64 + lane];
    float r3 = acc3 + bias[3 * 64 + lane];
    r0 = r0 > 0.f ? r0 : expm1f(r0);
    r1 = r1 > 0.f ? r1 : expm1f(r1);
    r2 = r2 > 0.f ? r2 : expm1f(r2);
    r3 = r3 > 0.f ? r3 : expm1f(r3);
    size_t base = (size_t)node * 256;
    Outb[base + 0 * 64 + lane] = f2b(r0);
    Outb[base + 1 * 64 + lane] = f2b(r1);
    Outb[base + 2 * 64 + lane] = f2b(r2);
    Outb[base + 3 * 64 + lane] = f2b(r3);
}

// ---- layer-2 fused softmax + gather + bias + ELU + mean-pool accum (H=1) ----
__global__ void agg2_k(const int* __restrict__ rowptr, const int* __restrict__ csrc,
                       const float* __restrict__ As, const float* __restrict__ Ad,
                       const __hip_bfloat16* __restrict__ Hb,
                       const float* __restrict__ bias, const int* __restrict__ batch,
                       float* __restrict__ pooled, int nnodes) {
    __shared__ int ssh[4][64];
    __shared__ float wsh[4][64];
    int lane = threadIdx.x & 63;
    int w = threadIdx.x >> 6;
    int node = blockIdx.x * 4 + w;
    int beg = rowptr[node], end = rowptr[node + 1];
    int deg = end - beg;
    const unsigned short* hb = (const unsigned short*)Hb;
    float ad = Ad[node];
    bool fast = (deg <= 64);
    if (fast) {
        bool act = lane < deg;
        int s = act ? csrc[beg + lane] : 0;
        float e = lrelu(As[s] + ad);
        if (!act) e = -INFINITY;
        float m = e;
#pragma unroll
        for (int o = 32; o > 0; o >>= 1) m = fmaxf(m, __shfl_xor(m, o));
        float x = act ? __expf(e - m) : 0.f;
        float d = x;
#pragma unroll
        for (int o = 32; o > 0; o >>= 1) d += __shfl_xor(d, o);
        ssh[w][lane] = s;
        wsh[w][lane] = x / d;
    }
    __syncthreads();
    float acc = 0.f;
    if (fast) {
        float p = 0.f;
        int j = 0;
        for (; j + 2 <= deg; j += 2) {
            int sA = ssh[w][j], sB = ssh[w][j + 1];
            float wA = wsh[w][j], wB = wsh[w][j + 1];
            acc += wA * b2f(hb[(size_t)sA * 64 + lane]);
            p   += wB * b2f(hb[(size_t)sB * 64 + lane]);
        }
        if (j < deg) acc += wsh[w][j] * b2f(hb[(size_t)ssh[w][j] * 64 + lane]);
        acc += p;
    } else {
        float m = -INFINITY;
        for (int j = beg + lane; j < end; j += 64) m = fmaxf(m, lrelu(As[csrc[j]] + ad));
#pragma unroll
        for (int o = 32; o > 0; o >>= 1) m = fmaxf(m, __shfl_xor(m, o));
        float d = 0.f;
        for (int j = beg + lane; j < end; j += 64) d += __expf(lrelu(As[csrc[j]] + ad) - m);
#pragma unroll
        for (int o = 32; o > 0; o >>= 1) d += __shfl_xor(d, o);
        for (int j = beg; j < end; j++) {
            int s = csrc[j];
            float wt = __expf(lrelu(As[s] + ad) - m) / d;
            acc += wt * b2f(hb[(size_t)s * 64 + lane]);
        }
    }
    float v = acc + bias[lane];
    v = v > 0.f ? v : expm1f(v);
    atomicAdd(&pooled[batch[node] * 64 + lane], v);
}

// ---- final: out[g,:] = (pooled[g,:]/cnt) @ Wl + bl ----
__global__ void final_k(const float* __restrict__ pooled, const float* __restrict__ cnt,
                        const float* __restrict__ Wl, const float* __restrict__ bl,
                        float* __restrict__ out) {
    int g = blockIdx.x;
    int t = threadIdx.x;  // 64
    __shared__ float s[64];
    float c = cnt[g];
    c = c > 1.f ? c : 1.f;
    s[t] = pooled[g * 64 + t] / c;
    __syncthreads();
    if (t < OUT_CH) {
        float acc = bl[t];
        for (int k = 0; k < 64; k++) acc += s[k] * Wl[k * OUT_CH + t];
        out[g * OUT_CH + t] = acc;
    }
}

extern "C" void kernel_launch(void* const* d_in, const int* in_sizes, int n_in,
                              void* d_out, int out_size, void* d_ws, size_t ws_size,
                              hipStream_t stream) {
    const float* x    = (const float*)d_in[0];
    const int*   ei   = (const int*)d_in[1];
    const int*   batch= (const int*)d_in[2];
    const float* W1   = (const float*)d_in[3];
    const float* as1  = (const float*)d_in[4];
    const float* ad1  = (const float*)d_in[5];
    const float* b1   = (const float*)d_in[6];
    const float* W2   = (const float*)d_in[7];
    const float* as2  = (const float*)d_in[8];
    const float* ad2  = (const float*)d_in[9];
    const float* b2   = (const float*)d_in[10];
    const float* Wl   = (const float*)d_in[11];
    const float* bl   = (const float*)d_in[12];
    float* out = (float*)d_out;

    const int* src = ei;
    const int* dst = ei + N_EDGES;
    const int ETOT = N_EDGES + N_NODES;
    const int NB = (N_NODES + 255) / 256;   // 196

    char* ws = (char*)d_ws;
    size_t off = 0;
    auto alloc = [&](size_t bytes) {
        void* p = ws + off;
        off = (off + bytes + 255) & ~((size_t)255);
        return p;
    };
    unsigned short* h1b  = (unsigned short*)alloc((size_t)N_NODES * 256 * 2);
    unsigned short* out1b= (unsigned short*)alloc((size_t)N_NODES * 256 * 2);
    float* As1    = (float*)alloc((size_t)N_NODES * 4 * 4);
    float* Ad1    = (float*)alloc((size_t)N_NODES * 4 * 4);
    float* As2    = (float*)alloc((size_t)N_NODES * 4);
    float* Ad2    = (float*)alloc((size_t)N_NODES * 4);
    int*   deg    = (int*)  alloc((size_t)N_NODES * 4);
    int*   rowptr = (int*)  alloc((size_t)(N_NODES + 1) * 4);
    int*   csrc   = (int*)  alloc((size_t)ETOT * 4);
    int*   rank   = (int*)  alloc((size_t)ETOT * 4);
    int*   bsum   = (int*)  alloc((size_t)NB * 4);
    unsigned short* Wt1 = (unsigned short*)alloc((size_t)256 * 128 * 2);
    unsigned short* Wt2 = (unsigned short*)alloc((size_t)64 * 256 * 2);
    float* pooled = (float*)alloc((size_t)N_GRAPHS * 64 * 4);
    float* cntf   = (float*)alloc((size_t)N_GRAPHS * 4);
    unsigned short* h2b = h1b;   // aliases h1b (dead after agg1_k)

    hipMemsetAsync(deg,    0, (size_t)N_NODES * 4, stream);
    hipMemsetAsync(pooled, 0, (size_t)N_GRAPHS * 64 * 4, stream);

    // ---- CSR build + per-graph counts + weight conv ----
    hist_k<<<(ETOT / 4 + 255) / 256, 256, 0, stream>>>(dst, deg, rank, ETOT);
    cntg_k<<<2, 256, 0, stream>>>(batch, cntf);
    blksum_k<<<NB, 256, 0, stream>>>(deg, bsum, N_NODES);
    scanb_k<<<1, 256, 0, stream>>>(bsum, NB);
    scanapply_k<<<NB, 256, 0, stream>>>(deg, bsum, rowptr, N_NODES);
    scatter_k<<<(ETOT + 255) / 256, 256, 0, stream>>>(src, dst, rowptr, rank, csrc, ETOT);
    convw_k<<<192, 256, 0, stream>>>(W1, W2, Wt1, Wt2);

    // ---- layer 1 (H=4): MFMA GEMM + fused attn coeffs ----
    mfma_gemm1_k<<<(N_NODES + 63) / 64, 256, 0, stream>>>(x, Wt1, h1b, as1, ad1,
                                                          As1, Ad1, N_NODES);
    agg1_k<<<N_NODES / 4, 256, 0, stream>>>(rowptr, csrc, As1, Ad1,
                                            (const __hip_bfloat16*)h1b, b1, out1b, N_NODES);

    // ---- layer 2 (H=1): MFMA GEMM + fused attn coeffs ----
    mfma_gemm2_k<<<(N_NODES + 63) / 64, 256, 0, stream>>>(out1b, Wt2, h2b, as2, ad2,
                                                          As2, Ad2, N_NODES);
    agg2_k<<<N_NODES / 4, 256, 0, stream>>>(rowptr, csrc, As2, Ad2,
                                            (const __hip_bfloat16*)h2b, b2, batch, pooled, N_NODES);

    // ---- head ----
    final_k<<<N_GRAPHS, 64, 0, stream>>>(pooled, cntf, Wl, bl, out);
}

// Round 12
// 234.585 us; speedup vs baseline: 6.3538x; 1.1187x over previous
//
#include <hip/hip_runtime.h>
#include <hip/hip_bf16.h>
#include <math.h>

#define N_NODES 50000
#define N_EDGES 800000
#define IN_CH 128
#define HID 64
#define HEADS 4
#define OUT_CH 10
#define N_GRAPHS 512
#define NEG_SLOPE 0.2f

#define ETOT_C (N_EDGES + N_NODES)          // 850000
#define GB1 ((N_NODES + 63) / 64)           // 782 gemm1 blocks
#define GH  ((ETOT_C / 4 + 255) / 256)      // 831 hist blocks (4-way ILP)
#define GZ  32                              // pooled-zero blocks

using short8_t = __attribute__((ext_vector_type(8))) short;
using f32x4 = __attribute__((ext_vector_type(4))) float;

__device__ __forceinline__ float b2f(unsigned short u) {
    return __uint_as_float(((unsigned)u) << 16);
}
__device__ __forceinline__ unsigned short f2b(float f) {
    __hip_bfloat16 b = __float2bfloat16(f);
    return *(unsigned short*)&b;
}
__device__ __forceinline__ short f2bs(float f) {
    __hip_bfloat16 b = __float2bfloat16(f);
    return *(short*)&b;
}
__device__ __forceinline__ float lrelu(float x) { return x > 0.f ? x : NEG_SLOPE * x; }

// ---- convert+transpose weights: Wt1[n][k]=bf16(W1[k][n]), Wt2 likewise ----
__global__ void convw_k(const float* __restrict__ W1, const float* __restrict__ W2,
                        unsigned short* __restrict__ Wt1, unsigned short* __restrict__ Wt2) {
    int idx = blockIdx.x * 256 + threadIdx.x;
    if (idx < 256 * 128) {               // Wt1: [256][128]
        int n = idx / 128, k = idx % 128;
        Wt1[idx] = f2b(W1[(size_t)k * 256 + n]);
    }
    int j = idx - 256 * 128;
    if (j >= 0 && j < 64 * 256) {        // Wt2: [64][256]
        int n = j / 256, k = j % 256;
        Wt2[j] = f2b(W2[(size_t)k * 64 + n]);
    }
}

// ---- MEGA 1: gemm1 (MFMA) || hist (atomics) || cntg || pooled-zero ----
// Independent work fused into one launch so the atomic/latency-bound hist
// overlaps the MFMA-bound gemm1 on disjoint pipes instead of serializing.
__global__ __launch_bounds__(256) void mega1_k(
        const float* __restrict__ X, const unsigned short* __restrict__ Wt,
        unsigned short* __restrict__ Yb,
        const float* __restrict__ asrc, const float* __restrict__ adst,
        float* __restrict__ As, float* __restrict__ Ad, int M,
        const int* __restrict__ dst, int* __restrict__ deg, int* __restrict__ rank,
        const int* __restrict__ batch, float* __restrict__ cntf,
        float* __restrict__ pooled) {
    int b = blockIdx.x;
    if (b < GB1) {
        // ---------------- gemm1: rows b*64..b*64+63 ----------------
        const int lane = threadIdx.x & 63;
        const int w = threadIdx.x >> 6;
        const int r0 = b * 64 + w * 16;
        const int l15 = lane & 15;
        const int rc = min(r0 + l15, M - 1);
        const int kg = (lane >> 4) * 8;

        f32x4 acc[16] = {};
#pragma unroll
        for (int kc = 0; kc < 4; kc++) {
            int k0 = kc * 32 + kg;
            float4 xa = *(const float4*)&X[(size_t)rc * 128 + k0];
            float4 xb = *(const float4*)&X[(size_t)rc * 128 + k0 + 4];
            short8_t af;
            af[0] = f2bs(xa.x); af[1] = f2bs(xa.y); af[2] = f2bs(xa.z); af[3] = f2bs(xa.w);
            af[4] = f2bs(xb.x); af[5] = f2bs(xb.y); af[6] = f2bs(xb.z); af[7] = f2bs(xb.w);
#pragma unroll
            for (int ct = 0; ct < 16; ct++) {
                int col = ct * 16 + l15;
                short8_t bf = *(const short8_t*)&Wt[(size_t)col * 128 + k0];
                acc[ct] = __builtin_amdgcn_mfma_f32_16x16x32_bf16(af, bf, acc[ct], 0, 0, 0);
            }
        }

        const int rbase = r0 + (lane >> 4) * 4;
#pragma unroll
        for (int reg = 0; reg < 4; reg++) {
            int gr = rbase + reg;
            float s0 = 0.f, s1 = 0.f, s2 = 0.f, s3 = 0.f;
            float d0 = 0.f, d1 = 0.f, d2 = 0.f, d3 = 0.f;
#pragma unroll
            for (int cg = 0; cg < 4; cg++) {
                int c = cg * 16 + l15;
                float v0 = acc[0 * 4 + cg][reg], v1 = acc[1 * 4 + cg][reg];
                float v2 = acc[2 * 4 + cg][reg], v3 = acc[3 * 4 + cg][reg];
                s0 += v0 * asrc[0 * 64 + c]; d0 += v0 * adst[0 * 64 + c];
                s1 += v1 * asrc[1 * 64 + c]; d1 += v1 * adst[1 * 64 + c];
                s2 += v2 * asrc[2 * 64 + c]; d2 += v2 * adst[2 * 64 + c];
                s3 += v3 * asrc[3 * 64 + c]; d3 += v3 * adst[3 * 64 + c];
            }
#pragma unroll
            for (int o = 8; o > 0; o >>= 1) {
                s0 += __shfl_xor(s0, o); d0 += __shfl_xor(d0, o);
                s1 += __shfl_xor(s1, o); d1 += __shfl_xor(d1, o);
                s2 += __shfl_xor(s2, o); d2 += __shfl_xor(d2, o);
                s3 += __shfl_xor(s3, o); d3 += __shfl_xor(d3, o);
            }
            if (l15 == 0 && gr < M) {
                *(float4*)&As[gr * 4] = make_float4(s0, s1, s2, s3);
                *(float4*)&Ad[gr * 4] = make_float4(d0, d1, d2, d3);
            }
        }
#pragma unroll
        for (int reg = 0; reg < 4; reg++) {
            int gr = rbase + reg;
            if (gr >= M) continue;
#pragma unroll
            for (int cg = 0; cg < 4; cg++) {
                int c = cg * 16 + l15;
                ushort4 p;
                p.x = f2b(acc[0 * 4 + cg][reg]);
                p.y = f2b(acc[1 * 4 + cg][reg]);
                p.z = f2b(acc[2 * 4 + cg][reg]);
                p.w = f2b(acc[3 * 4 + cg][reg]);
                *(ushort4*)&Yb[(size_t)gr * 256 + c * 4] = p;
            }
        }
        return;
    }
    b -= GB1;
    if (b < GH) {
        // ---------------- hist: deg histogram + per-edge rank (4-way ILP) ----
        const int nth = GH * 256;
        int i0 = b * 256 + threadIdx.x;
        int i1 = i0 + nth, i2 = i0 + 2 * nth, i3 = i0 + 3 * nth;
        bool v0 = i0 < ETOT_C, v1 = i1 < ETOT_C, v2 = i2 < ETOT_C, v3 = i3 < ETOT_C;
        int d0 = 0, d1 = 0, d2 = 0, d3 = 0;
        if (v0) d0 = (i0 < N_EDGES) ? dst[i0] : i0 - N_EDGES;
        if (v1) d1 = (i1 < N_EDGES) ? dst[i1] : i1 - N_EDGES;
        if (v2) d2 = (i2 < N_EDGES) ? dst[i2] : i2 - N_EDGES;
        if (v3) d3 = (i3 < N_EDGES) ? dst[i3] : i3 - N_EDGES;
        int r0 = 0, r1 = 0, r2 = 0, r3 = 0;
        if (v0) r0 = atomicAdd(&deg[d0], 1);
        if (v1) r1 = atomicAdd(&deg[d1], 1);
        if (v2) r2 = atomicAdd(&deg[d2], 1);
        if (v3) r3 = atomicAdd(&deg[d3], 1);
        if (v0) rank[i0] = r0;
        if (v1) rank[i1] = r1;
        if (v2) rank[i2] = r2;
        if (v3) rank[i3] = r3;
        return;
    }
    b -= GH;
    if (b < 2) {
        // ---------------- cntg: per-graph node counts (binary search) ----
        int g = b * 256 + threadIdx.x;
        if (g >= N_GRAPHS) return;
        int lo = 0, hi = N_NODES;
        while (lo < hi) { int mid = (lo + hi) >> 1; if (batch[mid] < g) lo = mid + 1; else hi = mid; }
        int lo2 = lo, hi2 = N_NODES;
        while (lo2 < hi2) { int mid = (lo2 + hi2) >> 1; if (batch[mid] < g + 1) lo2 = mid + 1; else hi2 = mid; }
        cntf[g] = (float)(lo2 - lo);
        return;
    }
    b -= 2;
    // ---------------- pooled zero: 32 blocks x 256 threads x float4 ----
    int idx = b * 256 + threadIdx.x;
    *(float4*)&pooled[(size_t)idx * 4] = make_float4(0.f, 0.f, 0.f, 0.f);
}

// ---- layer-2 MFMA GEMM (M x 64 = out1b[M][256] @ W2) + attn coeffs + bf16 out ----
__global__ __launch_bounds__(256) void mfma_gemm2_k(
        const unsigned short* __restrict__ Xb, const unsigned short* __restrict__ Wt,
        unsigned short* __restrict__ Yb,
        const float* __restrict__ asrc, const float* __restrict__ adst,
        float* __restrict__ As, float* __restrict__ Ad, int M) {
    const int lane = threadIdx.x & 63;
    const int w = threadIdx.x >> 6;
    const int r0 = blockIdx.x * 64 + w * 16;
    const int l15 = lane & 15;
    const int rc = min(r0 + l15, M - 1);
    const int kg = (lane >> 4) * 8;

    f32x4 acc[4] = {};
#pragma unroll
    for (int kc = 0; kc < 8; kc++) {
        int k0 = kc * 32 + kg;
        short8_t af = *(const short8_t*)&Xb[(size_t)rc * 256 + k0];
#pragma unroll
        for (int ct = 0; ct < 4; ct++) {
            int col = ct * 16 + l15;
            short8_t bf = *(const short8_t*)&Wt[(size_t)col * 256 + k0];
            acc[ct] = __builtin_amdgcn_mfma_f32_16x16x32_bf16(af, bf, acc[ct], 0, 0, 0);
        }
    }

    const int rbase = r0 + (lane >> 4) * 4;
#pragma unroll
    for (int reg = 0; reg < 4; reg++) {
        int gr = rbase + reg;
        float sv = 0.f, dv = 0.f;
#pragma unroll
        for (int ct = 0; ct < 4; ct++) {
            int c = ct * 16 + l15;
            float v = acc[ct][reg];
            sv += v * asrc[c];
            dv += v * adst[c];
        }
#pragma unroll
        for (int o = 8; o > 0; o >>= 1) { sv += __shfl_xor(sv, o); dv += __shfl_xor(dv, o); }
        if (l15 == 0 && gr < M) { As[gr] = sv; Ad[gr] = dv; }
        if (gr < M) {
#pragma unroll
            for (int ct = 0; ct < 4; ct++)
                Yb[(size_t)gr * 64 + ct * 16 + l15] = f2b(acc[ct][reg]);
        }
    }
}

// ---- 3-phase multi-block exclusive scan ----
__global__ void blksum_k(const int* __restrict__ deg, int* __restrict__ bsum, int n) {
    int t = threadIdx.x;
    int i = blockIdx.x * 256 + t;
    int v = (i < n) ? deg[i] : 0;
#pragma unroll
    for (int o = 32; o > 0; o >>= 1) v += __shfl_xor(v, o);
    __shared__ int wsum[4];
    if ((t & 63) == 0) wsum[t >> 6] = v;
    __syncthreads();
    if (t == 0) bsum[blockIdx.x] = wsum[0] + wsum[1] + wsum[2] + wsum[3];
}

__global__ void scanb_k(int* __restrict__ bsum, int nb) {
    __shared__ int tmp[256];
    int t = threadIdx.x;
    int v = (t < nb) ? bsum[t] : 0;
    tmp[t] = v;
    __syncthreads();
    for (int o = 1; o < 256; o <<= 1) {
        int u = (t >= o) ? tmp[t - o] : 0;
        __syncthreads();
        tmp[t] += u;
        __syncthreads();
    }
    if (t < nb) bsum[t] = tmp[t] - v;   // exclusive
}

__global__ void scanapply_k(const int* __restrict__ deg, const int* __restrict__ bsum,
                            int* __restrict__ rowptr, int n) {
    __shared__ int tmp[256];
    int t = threadIdx.x;
    int i = blockIdx.x * 256 + t;
    int v = (i < n) ? deg[i] : 0;
    tmp[t] = v;
    __syncthreads();
    for (int o = 1; o < 256; o <<= 1) {
        int u = (t >= o) ? tmp[t - o] : 0;
        __syncthreads();
        tmp[t] += u;
        __syncthreads();
    }
    int boff = bsum[blockIdx.x];
    if (i < n) rowptr[i] = boff + tmp[t] - v;
    if (i == n - 1) rowptr[n] = boff + tmp[t];
}

// ---- scatter src ids into CSR slots (atomic-free: uses saved rank) ----
__global__ void scatter_k(const int* __restrict__ src, const int* __restrict__ dst,
                          const int* __restrict__ rowptr, const int* __restrict__ rank,
                          int* __restrict__ csrc, int etot) {
    int i = blockIdx.x * blockDim.x + threadIdx.x;
    if (i >= etot) return;
    int s, d;
    if (i < N_EDGES) { s = src[i]; d = dst[i]; } else { s = d = i - N_EDGES; }
    csrc[rowptr[d] + rank[i]] = s;
}

// ---- layer-1 fused softmax + gather + bias + ELU (H=4), bf16 output ----
__global__ void agg1_k(const int* __restrict__ rowptr, const int* __restrict__ csrc,
                       const float* __restrict__ As, const float* __restrict__ Ad,
                       const __hip_bfloat16* __restrict__ Hb,
                       const float* __restrict__ bias,
                       unsigned short* __restrict__ Outb, int nnodes) {
    __shared__ int ssh[4][64];
    __shared__ float4 wsh[4][64];
    int lane = threadIdx.x & 63;
    int w = threadIdx.x >> 6;
    int node = blockIdx.x * 4 + w;
    int beg = rowptr[node], end = rowptr[node + 1];
    int deg = end - beg;
    const unsigned short* hb = (const unsigned short*)Hb;
    float4 bv = *(const float4*)&Ad[node * 4];
    bool fast = (deg <= 64);
    if (fast) {
        bool act = lane < deg;
        int s = act ? csrc[beg + lane] : 0;
        float4 a = *(const float4*)&As[s * 4];
        float e0 = lrelu(a.x + bv.x), e1 = lrelu(a.y + bv.y);
        float e2 = lrelu(a.z + bv.z), e3 = lrelu(a.w + bv.w);
        if (!act) { e0 = e1 = e2 = e3 = -INFINITY; }
        float m0 = e0, m1 = e1, m2 = e2, m3 = e3;
#pragma unroll
        for (int o = 32; o > 0; o >>= 1) {
            m0 = fmaxf(m0, __shfl_xor(m0, o)); m1 = fmaxf(m1, __shfl_xor(m1, o));
            m2 = fmaxf(m2, __shfl_xor(m2, o)); m3 = fmaxf(m3, __shfl_xor(m3, o));
        }
        float x0 = act ? __expf(e0 - m0) : 0.f;
        float x1 = act ? __expf(e1 - m1) : 0.f;
        float x2 = act ? __expf(e2 - m2) : 0.f;
        float x3 = act ? __expf(e3 - m3) : 0.f;
        float d0 = x0, d1 = x1, d2 = x2, d3 = x3;
#pragma unroll
        for (int o = 32; o > 0; o >>= 1) {
            d0 += __shfl_xor(d0, o); d1 += __shfl_xor(d1, o);
            d2 += __shfl_xor(d2, o); d3 += __shfl_xor(d3, o);
        }
        ssh[w][lane] = s;
        wsh[w][lane] = make_float4(x0 / d0, x1 / d1, x2 / d2, x3 / d3);
    }
    __syncthreads();
    float acc0 = 0.f, acc1 = 0.f, acc2 = 0.f, acc3 = 0.f;
    if (fast) {
        float p0 = 0.f, p1 = 0.f, p2 = 0.f, p3 = 0.f;
        int j = 0;
        for (; j + 4 <= deg; j += 4) {
            int sA = ssh[w][j], sB = ssh[w][j + 1], sC = ssh[w][j + 2], sD = ssh[w][j + 3];
            float4 wA = wsh[w][j], wB = wsh[w][j + 1], wC = wsh[w][j + 2], wD = wsh[w][j + 3];
            ushort4 vA = *(const ushort4*)&hb[(size_t)sA * 256 + lane * 4];
            ushort4 vB = *(const ushort4*)&hb[(size_t)sB * 256 + lane * 4];
            ushort4 vC = *(const ushort4*)&hb[(size_t)sC * 256 + lane * 4];
            ushort4 vD = *(const ushort4*)&hb[(size_t)sD * 256 + lane * 4];
            acc0 += wA.x * b2f(vA.x) + wC.x * b2f(vC.x);
            p0   += wB.x * b2f(vB.x) + wD.x * b2f(vD.x);
            acc1 += wA.y * b2f(vA.y) + wC.y * b2f(vC.y);
            p1   += wB.y * b2f(vB.y) + wD.y * b2f(vD.y);
            acc2 += wA.z * b2f(vA.z) + wC.z * b2f(vC.z);
            p2   += wB.z * b2f(vB.z) + wD.z * b2f(vD.z);
            acc3 += wA.w * b2f(vA.w) + wC.w * b2f(vC.w);
            p3   += wB.w * b2f(vB.w) + wD.w * b2f(vD.w);
        }
        for (; j < deg; j++) {
            int s = ssh[w][j];
            float4 wt = wsh[w][j];
            ushort4 v = *(const ushort4*)&hb[(size_t)s * 256 + lane * 4];
            acc0 += wt.x * b2f(v.x); acc1 += wt.y * b2f(v.y);
            acc2 += wt.z * b2f(v.z); acc3 += wt.w * b2f(v.w);
        }
        acc0 += p0; acc1 += p1; acc2 += p2; acc3 += p3;
    } else {
        float m0 = -INFINITY, m1 = -INFINITY, m2 = -INFINITY, m3 = -INFINITY;
        for (int j = beg + lane; j < end; j += 64) {
            float4 a = *(const float4*)&As[csrc[j] * 4];
            m0 = fmaxf(m0, lrelu(a.x + bv.x)); m1 = fmaxf(m1, lrelu(a.y + bv.y));
            m2 = fmaxf(m2, lrelu(a.z + bv.z)); m3 = fmaxf(m3, lrelu(a.w + bv.w));
        }
#pragma unroll
        for (int o = 32; o > 0; o >>= 1) {
            m0 = fmaxf(m0, __shfl_xor(m0, o)); m1 = fmaxf(m1, __shfl_xor(m1, o));
            m2 = fmaxf(m2, __shfl_xor(m2, o)); m3 = fmaxf(m3, __shfl_xor(m3, o));
        }
        float d0 = 0.f, d1 = 0.f, d2 = 0.f, d3 = 0.f;
        for (int j = beg + lane; j < end; j += 64) {
            float4 a = *(const float4*)&As[csrc[j] * 4];
            d0 += __expf(lrelu(a.x + bv.x) - m0); d1 += __expf(lrelu(a.y + bv.y) - m1);
            d2 += __expf(lrelu(a.z + bv.z) - m2); d3 += __expf(lrelu(a.w + bv.w) - m3);
        }
#pragma unroll
        for (int o = 32; o > 0; o >>= 1) {
            d0 += __shfl_xor(d0, o); d1 += __shfl_xor(d1, o);
            d2 += __shfl_xor(d2, o); d3 += __shfl_xor(d3, o);
        }
        for (int j = beg; j < end; j++) {
            int s = csrc[j];
            float4 a = *(const float4*)&As[s * 4];
            float w0 = __expf(lrelu(a.x + bv.x) - m0) / d0;
            float w1 = __expf(lrelu(a.y + bv.y) - m1) / d1;
            float w2 = __expf(lrelu(a.z + bv.z) - m2) / d2;
            float w3 = __expf(lrelu(a.w + bv.w) - m3) / d3;
            ushort4 v = *(const ushort4*)&hb[(size_t)s * 256 + lane * 4];
            acc0 += w0 * b2f(v.x); acc1 += w1 * b2f(v.y);
            acc2 += w2 * b2f(v.z); acc3 += w3 * b2f(v.w);
        }
    }
    float r0 = acc0 + bias[0 * 64 + lane];
    float r1 = acc1 + bias[1 * 64 + lane];
    float r2 = acc2 + bias[2 * 64 + lane];
    float r3 = acc3 + bias[3 * 64 + lane];
    r0 = r0 > 0.f ? r0 : expm1f(r0);
    r1 = r1 > 0.f ? r1 : expm1f(r1);
    r2 = r2 > 0.f ? r2 : expm1f(r2);
    r3 = r3 > 0.f ? r3 : expm1f(r3);
    size_t base = (size_t)node * 256;
    Outb[base + 0 * 64 + lane] = f2b(r0);
    Outb[base + 1 * 64 + lane] = f2b(r1);
    Outb[base + 2 * 64 + lane] = f2b(r2);
    Outb[base + 3 * 64 + lane] = f2b(r3);
}

// ---- layer-2 fused softmax + gather + bias + ELU + mean-pool accum (H=1) ----
__global__ void agg2_k(const int* __restrict__ rowptr, const int* __restrict__ csrc,
                       const float* __restrict__ As, const float* __restrict__ Ad,
                       const __hip_bfloat16* __restrict__ Hb,
                       const float* __restrict__ bias, const int* __restrict__ batch,
                       float* __restrict__ pooled, int nnodes) {
    __shared__ int ssh[4][64];
    __shared__ float wsh[4][64];
    int lane = threadIdx.x & 63;
    int w = threadIdx.x >> 6;
    int node = blockIdx.x * 4 + w;
    int beg = rowptr[node], end = rowptr[node + 1];
    int deg = end - beg;
    const unsigned short* hb = (const unsigned short*)Hb;
    float ad = Ad[node];
    bool fast = (deg <= 64);
    if (fast) {
        bool act = lane < deg;
        int s = act ? csrc[beg + lane] : 0;
        float e = lrelu(As[s] + ad);
        if (!act) e = -INFINITY;
        float m = e;
#pragma unroll
        for (int o = 32; o > 0; o >>= 1) m = fmaxf(m, __shfl_xor(m, o));
        float x = act ? __expf(e - m) : 0.f;
        float d = x;
#pragma unroll
        for (int o = 32; o > 0; o >>= 1) d += __shfl_xor(d, o);
        ssh[w][lane] = s;
        wsh[w][lane] = x / d;
    }
    __syncthreads();
    float acc = 0.f;
    if (fast) {
        float p = 0.f;
        int j = 0;
        for (; j + 4 <= deg; j += 4) {
            int sA = ssh[w][j], sB = ssh[w][j + 1], sC = ssh[w][j + 2], sD = ssh[w][j + 3];
            float wA = wsh[w][j], wB = wsh[w][j + 1], wC = wsh[w][j + 2], wD = wsh[w][j + 3];
            acc += wA * b2f(hb[(size_t)sA * 64 + lane]) + wC * b2f(hb[(size_t)sC * 64 + lane]);
            p   += wB * b2f(hb[(size_t)sB * 64 + lane]) + wD * b2f(hb[(size_t)sD * 64 + lane]);
        }
        for (; j < deg; j++) acc += wsh[w][j] * b2f(hb[(size_t)ssh[w][j] * 64 + lane]);
        acc += p;
    } else {
        float m = -INFINITY;
        for (int j = beg + lane; j < end; j += 64) m = fmaxf(m, lrelu(As[csrc[j]] + ad));
#pragma unroll
        for (int o = 32; o > 0; o >>= 1) m = fmaxf(m, __shfl_xor(m, o));
        float d = 0.f;
        for (int j = beg + lane; j < end; j += 64) d += __expf(lrelu(As[csrc[j]] + ad) - m);
#pragma unroll
        for (int o = 32; o > 0; o >>= 1) d += __shfl_xor(d, o);
        for (int j = beg; j < end; j++) {
            int s = csrc[j];
            float wt = __expf(lrelu(As[s] + ad) - m) / d;
            acc += wt * b2f(hb[(size_t)s * 64 + lane]);
        }
    }
    float v = acc + bias[lane];
    v = v > 0.f ? v : expm1f(v);
    atomicAdd(&pooled[batch[node] * 64 + lane], v);
}

// ---- final: out[g,:] = (pooled[g,:]/cnt) @ Wl + bl ----
__global__ void final_k(const float* __restrict__ pooled, const float* __restrict__ cnt,
                        const float* __restrict__ Wl, const float* __restrict__ bl,
                        float* __restrict__ out) {
    int g = blockIdx.x;
    int t = threadIdx.x;  // 64
    __shared__ float s[64];
    float c = cnt[g];
    c = c > 1.f ? c : 1.f;
    s[t] = pooled[g * 64 + t] / c;
    __syncthreads();
    if (t < OUT_CH) {
        float acc = bl[t];
        for (int k = 0; k < 64; k++) acc += s[k] * Wl[k * OUT_CH + t];
        out[g * OUT_CH + t] = acc;
    }
}

extern "C" void kernel_launch(void* const* d_in, const int* in_sizes, int n_in,
                              void* d_out, int out_size, void* d_ws, size_t ws_size,
                              hipStream_t stream) {
    const float* x    = (const float*)d_in[0];
    const int*   ei   = (const int*)d_in[1];
    const int*   batch= (const int*)d_in[2];
    const float* W1   = (const float*)d_in[3];
    const float* as1  = (const float*)d_in[4];
    const float* ad1  = (const float*)d_in[5];
    const float* b1   = (const float*)d_in[6];
    const float* W2   = (const float*)d_in[7];
    const float* as2  = (const float*)d_in[8];
    const float* ad2  = (const float*)d_in[9];
    const float* b2   = (const float*)d_in[10];
    const float* Wl   = (const float*)d_in[11];
    const float* bl   = (const float*)d_in[12];
    float* out = (float*)d_out;

    const int* src = ei;
    const int* dst = ei + N_EDGES;
    const int ETOT = ETOT_C;
    const int NB = (N_NODES + 255) / 256;   // 196

    char* ws = (char*)d_ws;
    size_t off = 0;
    auto alloc = [&](size_t bytes) {
        void* p = ws + off;
        off = (off + bytes + 255) & ~((size_t)255);
        return p;
    };
    unsigned short* h1b  = (unsigned short*)alloc((size_t)N_NODES * 256 * 2);
    unsigned short* out1b= (unsigned short*)alloc((size_t)N_NODES * 256 * 2);
    float* As1    = (float*)alloc((size_t)N_NODES * 4 * 4);
    float* Ad1    = (float*)alloc((size_t)N_NODES * 4 * 4);
    float* As2    = (float*)alloc((size_t)N_NODES * 4);
    float* Ad2    = (float*)alloc((size_t)N_NODES * 4);
    int*   deg    = (int*)  alloc((size_t)N_NODES * 4);
    int*   rowptr = (int*)  alloc((size_t)(N_NODES + 1) * 4);
    int*   csrc   = (int*)  alloc((size_t)ETOT * 4);
    int*   rank   = (int*)  alloc((size_t)ETOT * 4);
    int*   bsum   = (int*)  alloc((size_t)NB * 4);
    unsigned short* Wt1 = (unsigned short*)alloc((size_t)256 * 128 * 2);
    unsigned short* Wt2 = (unsigned short*)alloc((size_t)64 * 256 * 2);
    float* pooled = (float*)alloc((size_t)N_GRAPHS * 64 * 4);
    float* cntf   = (float*)alloc((size_t)N_GRAPHS * 4);
    unsigned short* h2b = h1b;   // aliases h1b (dead after agg1_k)

    hipMemsetAsync(deg, 0, (size_t)N_NODES * 4, stream);

    // ---- weight conversion (gemm1 dependency), then fused mega-launch ----
    convw_k<<<192, 256, 0, stream>>>(W1, W2, Wt1, Wt2);
    mega1_k<<<GB1 + GH + 2 + GZ, 256, 0, stream>>>(
        x, Wt1, h1b, as1, ad1, As1, Ad1, N_NODES,
        dst, deg, rank, batch, cntf, pooled);

    // ---- CSR finalize ----
    blksum_k<<<NB, 256, 0, stream>>>(deg, bsum, N_NODES);
    scanb_k<<<1, 256, 0, stream>>>(bsum, NB);
    scanapply_k<<<NB, 256, 0, stream>>>(deg, bsum, rowptr, N_NODES);
    scatter_k<<<(ETOT + 255) / 256, 256, 0, stream>>>(src, dst, rowptr, rank, csrc, ETOT);

    // ---- layer 1 aggregate ----
    agg1_k<<<N_NODES / 4, 256, 0, stream>>>(rowptr, csrc, As1, Ad1,
                                            (const __hip_bfloat16*)h1b, b1, out1b, N_NODES);

    // ---- layer 2 ----
    mfma_gemm2_k<<<(N_NODES + 63) / 64, 256, 0, stream>>>(out1b, Wt2, h2b, as2, ad2,
                                                          As2, Ad2, N_NODES);
    agg2_k<<<N_NODES / 4, 256, 0, stream>>>(rowptr, csrc, As2, Ad2,
                                            (const __hip_bfloat16*)h2b, b2, batch, pooled, N_NODES);

    // ---- head ----
    final_k<<<N_GRAPHS, 64, 0, stream>>>(pooled, cntf, Wl, bl, out);
}

// Round 13
// 219.254 us; speedup vs baseline: 6.7981x; 1.0699x over previous
//
#include <hip/hip_runtime.h>
#include <hip/hip_bf16.h>
#include <math.h>

#define N_NODES 50000
#define N_EDGES 800000
#define IN_CH 128
#define HID 64
#define HEADS 4
#define OUT_CH 10
#define N_GRAPHS 512
#define NEG_SLOPE 0.2f

#define ETOT_C (N_EDGES + N_NODES)          // 850000
#define NPB 128                              // nodes per bucket
#define NBUK ((N_NODES + NPB - 1) / NPB)     // 391 buckets
#define EPB 2048                             // edges per pass-A/B block
#define GA ((ETOT_C + EPB - 1) / EPB)        // 416 pass-A blocks
#define GB1 ((N_NODES + 63) / 64)            // 782 gemm1 blocks
#define GZ 32                                // pooled-zero blocks

using short8_t = __attribute__((ext_vector_type(8))) short;
using f32x4 = __attribute__((ext_vector_type(4))) float;

__device__ __forceinline__ float b2f(unsigned short u) {
    return __uint_as_float(((unsigned)u) << 16);
}
__device__ __forceinline__ unsigned short f2b(float f) {
    __hip_bfloat16 b = __float2bfloat16(f);
    return *(unsigned short*)&b;
}
__device__ __forceinline__ short f2bs(float f) {
    __hip_bfloat16 b = __float2bfloat16(f);
    return *(short*)&b;
}
__device__ __forceinline__ float lrelu(float x) { return x > 0.f ? x : NEG_SLOPE * x; }

// ---- convert+transpose weights: Wt1[n][k]=bf16(W1[k][n]), Wt2 likewise ----
__global__ void convw_k(const float* __restrict__ W1, const float* __restrict__ W2,
                        unsigned short* __restrict__ Wt1, unsigned short* __restrict__ Wt2) {
    int idx = blockIdx.x * 256 + threadIdx.x;
    if (idx < 256 * 128) {               // Wt1: [256][128]
        int n = idx / 128, k = idx % 128;
        Wt1[idx] = f2b(W1[(size_t)k * 256 + n]);
    }
    int j = idx - 256 * 128;
    if (j >= 0 && j < 64 * 256) {        // Wt2: [64][256]
        int n = j / 256, k = j % 256;
        Wt2[j] = f2b(W2[(size_t)k * 64 + n]);
    }
}

// ---- MEGA 1: gemm1 (MFMA) || bucket-count passA (LDS hist) || cntg || zero ----
__global__ __launch_bounds__(256) void mega1_k(
        const float* __restrict__ X, const unsigned short* __restrict__ Wt,
        unsigned short* __restrict__ Yb,
        const float* __restrict__ asrc, const float* __restrict__ adst,
        float* __restrict__ As, float* __restrict__ Ad, int M,
        const int* __restrict__ dst, unsigned* __restrict__ bcnt,
        const int* __restrict__ batch, float* __restrict__ cntf,
        float* __restrict__ pooled) {
    int b = blockIdx.x;
    if (b < GB1) {
        // ---------------- gemm1 ----------------
        const int lane = threadIdx.x & 63;
        const int w = threadIdx.x >> 6;
        const int r0 = b * 64 + w * 16;
        const int l15 = lane & 15;
        const int rc = min(r0 + l15, M - 1);
        const int kg = (lane >> 4) * 8;

        f32x4 acc[16] = {};
#pragma unroll
        for (int kc = 0; kc < 4; kc++) {
            int k0 = kc * 32 + kg;
            float4 xa = *(const float4*)&X[(size_t)rc * 128 + k0];
            float4 xb = *(const float4*)&X[(size_t)rc * 128 + k0 + 4];
            short8_t af;
            af[0] = f2bs(xa.x); af[1] = f2bs(xa.y); af[2] = f2bs(xa.z); af[3] = f2bs(xa.w);
            af[4] = f2bs(xb.x); af[5] = f2bs(xb.y); af[6] = f2bs(xb.z); af[7] = f2bs(xb.w);
#pragma unroll
            for (int ct = 0; ct < 16; ct++) {
                int col = ct * 16 + l15;
                short8_t bf = *(const short8_t*)&Wt[(size_t)col * 128 + k0];
                acc[ct] = __builtin_amdgcn_mfma_f32_16x16x32_bf16(af, bf, acc[ct], 0, 0, 0);
            }
        }

        const int rbase = r0 + (lane >> 4) * 4;
#pragma unroll
        for (int reg = 0; reg < 4; reg++) {
            int gr = rbase + reg;
            float s0 = 0.f, s1 = 0.f, s2 = 0.f, s3 = 0.f;
            float d0 = 0.f, d1 = 0.f, d2 = 0.f, d3 = 0.f;
#pragma unroll
            for (int cg = 0; cg < 4; cg++) {
                int c = cg * 16 + l15;
                float v0 = acc[0 * 4 + cg][reg], v1 = acc[1 * 4 + cg][reg];
                float v2 = acc[2 * 4 + cg][reg], v3 = acc[3 * 4 + cg][reg];
                s0 += v0 * asrc[0 * 64 + c]; d0 += v0 * adst[0 * 64 + c];
                s1 += v1 * asrc[1 * 64 + c]; d1 += v1 * adst[1 * 64 + c];
                s2 += v2 * asrc[2 * 64 + c]; d2 += v2 * adst[2 * 64 + c];
                s3 += v3 * asrc[3 * 64 + c]; d3 += v3 * adst[3 * 64 + c];
            }
#pragma unroll
            for (int o = 8; o > 0; o >>= 1) {
                s0 += __shfl_xor(s0, o); d0 += __shfl_xor(d0, o);
                s1 += __shfl_xor(s1, o); d1 += __shfl_xor(d1, o);
                s2 += __shfl_xor(s2, o); d2 += __shfl_xor(d2, o);
                s3 += __shfl_xor(s3, o); d3 += __shfl_xor(d3, o);
            }
            if (l15 == 0 && gr < M) {
                *(float4*)&As[gr * 4] = make_float4(s0, s1, s2, s3);
                *(float4*)&Ad[gr * 4] = make_float4(d0, d1, d2, d3);
            }
        }
#pragma unroll
        for (int reg = 0; reg < 4; reg++) {
            int gr = rbase + reg;
            if (gr >= M) continue;
#pragma unroll
            for (int cg = 0; cg < 4; cg++) {
                int c = cg * 16 + l15;
                ushort4 p;
                p.x = f2b(acc[0 * 4 + cg][reg]);
                p.y = f2b(acc[1 * 4 + cg][reg]);
                p.z = f2b(acc[2 * 4 + cg][reg]);
                p.w = f2b(acc[3 * 4 + cg][reg]);
                *(ushort4*)&Yb[(size_t)gr * 256 + c * 4] = p;
            }
        }
        return;
    }
    b -= GB1;
    if (b < GA) {
        // ---------------- passA: bucket counts via LDS histogram ----------------
        __shared__ unsigned bins[NBUK];
        int t = threadIdx.x;
        for (int i = t; i < NBUK; i += 256) bins[i] = 0;
        __syncthreads();
        int e0 = b * EPB;
        int e1 = min(e0 + EPB, ETOT_C);
        for (int i = e0 + t; i < e1; i += 256) {
            int d = (i < N_EDGES) ? dst[i] : i - N_EDGES;
            atomicAdd(&bins[d >> 7], 1u);
        }
        __syncthreads();
        for (int i = t; i < NBUK; i += 256)
            if (bins[i]) atomicAdd(&bcnt[i], bins[i]);   // consecutive addrs -> coalesced
        return;
    }
    b -= GA;
    if (b < 2) {
        // ---------------- cntg: per-graph node counts ----------------
        int g = b * 256 + threadIdx.x;
        if (g >= N_GRAPHS) return;
        int lo = 0, hi = N_NODES;
        while (lo < hi) { int mid = (lo + hi) >> 1; if (batch[mid] < g) lo = mid + 1; else hi = mid; }
        int lo2 = lo, hi2 = N_NODES;
        while (lo2 < hi2) { int mid = (lo2 + hi2) >> 1; if (batch[mid] < g + 1) lo2 = mid + 1; else hi2 = mid; }
        cntf[g] = (float)(lo2 - lo);
        return;
    }
    b -= 2;
    // ---------------- pooled zero ----------------
    int idx = b * 256 + threadIdx.x;
    *(float4*)&pooled[(size_t)idx * 4] = make_float4(0.f, 0.f, 0.f, 0.f);
}

// ---- scanB: exclusive scan of 391 bucket counts -> bbase, bcur ----
__global__ void scanB_k(const unsigned* __restrict__ bcnt, int* __restrict__ bbase,
                        unsigned* __restrict__ bcur) {
    __shared__ int tmp[512];
    int t = threadIdx.x;
    int v = (t < NBUK) ? (int)bcnt[t] : 0;
    tmp[t] = v;
    __syncthreads();
    for (int o = 1; o < 512; o <<= 1) {
        int u = (t >= o) ? tmp[t - o] : 0;
        __syncthreads();
        tmp[t] += u;
        __syncthreads();
    }
    if (t < NBUK) {
        int ex = tmp[t] - v;
        bbase[t] = ex;
        bcur[t] = (unsigned)ex;
    }
    if (t == NBUK - 1) bbase[NBUK] = tmp[t];
}

// ---- passB: bucket the edges -> ebuf[(src,dst)] grouped by bucket ----
__global__ __launch_bounds__(256) void passB_k(const int* __restrict__ src,
                                               const int* __restrict__ dst,
                                               unsigned* __restrict__ bcur,
                                               int2* __restrict__ ebuf) {
    __shared__ unsigned bins[NBUK];
    __shared__ unsigned bbl[NBUK];
    __shared__ int dstash[EPB];
    int b = blockIdx.x;
    int t = threadIdx.x;
    for (int i = t; i < NBUK; i += 256) bins[i] = 0;
    __syncthreads();
    int e0 = b * EPB;
    int e1 = min(e0 + EPB, ETOT_C);
    for (int i = e0 + t; i < e1; i += 256) {
        int d = (i < N_EDGES) ? dst[i] : i - N_EDGES;
        dstash[i - e0] = d;
        atomicAdd(&bins[d >> 7], 1u);
    }
    __syncthreads();
    for (int i = t; i < NBUK; i += 256) {
        bbl[i] = bins[i] ? atomicAdd(&bcur[i], bins[i]) : 0u;
    }
    __syncthreads();
    for (int i = t; i < NBUK; i += 256) bins[i] = 0;
    __syncthreads();
    for (int i = e0 + t; i < e1; i += 256) {
        int d = dstash[i - e0];
        int s = (i < N_EDGES) ? src[i] : i - N_EDGES;
        unsigned r = atomicAdd(&bins[d >> 7], 1u);
        ebuf[bbl[d >> 7] + r] = make_int2(s, d);
    }
}

// ---- passC: per-bucket CSR finalize (rowptr + csrc), no global atomics ----
__global__ __launch_bounds__(256) void passC_k(const int* __restrict__ bbase,
                                               const int2* __restrict__ ebuf,
                                               int* __restrict__ rowptr,
                                               int* __restrict__ csrc) {
    __shared__ int cnt[NPB];
    __shared__ int loc[NPB];
    __shared__ int cur[NPB];
    int b = blockIdx.x;
    int t = threadIdx.x;
    int base = bbase[b], end = bbase[b + 1];
    if (t < NPB) cnt[t] = 0;
    __syncthreads();
    for (int j = base + t; j < end; j += 256) {
        int2 e = ebuf[j];
        atomicAdd(&cnt[e.y & (NPB - 1)], 1);
    }
    __syncthreads();
    if (t < NPB) loc[t] = cnt[t];
    __syncthreads();
    for (int o = 1; o < NPB; o <<= 1) {
        int v = (t < NPB && t >= o) ? loc[t - o] : 0;
        __syncthreads();
        if (t < NPB) loc[t] += v;
        __syncthreads();
    }
    // loc = inclusive scan; exclusive = loc - cnt
    if (t < NPB) {
        int node = b * NPB + t;
        if (node < N_NODES) rowptr[node] = base + loc[t] - cnt[t];
        cur[t] = 0;
    }
    if (b == NBUK - 1 && t == 0) rowptr[N_NODES] = end;
    __syncthreads();
    for (int j = base + t; j < end; j += 256) {
        int2 e = ebuf[j];
        int n = e.y & (NPB - 1);
        int r = atomicAdd(&cur[n], 1);
        csrc[base + loc[n] - cnt[n] + r] = e.x;
    }
}

// ---- layer-2 MFMA GEMM + attn coeffs + bf16 out ----
__global__ __launch_bounds__(256) void mfma_gemm2_k(
        const unsigned short* __restrict__ Xb, const unsigned short* __restrict__ Wt,
        unsigned short* __restrict__ Yb,
        const float* __restrict__ asrc, const float* __restrict__ adst,
        float* __restrict__ As, float* __restrict__ Ad, int M) {
    const int lane = threadIdx.x & 63;
    const int w = threadIdx.x >> 6;
    const int r0 = blockIdx.x * 64 + w * 16;
    const int l15 = lane & 15;
    const int rc = min(r0 + l15, M - 1);
    const int kg = (lane >> 4) * 8;

    f32x4 acc[4] = {};
#pragma unroll
    for (int kc = 0; kc < 8; kc++) {
        int k0 = kc * 32 + kg;
        short8_t af = *(const short8_t*)&Xb[(size_t)rc * 256 + k0];
#pragma unroll
        for (int ct = 0; ct < 4; ct++) {
            int col = ct * 16 + l15;
            short8_t bf = *(const short8_t*)&Wt[(size_t)col * 256 + k0];
            acc[ct] = __builtin_amdgcn_mfma_f32_16x16x32_bf16(af, bf, acc[ct], 0, 0, 0);
        }
    }

    const int rbase = r0 + (lane >> 4) * 4;
#pragma unroll
    for (int reg = 0; reg < 4; reg++) {
        int gr = rbase + reg;
        float sv = 0.f, dv = 0.f;
#pragma unroll
        for (int ct = 0; ct < 4; ct++) {
            int c = ct * 16 + l15;
            float v = acc[ct][reg];
            sv += v * asrc[c];
            dv += v * adst[c];
        }
#pragma unroll
        for (int o = 8; o > 0; o >>= 1) { sv += __shfl_xor(sv, o); dv += __shfl_xor(dv, o); }
        if (l15 == 0 && gr < M) { As[gr] = sv; Ad[gr] = dv; }
        if (gr < M) {
#pragma unroll
            for (int ct = 0; ct < 4; ct++)
                Yb[(size_t)gr * 64 + ct * 16 + l15] = f2b(acc[ct][reg]);
        }
    }
}

// ---- layer-1 fused softmax + gather + bias + ELU (H=4), bf16 output ----
__global__ void agg1_k(const int* __restrict__ rowptr, const int* __restrict__ csrc,
                       const float* __restrict__ As, const float* __restrict__ Ad,
                       const __hip_bfloat16* __restrict__ Hb,
                       const float* __restrict__ bias,
                       unsigned short* __restrict__ Outb, int nnodes) {
    __shared__ int ssh[4][64];
    __shared__ float4 wsh[4][64];
    int lane = threadIdx.x & 63;
    int w = threadIdx.x >> 6;
    int node = blockIdx.x * 4 + w;
    int beg = rowptr[node], end = rowptr[node + 1];
    int deg = end - beg;
    const unsigned short* hb = (const unsigned short*)Hb;
    float4 bv = *(const float4*)&Ad[node * 4];
    bool fast = (deg <= 64);
    if (fast) {
        bool act = lane < deg;
        int s = act ? csrc[beg + lane] : 0;
        float4 a = *(const float4*)&As[s * 4];
        float e0 = lrelu(a.x + bv.x), e1 = lrelu(a.y + bv.y);
        float e2 = lrelu(a.z + bv.z), e3 = lrelu(a.w + bv.w);
        if (!act) { e0 = e1 = e2 = e3 = -INFINITY; }
        float m0 = e0, m1 = e1, m2 = e2, m3 = e3;
#pragma unroll
        for (int o = 32; o > 0; o >>= 1) {
            m0 = fmaxf(m0, __shfl_xor(m0, o)); m1 = fmaxf(m1, __shfl_xor(m1, o));
            m2 = fmaxf(m2, __shfl_xor(m2, o)); m3 = fmaxf(m3, __shfl_xor(m3, o));
        }
        float x0 = act ? __expf(e0 - m0) : 0.f;
        float x1 = act ? __expf(e1 - m1) : 0.f;
        float x2 = act ? __expf(e2 - m2) : 0.f;
        float x3 = act ? __expf(e3 - m3) : 0.f;
        float d0 = x0, d1 = x1, d2 = x2, d3 = x3;
#pragma unroll
        for (int o = 32; o > 0; o >>= 1) {
            d0 += __shfl_xor(d0, o); d1 += __shfl_xor(d1, o);
            d2 += __shfl_xor(d2, o); d3 += __shfl_xor(d3, o);
        }
        ssh[w][lane] = s;
        wsh[w][lane] = make_float4(x0 / d0, x1 / d1, x2 / d2, x3 / d3);
    }
    __syncthreads();
    float acc0 = 0.f, acc1 = 0.f, acc2 = 0.f, acc3 = 0.f;
    if (fast) {
        float p0 = 0.f, p1 = 0.f, p2 = 0.f, p3 = 0.f;
        int j = 0;
        for (; j + 4 <= deg; j += 4) {
            int sA = ssh[w][j], sB = ssh[w][j + 1], sC = ssh[w][j + 2], sD = ssh[w][j + 3];
            float4 wA = wsh[w][j], wB = wsh[w][j + 1], wC = wsh[w][j + 2], wD = wsh[w][j + 3];
            ushort4 vA = *(const ushort4*)&hb[(size_t)sA * 256 + lane * 4];
            ushort4 vB = *(const ushort4*)&hb[(size_t)sB * 256 + lane * 4];
            ushort4 vC = *(const ushort4*)&hb[(size_t)sC * 256 + lane * 4];
            ushort4 vD = *(const ushort4*)&hb[(size_t)sD * 256 + lane * 4];
            acc0 += wA.x * b2f(vA.x) + wC.x * b2f(vC.x);
            p0   += wB.x * b2f(vB.x) + wD.x * b2f(vD.x);
            acc1 += wA.y * b2f(vA.y) + wC.y * b2f(vC.y);
            p1   += wB.y * b2f(vB.y) + wD.y * b2f(vD.y);
            acc2 += wA.z * b2f(vA.z) + wC.z * b2f(vC.z);
            p2   += wB.z * b2f(vB.z) + wD.z * b2f(vD.z);
            acc3 += wA.w * b2f(vA.w) + wC.w * b2f(vC.w);
            p3   += wB.w * b2f(vB.w) + wD.w * b2f(vD.w);
        }
        for (; j < deg; j++) {
            int s = ssh[w][j];
            float4 wt = wsh[w][j];
            ushort4 v = *(const ushort4*)&hb[(size_t)s * 256 + lane * 4];
            acc0 += wt.x * b2f(v.x); acc1 += wt.y * b2f(v.y);
            acc2 += wt.z * b2f(v.z); acc3 += wt.w * b2f(v.w);
        }
        acc0 += p0; acc1 += p1; acc2 += p2; acc3 += p3;
    } else {
        float m0 = -INFINITY, m1 = -INFINITY, m2 = -INFINITY, m3 = -INFINITY;
        for (int j = beg + lane; j < end; j += 64) {
            float4 a = *(const float4*)&As[csrc[j] * 4];
            m0 = fmaxf(m0, lrelu(a.x + bv.x)); m1 = fmaxf(m1, lrelu(a.y + bv.y));
            m2 = fmaxf(m2, lrelu(a.z + bv.z)); m3 = fmaxf(m3, lrelu(a.w + bv.w));
        }
#pragma unroll
        for (int o = 32; o > 0; o >>= 1) {
            m0 = fmaxf(m0, __shfl_xor(m0, o)); m1 = fmaxf(m1, __shfl_xor(m1, o));
            m2 = fmaxf(m2, __shfl_xor(m2, o)); m3 = fmaxf(m3, __shfl_xor(m3, o));
        }
        float d0 = 0.f, d1 = 0.f, d2 = 0.f, d3 = 0.f;
        for (int j = beg + lane; j < end; j += 64) {
            float4 a = *(const float4*)&As[csrc[j] * 4];
            d0 += __expf(lrelu(a.x + bv.x) - m0); d1 += __expf(lrelu(a.y + bv.y) - m1);
            d2 += __expf(lrelu(a.z + bv.z) - m2); d3 += __expf(lrelu(a.w + bv.w) - m3);
        }
#pragma unroll
        for (int o = 32; o > 0; o >>= 1) {
            d0 += __shfl_xor(d0, o); d1 += __shfl_xor(d1, o);
            d2 += __shfl_xor(d2, o); d3 += __shfl_xor(d3, o);
        }
        for (int j = beg; j < end; j++) {
            int s = csrc[j];
            float4 a = *(const float4*)&As[s * 4];
            float w0 = __expf(lrelu(a.x + bv.x) - m0) / d0;
            float w1 = __expf(lrelu(a.y + bv.y) - m1) / d1;
            float w2 = __expf(lrelu(a.z + bv.z) - m2) / d2;
            float w3 = __expf(lrelu(a.w + bv.w) - m3) / d3;
            ushort4 v = *(const ushort4*)&hb[(size_t)s * 256 + lane * 4];
            acc0 += w0 * b2f(v.x); acc1 += w1 * b2f(v.y);
            acc2 += w2 * b2f(v.z); acc3 += w3 * b2f(v.w);
        }
    }
    float r0 = acc0 + bias[0 * 64 + lane];
    float r1 = acc1 + bias[1 * 64 + lane];
    float r2 = acc2 + bias[2 * 64 + lane];
    float r3 = acc3 + bias[3 * 64 + lane];
    r0 = r0 > 0.f ? r0 : expm1f(r0);
    r1 = r1 > 0.f ? r1 : expm1f(r1);
    r2 = r2 > 0.f ? r2 : expm1f(r2);
    r3 = r3 > 0.f ? r3 : expm1f(r3);
    size_t base = (size_t)node * 256;
    Outb[base + 0 * 64 + lane] = f2b(r0);
    Outb[base + 1 * 64 + lane] = f2b(r1);
    Outb[base + 2 * 64 + lane] = f2b(r2);
    Outb[base + 3 * 64 + lane] = f2b(r3);
}

// ---- layer-2 fused softmax + gather + bias + ELU + mean-pool accum (H=1) ----
__global__ void agg2_k(const int* __restrict__ rowptr, const int* __restrict__ csrc,
                       const float* __restrict__ As, const float* __restrict__ Ad,
                       const __hip_bfloat16* __restrict__ Hb,
                       const float* __restrict__ bias, const int* __restrict__ batch,
                       float* __restrict__ pooled, int nnodes) {
    __shared__ int ssh[4][64];
    __shared__ float wsh[4][64];
    int lane = threadIdx.x & 63;
    int w = threadIdx.x >> 6;
    int node = blockIdx.x * 4 + w;
    int beg = rowptr[node], end = rowptr[node + 1];
    int deg = end - beg;
    const unsigned short* hb = (const unsigned short*)Hb;
    float ad = Ad[node];
    bool fast = (deg <= 64);
    if (fast) {
        bool act = lane < deg;
        int s = act ? csrc[beg + lane] : 0;
        float e = lrelu(As[s] + ad);
        if (!act) e = -INFINITY;
        float m = e;
#pragma unroll
        for (int o = 32; o > 0; o >>= 1) m = fmaxf(m, __shfl_xor(m, o));
        float x = act ? __expf(e - m) : 0.f;
        float d = x;
#pragma unroll
        for (int o = 32; o > 0; o >>= 1) d += __shfl_xor(d, o);
        ssh[w][lane] = s;
        wsh[w][lane] = x / d;
    }
    __syncthreads();
    float acc = 0.f;
    if (fast) {
        float p = 0.f;
        int j = 0;
        for (; j + 4 <= deg; j += 4) {
            int sA = ssh[w][j], sB = ssh[w][j + 1], sC = ssh[w][j + 2], sD = ssh[w][j + 3];
            float wA = wsh[w][j], wB = wsh[w][j + 1], wC = wsh[w][j + 2], wD = wsh[w][j + 3];
            acc += wA * b2f(hb[(size_t)sA * 64 + lane]) + wC * b2f(hb[(size_t)sC * 64 + lane]);
            p   += wB * b2f(hb[(size_t)sB * 64 + lane]) + wD * b2f(hb[(size_t)sD * 64 + lane]);
        }
        for (; j < deg; j++) acc += wsh[w][j] * b2f(hb[(size_t)ssh[w][j] * 64 + lane]);
        acc += p;
    } else {
        float m = -INFINITY;
        for (int j = beg + lane; j < end; j += 64) m = fmaxf(m, lrelu(As[csrc[j]] + ad));
#pragma unroll
        for (int o = 32; o > 0; o >>= 1) m = fmaxf(m, __shfl_xor(m, o));
        float d = 0.f;
        for (int j = beg + lane; j < end; j += 64) d += __expf(lrelu(As[csrc[j]] + ad) - m);
#pragma unroll
        for (int o = 32; o > 0; o >>= 1) d += __shfl_xor(d, o);
        for (int j = beg; j < end; j++) {
            int s = csrc[j];
            float wt = __expf(lrelu(As[s] + ad) - m) / d;
            acc += wt * b2f(hb[(size_t)s * 64 + lane]);
        }
    }
    float v = acc + bias[lane];
    v = v > 0.f ? v : expm1f(v);
    atomicAdd(&pooled[batch[node] * 64 + lane], v);
}

// ---- final: out[g,:] = (pooled[g,:]/cnt) @ Wl + bl ----
__global__ void final_k(const float* __restrict__ pooled, const float* __restrict__ cnt,
                        const float* __restrict__ Wl, const float* __restrict__ bl,
                        float* __restrict__ out) {
    int g = blockIdx.x;
    int t = threadIdx.x;  // 64
    __shared__ float s[64];
    float c = cnt[g];
    c = c > 1.f ? c : 1.f;
    s[t] = pooled[g * 64 + t] / c;
    __syncthreads();
    if (t < OUT_CH) {
        float acc = bl[t];
        for (int k = 0; k < 64; k++) acc += s[k] * Wl[k * OUT_CH + t];
        out[g * OUT_CH + t] = acc;
    }
}

extern "C" void kernel_launch(void* const* d_in, const int* in_sizes, int n_in,
                              void* d_out, int out_size, void* d_ws, size_t ws_size,
                              hipStream_t stream) {
    const float* x    = (const float*)d_in[0];
    const int*   ei   = (const int*)d_in[1];
    const int*   batch= (const int*)d_in[2];
    const float* W1   = (const float*)d_in[3];
    const float* as1  = (const float*)d_in[4];
    const float* ad1  = (const float*)d_in[5];
    const float* b1   = (const float*)d_in[6];
    const float* W2   = (const float*)d_in[7];
    const float* as2  = (const float*)d_in[8];
    const float* ad2  = (const float*)d_in[9];
    const float* b2   = (const float*)d_in[10];
    const float* Wl   = (const float*)d_in[11];
    const float* bl   = (const float*)d_in[12];
    float* out = (float*)d_out;

    const int* src = ei;
    const int* dst = ei + N_EDGES;

    char* ws = (char*)d_ws;
    size_t off = 0;
    auto alloc = [&](size_t bytes) {
        void* p = ws + off;
        off = (off + bytes + 255) & ~((size_t)255);
        return p;
    };
    unsigned short* h1b  = (unsigned short*)alloc((size_t)N_NODES * 256 * 2);
    unsigned short* out1b= (unsigned short*)alloc((size_t)N_NODES * 256 * 2);
    float* As1    = (float*)alloc((size_t)N_NODES * 4 * 4);
    float* Ad1    = (float*)alloc((size_t)N_NODES * 4 * 4);
    float* As2    = (float*)alloc((size_t)N_NODES * 4);
    float* Ad2    = (float*)alloc((size_t)N_NODES * 4);
    int*   rowptr = (int*)  alloc((size_t)(N_NODES + 1) * 4);
    int*   csrc   = (int*)  alloc((size_t)ETOT_C * 4);
    int2*  ebuf   = (int2*) alloc((size_t)ETOT_C * 8);
    unsigned* bcnt= (unsigned*)alloc((size_t)NBUK * 4);
    int*   bbase  = (int*)  alloc((size_t)(NBUK + 1) * 4);
    unsigned* bcur= (unsigned*)alloc((size_t)NBUK * 4);
    unsigned short* Wt1 = (unsigned short*)alloc((size_t)256 * 128 * 2);
    unsigned short* Wt2 = (unsigned short*)alloc((size_t)64 * 256 * 2);
    float* pooled = (float*)alloc((size_t)N_GRAPHS * 64 * 4);
    float* cntf   = (float*)alloc((size_t)N_GRAPHS * 4);
    unsigned short* h2b = h1b;   // aliases h1b (dead after agg1_k)

    hipMemsetAsync(bcnt, 0, (size_t)NBUK * 4, stream);

    // ---- weight conversion, then mega launch (gemm1 || passA || cntg || zero) ----
    convw_k<<<192, 256, 0, stream>>>(W1, W2, Wt1, Wt2);
    mega1_k<<<GB1 + GA + 2 + GZ, 256, 0, stream>>>(
        x, Wt1, h1b, as1, ad1, As1, Ad1, N_NODES,
        dst, bcnt, batch, cntf, pooled);

    // ---- bucketed CSR build (no random global atomics) ----
    scanB_k<<<1, 512, 0, stream>>>(bcnt, bbase, bcur);
    passB_k<<<GA, 256, 0, stream>>>(src, dst, bcur, ebuf);
    passC_k<<<NBUK, 256, 0, stream>>>(bbase, ebuf, rowptr, csrc);

    // ---- layer 1 aggregate ----
    agg1_k<<<N_NODES / 4, 256, 0, stream>>>(rowptr, csrc, As1, Ad1,
                                            (const __hip_bfloat16*)h1b, b1, out1b, N_NODES);

    // ---- layer 2 ----
    mfma_gemm2_k<<<(N_NODES + 63) / 64, 256, 0, stream>>>(out1b, Wt2, h2b, as2, ad2,
                                                          As2, Ad2, N_NODES);
    agg2_k<<<N_NODES / 4, 256, 0, stream>>>(rowptr, csrc, As2, Ad2,
                                            (const __hip_bfloat16*)h2b, b2, batch, pooled, N_NODES);

    // ---- head ----
    final_k<<<N_GRAPHS, 64, 0, stream>>>(pooled, cntf, Wl, bl, out);
}

// Round 14
// 212.907 us; speedup vs baseline: 7.0007x; 1.0298x over previous
//
#include <hip/hip_runtime.h>
#include <hip/hip_bf16.h>
#include <math.h>

#define N_NODES 50000
#define N_EDGES 800000
#define IN_CH 128
#define HID 64
#define HEADS 4
#define OUT_CH 10
#define N_GRAPHS 512
#define NEG_SLOPE 0.2f

#define ETOT_C (N_EDGES + N_NODES)          // 850000
#define NPB 128                              // nodes per bucket
#define NBUK ((N_NODES + NPB - 1) / NPB)     // 391 buckets
#define EPB 2048                             // edges per pass-A/B block
#define GA ((ETOT_C + EPB - 1) / EPB)        // 416 passA/passB blocks
#define GB1 ((N_NODES + 63) / 64)            // 782 gemm1 blocks
#define GZ 32                                // pooled-zero blocks
#define GW 192                               // convw blocks

using short8_t = __attribute__((ext_vector_type(8))) short;
using f32x4 = __attribute__((ext_vector_type(4))) float;

__device__ __forceinline__ float b2f(unsigned short u) {
    return __uint_as_float(((unsigned)u) << 16);
}
__device__ __forceinline__ unsigned short f2b(float f) {
    __hip_bfloat16 b = __float2bfloat16(f);
    return *(unsigned short*)&b;
}
__device__ __forceinline__ short f2bs(float f) {
    __hip_bfloat16 b = __float2bfloat16(f);
    return *(short*)&b;
}
__device__ __forceinline__ float lrelu(float x) { return x > 0.f ? x : NEG_SLOPE * x; }

// ---- MEGA A: passA bucket-count || cntg || pooled-zero || convw ----
__global__ __launch_bounds__(256) void megaA_k(
        const int* __restrict__ dst, unsigned* __restrict__ bcnt,
        const int* __restrict__ batch, float* __restrict__ cntf,
        float* __restrict__ pooled,
        const float* __restrict__ W1, const float* __restrict__ W2,
        unsigned short* __restrict__ Wt1, unsigned short* __restrict__ Wt2) {
    int b = blockIdx.x;
    int t = threadIdx.x;
    if (b < GA) {
        // ---------------- passA: bucket counts via LDS histogram ----------------
        __shared__ unsigned bins[NBUK];
        for (int i = t; i < NBUK; i += 256) bins[i] = 0;
        __syncthreads();
        int e0 = b * EPB;
        int e1 = min(e0 + EPB, ETOT_C);
        for (int i = e0 + t; i < e1; i += 256) {
            int d = (i < N_EDGES) ? dst[i] : i - N_EDGES;
            atomicAdd(&bins[d >> 7], 1u);
        }
        __syncthreads();
        for (int i = t; i < NBUK; i += 256)
            if (bins[i]) atomicAdd(&bcnt[i], bins[i]);   // consecutive addrs -> coalesced
        return;
    }
    b -= GA;
    if (b < 2) {
        // ---------------- cntg ----------------
        int g = b * 256 + t;
        if (g >= N_GRAPHS) return;
        int lo = 0, hi = N_NODES;
        while (lo < hi) { int mid = (lo + hi) >> 1; if (batch[mid] < g) lo = mid + 1; else hi = mid; }
        int lo2 = lo, hi2 = N_NODES;
        while (lo2 < hi2) { int mid = (lo2 + hi2) >> 1; if (batch[mid] < g + 1) lo2 = mid + 1; else hi2 = mid; }
        cntf[g] = (float)(lo2 - lo);
        return;
    }
    b -= 2;
    if (b < GZ) {
        // ---------------- pooled zero ----------------
        int idx = b * 256 + t;
        *(float4*)&pooled[(size_t)idx * 4] = make_float4(0.f, 0.f, 0.f, 0.f);
        return;
    }
    b -= GZ;
    // ---------------- convw: bf16-transpose weights ----------------
    int idx = b * 256 + t;
    if (idx < 256 * 128) {               // Wt1: [256][128]
        int n = idx / 128, k = idx % 128;
        Wt1[idx] = f2b(W1[(size_t)k * 256 + n]);
    }
    int j = idx - 256 * 128;
    if (j >= 0 && j < 64 * 256) {        // Wt2: [64][256]
        int n = j / 256, k = j % 256;
        Wt2[j] = f2b(W2[(size_t)k * 64 + n]);
    }
}

// ---- scanB: exclusive scan of 391 bucket counts -> bbase, bcur ----
__global__ void scanB_k(const unsigned* __restrict__ bcnt, int* __restrict__ bbase,
                        unsigned* __restrict__ bcur) {
    __shared__ int tmp[512];
    int t = threadIdx.x;
    int v = (t < NBUK) ? (int)bcnt[t] : 0;
    tmp[t] = v;
    __syncthreads();
    for (int o = 1; o < 512; o <<= 1) {
        int u = (t >= o) ? tmp[t - o] : 0;
        __syncthreads();
        tmp[t] += u;
        __syncthreads();
    }
    if (t < NBUK) {
        int ex = tmp[t] - v;
        bbase[t] = ex;
        bcur[t] = (unsigned)ex;
    }
    if (t == NBUK - 1) bbase[NBUK] = tmp[t];
}

// ---- MEGA B: gemm1 (MFMA) || passB (edge bucketing) ----
__global__ __launch_bounds__(256) void megaB_k(
        const float* __restrict__ X, const unsigned short* __restrict__ Wt,
        unsigned short* __restrict__ Yb,
        const float* __restrict__ asrc, const float* __restrict__ adst,
        float* __restrict__ As, float* __restrict__ Ad, int M,
        const int* __restrict__ src, const int* __restrict__ dst,
        unsigned* __restrict__ bcur, int2* __restrict__ ebuf) {
    int b = blockIdx.x;
    if (b < GB1) {
        // ---------------- gemm1 ----------------
        const int lane = threadIdx.x & 63;
        const int w = threadIdx.x >> 6;
        const int r0 = b * 64 + w * 16;
        const int l15 = lane & 15;
        const int rc = min(r0 + l15, M - 1);
        const int kg = (lane >> 4) * 8;

        f32x4 acc[16] = {};
#pragma unroll
        for (int kc = 0; kc < 4; kc++) {
            int k0 = kc * 32 + kg;
            float4 xa = *(const float4*)&X[(size_t)rc * 128 + k0];
            float4 xb = *(const float4*)&X[(size_t)rc * 128 + k0 + 4];
            short8_t af;
            af[0] = f2bs(xa.x); af[1] = f2bs(xa.y); af[2] = f2bs(xa.z); af[3] = f2bs(xa.w);
            af[4] = f2bs(xb.x); af[5] = f2bs(xb.y); af[6] = f2bs(xb.z); af[7] = f2bs(xb.w);
#pragma unroll
            for (int ct = 0; ct < 16; ct++) {
                int col = ct * 16 + l15;
                short8_t bf = *(const short8_t*)&Wt[(size_t)col * 128 + k0];
                acc[ct] = __builtin_amdgcn_mfma_f32_16x16x32_bf16(af, bf, acc[ct], 0, 0, 0);
            }
        }

        const int rbase = r0 + (lane >> 4) * 4;
#pragma unroll
        for (int reg = 0; reg < 4; reg++) {
            int gr = rbase + reg;
            float s0 = 0.f, s1 = 0.f, s2 = 0.f, s3 = 0.f;
            float d0 = 0.f, d1 = 0.f, d2 = 0.f, d3 = 0.f;
#pragma unroll
            for (int cg = 0; cg < 4; cg++) {
                int c = cg * 16 + l15;
                float v0 = acc[0 * 4 + cg][reg], v1 = acc[1 * 4 + cg][reg];
                float v2 = acc[2 * 4 + cg][reg], v3 = acc[3 * 4 + cg][reg];
                s0 += v0 * asrc[0 * 64 + c]; d0 += v0 * adst[0 * 64 + c];
                s1 += v1 * asrc[1 * 64 + c]; d1 += v1 * adst[1 * 64 + c];
                s2 += v2 * asrc[2 * 64 + c]; d2 += v2 * adst[2 * 64 + c];
                s3 += v3 * asrc[3 * 64 + c]; d3 += v3 * adst[3 * 64 + c];
            }
#pragma unroll
            for (int o = 8; o > 0; o >>= 1) {
                s0 += __shfl_xor(s0, o); d0 += __shfl_xor(d0, o);
                s1 += __shfl_xor(s1, o); d1 += __shfl_xor(d1, o);
                s2 += __shfl_xor(s2, o); d2 += __shfl_xor(d2, o);
                s3 += __shfl_xor(s3, o); d3 += __shfl_xor(d3, o);
            }
            if (l15 == 0 && gr < M) {
                *(float4*)&As[gr * 4] = make_float4(s0, s1, s2, s3);
                *(float4*)&Ad[gr * 4] = make_float4(d0, d1, d2, d3);
            }
        }
#pragma unroll
        for (int reg = 0; reg < 4; reg++) {
            int gr = rbase + reg;
            if (gr >= M) continue;
#pragma unroll
            for (int cg = 0; cg < 4; cg++) {
                int c = cg * 16 + l15;
                ushort4 p;
                p.x = f2b(acc[0 * 4 + cg][reg]);
                p.y = f2b(acc[1 * 4 + cg][reg]);
                p.z = f2b(acc[2 * 4 + cg][reg]);
                p.w = f2b(acc[3 * 4 + cg][reg]);
                *(ushort4*)&Yb[(size_t)gr * 256 + c * 4] = p;
            }
        }
        return;
    }
    b -= GB1;
    // ---------------- passB: bucket the edges -> ebuf grouped by bucket ----
    {
        __shared__ unsigned bins[NBUK];
        __shared__ unsigned bbl[NBUK];
        __shared__ int dstash[EPB];
        int t = threadIdx.x;
        for (int i = t; i < NBUK; i += 256) bins[i] = 0;
        __syncthreads();
        int e0 = b * EPB;
        int e1 = min(e0 + EPB, ETOT_C);
        for (int i = e0 + t; i < e1; i += 256) {
            int d = (i < N_EDGES) ? dst[i] : i - N_EDGES;
            dstash[i - e0] = d;
            atomicAdd(&bins[d >> 7], 1u);
        }
        __syncthreads();
        for (int i = t; i < NBUK; i += 256) {
            bbl[i] = bins[i] ? atomicAdd(&bcur[i], bins[i]) : 0u;
        }
        __syncthreads();
        for (int i = t; i < NBUK; i += 256) bins[i] = 0;
        __syncthreads();
        for (int i = e0 + t; i < e1; i += 256) {
            int d = dstash[i - e0];
            int s = (i < N_EDGES) ? src[i] : i - N_EDGES;
            unsigned r = atomicAdd(&bins[d >> 7], 1u);
            ebuf[bbl[d >> 7] + r] = make_int2(s, d);
        }
    }
}

// ---- passC: per-bucket CSR finalize (rowptr + csrc), no global atomics ----
__global__ __launch_bounds__(256) void passC_k(const int* __restrict__ bbase,
                                               const int2* __restrict__ ebuf,
                                               int* __restrict__ rowptr,
                                               int* __restrict__ csrc) {
    __shared__ int cnt[NPB];
    __shared__ int loc[NPB];
    __shared__ int cur[NPB];
    int b = blockIdx.x;
    int t = threadIdx.x;
    int base = bbase[b], end = bbase[b + 1];
    if (t < NPB) cnt[t] = 0;
    __syncthreads();
    for (int j = base + t; j < end; j += 256) {
        int2 e = ebuf[j];
        atomicAdd(&cnt[e.y & (NPB - 1)], 1);
    }
    __syncthreads();
    if (t < NPB) loc[t] = cnt[t];
    __syncthreads();
    for (int o = 1; o < NPB; o <<= 1) {
        int v = (t < NPB && t >= o) ? loc[t - o] : 0;
        __syncthreads();
        if (t < NPB) loc[t] += v;
        __syncthreads();
    }
    if (t < NPB) {
        int node = b * NPB + t;
        if (node < N_NODES) rowptr[node] = base + loc[t] - cnt[t];
        cur[t] = 0;
    }
    if (b == NBUK - 1 && t == 0) rowptr[N_NODES] = end;
    __syncthreads();
    for (int j = base + t; j < end; j += 256) {
        int2 e = ebuf[j];
        int n = e.y & (NPB - 1);
        int r = atomicAdd(&cur[n], 1);
        csrc[base + loc[n] - cnt[n] + r] = e.x;
    }
}

// ---- layer-2 MFMA GEMM + attn coeffs + bf16 out ----
__global__ __launch_bounds__(256) void mfma_gemm2_k(
        const unsigned short* __restrict__ Xb, const unsigned short* __restrict__ Wt,
        unsigned short* __restrict__ Yb,
        const float* __restrict__ asrc, const float* __restrict__ adst,
        float* __restrict__ As, float* __restrict__ Ad, int M) {
    const int lane = threadIdx.x & 63;
    const int w = threadIdx.x >> 6;
    const int r0 = blockIdx.x * 64 + w * 16;
    const int l15 = lane & 15;
    const int rc = min(r0 + l15, M - 1);
    const int kg = (lane >> 4) * 8;

    f32x4 acc[4] = {};
#pragma unroll
    for (int kc = 0; kc < 8; kc++) {
        int k0 = kc * 32 + kg;
        short8_t af = *(const short8_t*)&Xb[(size_t)rc * 256 + k0];
#pragma unroll
        for (int ct = 0; ct < 4; ct++) {
            int col = ct * 16 + l15;
            short8_t bf = *(const short8_t*)&Wt[(size_t)col * 256 + k0];
            acc[ct] = __builtin_amdgcn_mfma_f32_16x16x32_bf16(af, bf, acc[ct], 0, 0, 0);
        }
    }

    const int rbase = r0 + (lane >> 4) * 4;
#pragma unroll
    for (int reg = 0; reg < 4; reg++) {
        int gr = rbase + reg;
        float sv = 0.f, dv = 0.f;
#pragma unroll
        for (int ct = 0; ct < 4; ct++) {
            int c = ct * 16 + l15;
            float v = acc[ct][reg];
            sv += v * asrc[c];
            dv += v * adst[c];
        }
#pragma unroll
        for (int o = 8; o > 0; o >>= 1) { sv += __shfl_xor(sv, o); dv += __shfl_xor(dv, o); }
        if (l15 == 0 && gr < M) { As[gr] = sv; Ad[gr] = dv; }
        if (gr < M) {
#pragma unroll
            for (int ct = 0; ct < 4; ct++)
                Yb[(size_t)gr * 64 + ct * 16 + l15] = f2b(acc[ct][reg]);
        }
    }
}

// ---- layer-1 fused softmax + gather + bias + ELU (H=4), bf16 output ----
__global__ void agg1_k(const int* __restrict__ rowptr, const int* __restrict__ csrc,
                       const float* __restrict__ As, const float* __restrict__ Ad,
                       const __hip_bfloat16* __restrict__ Hb,
                       const float* __restrict__ bias,
                       unsigned short* __restrict__ Outb, int nnodes) {
    __shared__ int ssh[4][64];
    __shared__ float4 wsh[4][64];
    int lane = threadIdx.x & 63;
    int w = threadIdx.x >> 6;
    int node = blockIdx.x * 4 + w;
    int beg = rowptr[node], end = rowptr[node + 1];
    int deg = end - beg;
    const unsigned short* hb = (const unsigned short*)Hb;
    float4 bv = *(const float4*)&Ad[node * 4];
    bool fast = (deg <= 64);
    if (fast) {
        bool act = lane < deg;
        int s = act ? csrc[beg + lane] : 0;
        float4 a = *(const float4*)&As[s * 4];
        float e0 = lrelu(a.x + bv.x), e1 = lrelu(a.y + bv.y);
        float e2 = lrelu(a.z + bv.z), e3 = lrelu(a.w + bv.w);
        if (!act) { e0 = e1 = e2 = e3 = -INFINITY; }
        float m0 = e0, m1 = e1, m2 = e2, m3 = e3;
#pragma unroll
        for (int o = 32; o > 0; o >>= 1) {
            m0 = fmaxf(m0, __shfl_xor(m0, o)); m1 = fmaxf(m1, __shfl_xor(m1, o));
            m2 = fmaxf(m2, __shfl_xor(m2, o)); m3 = fmaxf(m3, __shfl_xor(m3, o));
        }
        float x0 = act ? __expf(e0 - m0) : 0.f;
        float x1 = act ? __expf(e1 - m1) : 0.f;
        float x2 = act ? __expf(e2 - m2) : 0.f;
        float x3 = act ? __expf(e3 - m3) : 0.f;
        float d0 = x0, d1 = x1, d2 = x2, d3 = x3;
#pragma unroll
        for (int o = 32; o > 0; o >>= 1) {
            d0 += __shfl_xor(d0, o); d1 += __shfl_xor(d1, o);
            d2 += __shfl_xor(d2, o); d3 += __shfl_xor(d3, o);
        }
        ssh[w][lane] = s;
        wsh[w][lane] = make_float4(x0 / d0, x1 / d1, x2 / d2, x3 / d3);
    }
    __syncthreads();
    float acc0 = 0.f, acc1 = 0.f, acc2 = 0.f, acc3 = 0.f;
    if (fast) {
        float p0 = 0.f, p1 = 0.f, p2 = 0.f, p3 = 0.f;
        int j = 0;
        for (; j + 4 <= deg; j += 4) {
            int sA = ssh[w][j], sB = ssh[w][j + 1], sC = ssh[w][j + 2], sD = ssh[w][j + 3];
            float4 wA = wsh[w][j], wB = wsh[w][j + 1], wC = wsh[w][j + 2], wD = wsh[w][j + 3];
            ushort4 vA = *(const ushort4*)&hb[(size_t)sA * 256 + lane * 4];
            ushort4 vB = *(const ushort4*)&hb[(size_t)sB * 256 + lane * 4];
            ushort4 vC = *(const ushort4*)&hb[(size_t)sC * 256 + lane * 4];
            ushort4 vD = *(const ushort4*)&hb[(size_t)sD * 256 + lane * 4];
            acc0 += wA.x * b2f(vA.x) + wC.x * b2f(vC.x);
            p0   += wB.x * b2f(vB.x) + wD.x * b2f(vD.x);
            acc1 += wA.y * b2f(vA.y) + wC.y * b2f(vC.y);
            p1   += wB.y * b2f(vB.y) + wD.y * b2f(vD.y);
            acc2 += wA.z * b2f(vA.z) + wC.z * b2f(vC.z);
            p2   += wB.z * b2f(vB.z) + wD.z * b2f(vD.z);
            acc3 += wA.w * b2f(vA.w) + wC.w * b2f(vC.w);
            p3   += wB.w * b2f(vB.w) + wD.w * b2f(vD.w);
        }
        for (; j < deg; j++) {
            int s = ssh[w][j];
            float4 wt = wsh[w][j];
            ushort4 v = *(const ushort4*)&hb[(size_t)s * 256 + lane * 4];
            acc0 += wt.x * b2f(v.x); acc1 += wt.y * b2f(v.y);
            acc2 += wt.z * b2f(v.z); acc3 += wt.w * b2f(v.w);
        }
        acc0 += p0; acc1 += p1; acc2 += p2; acc3 += p3;
    } else {
        float m0 = -INFINITY, m1 = -INFINITY, m2 = -INFINITY, m3 = -INFINITY;
        for (int j = beg + lane; j < end; j += 64) {
            float4 a = *(const float4*)&As[csrc[j] * 4];
            m0 = fmaxf(m0, lrelu(a.x + bv.x)); m1 = fmaxf(m1, lrelu(a.y + bv.y));
            m2 = fmaxf(m2, lrelu(a.z + bv.z)); m3 = fmaxf(m3, lrelu(a.w + bv.w));
        }
#pragma unroll
        for (int o = 32; o > 0; o >>= 1) {
            m0 = fmaxf(m0, __shfl_xor(m0, o)); m1 = fmaxf(m1, __shfl_xor(m1, o));
            m2 = fmaxf(m2, __shfl_xor(m2, o)); m3 = fmaxf(m3, __shfl_xor(m3, o));
        }
        float d0 = 0.f, d1 = 0.f, d2 = 0.f, d3 = 0.f;
        for (int j = beg + lane; j < end; j += 64) {
            float4 a = *(const float4*)&As[csrc[j] * 4];
            d0 += __expf(lrelu(a.x + bv.x) - m0); d1 += __expf(lrelu(a.y + bv.y) - m1);
            d2 += __expf(lrelu(a.z + bv.z) - m2); d3 += __expf(lrelu(a.w + bv.w) - m3);
        }
#pragma unroll
        for (int o = 32; o > 0; o >>= 1) {
            d0 += __shfl_xor(d0, o); d1 += __shfl_xor(d1, o);
            d2 += __shfl_xor(d2, o); d3 += __shfl_xor(d3, o);
        }
        for (int j = beg; j < end; j++) {
            int s = csrc[j];
            float4 a = *(const float4*)&As[s * 4];
            float w0 = __expf(lrelu(a.x + bv.x) - m0) / d0;
            float w1 = __expf(lrelu(a.y + bv.y) - m1) / d1;
            float w2 = __expf(lrelu(a.z + bv.z) - m2) / d2;
            float w3 = __expf(lrelu(a.w + bv.w) - m3) / d3;
            ushort4 v = *(const ushort4*)&hb[(size_t)s * 256 + lane * 4];
            acc0 += w0 * b2f(v.x); acc1 += w1 * b2f(v.y);
            acc2 += w2 * b2f(v.z); acc3 += w3 * b2f(v.w);
        }
    }
    float r0 = acc0 + bias[0 * 64 + lane];
    float r1 = acc1 + bias[1 * 64 + lane];
    float r2 = acc2 + bias[2 * 64 + lane];
    float r3 = acc3 + bias[3 * 64 + lane];
    r0 = r0 > 0.f ? r0 : expm1f(r0);
    r1 = r1 > 0.f ? r1 : expm1f(r1);
    r2 = r2 > 0.f ? r2 : expm1f(r2);
    r3 = r3 > 0.f ? r3 : expm1f(r3);
    size_t base = (size_t)node * 256;
    Outb[base + 0 * 64 + lane] = f2b(r0);
    Outb[base + 1 * 64 + lane] = f2b(r1);
    Outb[base + 2 * 64 + lane] = f2b(r2);
    Outb[base + 3 * 64 + lane] = f2b(r3);
}

// ---- layer-2 fused softmax + gather + bias + ELU + mean-pool accum (H=1) ----
__global__ void agg2_k(const int* __restrict__ rowptr, const int* __restrict__ csrc,
                       const float* __restrict__ As, const float* __restrict__ Ad,
                       const __hip_bfloat16* __restrict__ Hb,
                       const float* __restrict__ bias, const int* __restrict__ batch,
                       float* __restrict__ pooled, int nnodes) {
    __shared__ int ssh[4][64];
    __shared__ float wsh[4][64];
    int lane = threadIdx.x & 63;
    int w = threadIdx.x >> 6;
    int node = blockIdx.x * 4 + w;
    int beg = rowptr[node], end = rowptr[node + 1];
    int deg = end - beg;
    const unsigned short* hb = (const unsigned short*)Hb;
    float ad = Ad[node];
    bool fast = (deg <= 64);
    if (fast) {
        bool act = lane < deg;
        int s = act ? csrc[beg + lane] : 0;
        float e = lrelu(As[s] + ad);
        if (!act) e = -INFINITY;
        float m = e;
#pragma unroll
        for (int o = 32; o > 0; o >>= 1) m = fmaxf(m, __shfl_xor(m, o));
        float x = act ? __expf(e - m) : 0.f;
        float d = x;
#pragma unroll
        for (int o = 32; o > 0; o >>= 1) d += __shfl_xor(d, o);
        ssh[w][lane] = s;
        wsh[w][lane] = x / d;
    }
    __syncthreads();
    float acc = 0.f;
    if (fast) {
        float p = 0.f;
        int j = 0;
        for (; j + 4 <= deg; j += 4) {
            int sA = ssh[w][j], sB = ssh[w][j + 1], sC = ssh[w][j + 2], sD = ssh[w][j + 3];
            float wA = wsh[w][j], wB = wsh[w][j + 1], wC = wsh[w][j + 2], wD = wsh[w][j + 3];
            acc += wA * b2f(hb[(size_t)sA * 64 + lane]) + wC * b2f(hb[(size_t)sC * 64 + lane]);
            p   += wB * b2f(hb[(size_t)sB * 64 + lane]) + wD * b2f(hb[(size_t)sD * 64 + lane]);
        }
        for (; j < deg; j++) acc += wsh[w][j] * b2f(hb[(size_t)ssh[w][j] * 64 + lane]);
        acc += p;
    } else {
        float m = -INFINITY;
        for (int j = beg + lane; j < end; j += 64) m = fmaxf(m, lrelu(As[csrc[j]] + ad));
#pragma unroll
        for (int o = 32; o > 0; o >>= 1) m = fmaxf(m, __shfl_xor(m, o));
        float d = 0.f;
        for (int j = beg + lane; j < end; j += 64) d += __expf(lrelu(As[csrc[j]] + ad) - m);
#pragma unroll
        for (int o = 32; o > 0; o >>= 1) d += __shfl_xor(d, o);
        for (int j = beg; j < end; j++) {
            int s = csrc[j];
            float wt = __expf(lrelu(As[s] + ad) - m) / d;
            acc += wt * b2f(hb[(size_t)s * 64 + lane]);
        }
    }
    float v = acc + bias[lane];
    v = v > 0.f ? v : expm1f(v);
    atomicAdd(&pooled[batch[node] * 64 + lane], v);
}

// ---- final: out[g,:] = (pooled[g,:]/cnt) @ Wl + bl ----
__global__ void final_k(const float* __restrict__ pooled, const float* __restrict__ cnt,
                        const float* __restrict__ Wl, const float* __restrict__ bl,
                        float* __restrict__ out) {
    int g = blockIdx.x;
    int t = threadIdx.x;  // 64
    __shared__ float s[64];
    float c = cnt[g];
    c = c > 1.f ? c : 1.f;
    s[t] = pooled[g * 64 + t] / c;
    __syncthreads();
    if (t < OUT_CH) {
        float acc = bl[t];
        for (int k = 0; k < 64; k++) acc += s[k] * Wl[k * OUT_CH + t];
        out[g * OUT_CH + t] = acc;
    }
}

extern "C" void kernel_launch(void* const* d_in, const int* in_sizes, int n_in,
                              void* d_out, int out_size, void* d_ws, size_t ws_size,
                              hipStream_t stream) {
    const float* x    = (const float*)d_in[0];
    const int*   ei   = (const int*)d_in[1];
    const int*   batch= (const int*)d_in[2];
    const float* W1   = (const float*)d_in[3];
    const float* as1  = (const float*)d_in[4];
    const float* ad1  = (const float*)d_in[5];
    const float* b1   = (const float*)d_in[6];
    const float* W2   = (const float*)d_in[7];
    const float* as2  = (const float*)d_in[8];
    const float* ad2  = (const float*)d_in[9];
    const float* b2   = (const float*)d_in[10];
    const float* Wl   = (const float*)d_in[11];
    const float* bl   = (const float*)d_in[12];
    float* out = (float*)d_out;

    const int* src = ei;
    const int* dst = ei + N_EDGES;

    char* ws = (char*)d_ws;
    size_t off = 0;
    auto alloc = [&](size_t bytes) {
        void* p = ws + off;
        off = (off + bytes + 255) & ~((size_t)255);
        return p;
    };
    unsigned short* h1b  = (unsigned short*)alloc((size_t)N_NODES * 256 * 2);
    unsigned short* out1b= (unsigned short*)alloc((size_t)N_NODES * 256 * 2);
    float* As1    = (float*)alloc((size_t)N_NODES * 4 * 4);
    float* Ad1    = (float*)alloc((size_t)N_NODES * 4 * 4);
    float* As2    = (float*)alloc((size_t)N_NODES * 4);
    float* Ad2    = (float*)alloc((size_t)N_NODES * 4);
    int*   rowptr = (int*)  alloc((size_t)(N_NODES + 1) * 4);
    int*   csrc   = (int*)  alloc((size_t)ETOT_C * 4);
    int2*  ebuf   = (int2*) alloc((size_t)ETOT_C * 8);
    unsigned* bcnt= (unsigned*)alloc((size_t)NBUK * 4);
    int*   bbase  = (int*)  alloc((size_t)(NBUK + 1) * 4);
    unsigned* bcur= (unsigned*)alloc((size_t)NBUK * 4);
    unsigned short* Wt1 = (unsigned short*)alloc((size_t)256 * 128 * 2);
    unsigned short* Wt2 = (unsigned short*)alloc((size_t)64 * 256 * 2);
    float* pooled = (float*)alloc((size_t)N_GRAPHS * 64 * 4);
    float* cntf   = (float*)alloc((size_t)N_GRAPHS * 4);
    unsigned short* h2b = h1b;   // aliases h1b (dead after agg1_k)

    hipMemsetAsync(bcnt, 0, (size_t)NBUK * 4, stream);

    // ---- megaA: passA || cntg || pooled-zero || convw ----
    megaA_k<<<GA + 2 + GZ + GW, 256, 0, stream>>>(dst, bcnt, batch, cntf, pooled,
                                                  W1, W2, Wt1, Wt2);
    scanB_k<<<1, 512, 0, stream>>>(bcnt, bbase, bcur);

    // ---- megaB: gemm1 || passB ----
    megaB_k<<<GB1 + GA, 256, 0, stream>>>(x, Wt1, h1b, as1, ad1, As1, Ad1, N_NODES,
                                          src, dst, bcur, ebuf);
    passC_k<<<NBUK, 256, 0, stream>>>(bbase, ebuf, rowptr, csrc);

    // ---- layer 1 aggregate ----
    agg1_k<<<N_NODES / 4, 256, 0, stream>>>(rowptr, csrc, As1, Ad1,
                                            (const __hip_bfloat16*)h1b, b1, out1b, N_NODES);

    // ---- layer 2 ----
    mfma_gemm2_k<<<(N_NODES + 63) / 64, 256, 0, stream>>>(out1b, Wt2, h2b, as2, ad2,
                                                          As2, Ad2, N_NODES);
    agg2_k<<<N_NODES / 4, 256, 0, stream>>>(rowptr, csrc, As2, Ad2,
                                            (const __hip_bfloat16*)h2b, b2, batch, pooled, N_NODES);

    // ---- head ----
    final_k<<<N_GRAPHS, 64, 0, stream>>>(pooled, cntf, Wl, bl, out);
}